// Round 1
// baseline (1994.115 us; speedup 1.0000x reference)
//
#include <hip/hip_runtime.h>
#include <math.h>

// Problem constants
#define S_LEN   2048
#define E_DIM   2048
#define NH      64
#define P_DIM   64
#define N_DIM   128
#define K_CONV  4
#define CS      256
#define NCHUNK  8          // S_LEN / CS
#define INTER   4096       // NH * P_DIM
#define CONVD   4352       // INTER + 2*N_DIM
#define PROJ    8512       // INTER + CONVD + NH
#define EPS     1e-5f

// Workspace layout (float offsets)
#define OFF_PROJ 0ull
#define OFF_HBC  17432576ull                 // 2048*8512
#define OFF_DT   (OFF_HBC + 2048ull*4352)    // 26345472
#define OFF_GM   (OFF_DT + 2048ull*64)       // 26476544
#define OFF_Y    (OFF_GM + 8ull*256*256)     // 27000832
#define OFF_YN   (OFF_Y + 2048ull*4096)      // 35389440
// total end: 43778048 floats = 175.1 MB

// ---------------------------------------------------------------------------
// Generic NT GEMM: C[m][n] = sum_k A[m][k] * B[n][k]
// 128x64 tile per block, 256 threads, 8x4 micro-tile, K-step 16.
// M%128==0, N%64==0, K%16==0 for all call sites.
// ---------------------------------------------------------------------------
__global__ __launch_bounds__(256) void gemm_nt(
    const float* __restrict__ A, int lda, long long sA,
    const float* __restrict__ B, int ldb, long long sB,
    float* __restrict__ C, int ldc, long long sC, int K)
{
    A += (long long)blockIdx.z * sA;
    B += (long long)blockIdx.z * sB;
    C += (long long)blockIdx.z * sC;
    const int t  = threadIdx.x;
    const int m0 = blockIdx.y * 128;
    const int n0 = blockIdx.x * 64;
    __shared__ float As[16][132];   // [k][m], pad keeps b128 reads/writes clean
    __shared__ float Bs[16][68];    // [k][n]
    const int tx = t & 15;          // n group (x4)
    const int ty = t >> 4;          // m group (x8)

    const int arow = t & 127;
    const int akh  = (t >> 7) * 8;
    const float* Aload = A + (size_t)(m0 + arow) * (size_t)lda + akh;
    const int brow = t & 63;
    const int bk4  = (t >> 6) * 4;
    const float* Bload = B + (size_t)(n0 + brow) * (size_t)ldb + bk4;

    float acc[8][4];
#pragma unroll
    for (int i = 0; i < 8; i++)
#pragma unroll
        for (int j = 0; j < 4; j++) acc[i][j] = 0.f;

    for (int k0 = 0; k0 < K; k0 += 16) {
        __syncthreads();
        float4 a0 = *(const float4*)(Aload + k0);
        float4 a1 = *(const float4*)(Aload + k0 + 4);
        float4 b0 = *(const float4*)(Bload + k0);
        As[akh + 0][arow] = a0.x; As[akh + 1][arow] = a0.y;
        As[akh + 2][arow] = a0.z; As[akh + 3][arow] = a0.w;
        As[akh + 4][arow] = a1.x; As[akh + 5][arow] = a1.y;
        As[akh + 6][arow] = a1.z; As[akh + 7][arow] = a1.w;
        Bs[bk4 + 0][brow] = b0.x; Bs[bk4 + 1][brow] = b0.y;
        Bs[bk4 + 2][brow] = b0.z; Bs[bk4 + 3][brow] = b0.w;
        __syncthreads();
#pragma unroll
        for (int k = 0; k < 16; k++) {
            float4 a4 = *(const float4*)(&As[k][ty * 8]);
            float4 a5 = *(const float4*)(&As[k][ty * 8 + 4]);
            float4 b4 = *(const float4*)(&Bs[k][tx * 4]);
            float am[8] = {a4.x, a4.y, a4.z, a4.w, a5.x, a5.y, a5.z, a5.w};
            float bn[4] = {b4.x, b4.y, b4.z, b4.w};
#pragma unroll
            for (int i = 0; i < 8; i++)
#pragma unroll
                for (int j = 0; j < 4; j++) acc[i][j] += am[i] * bn[j];
        }
    }
#pragma unroll
    for (int i = 0; i < 8; i++) {
        float4 o = make_float4(acc[i][0], acc[i][1], acc[i][2], acc[i][3]);
        *(float4*)(C + (size_t)(m0 + ty * 8 + i) * (size_t)ldc + n0 + tx * 4) = o;
    }
}

// ---------------------------------------------------------------------------
// Causal depthwise conv (K=4) + bias + SiLU over proj[:, INTER:INTER+CONVD]
// ---------------------------------------------------------------------------
__global__ __launch_bounds__(256) void conv_silu_kernel(
    const float* __restrict__ proj, const float* __restrict__ conv_w,
    const float* __restrict__ conv_b, float* __restrict__ out)
{
    const int c = blockIdx.x * 256 + threadIdx.x;   // [0, 4352)
    const int s = blockIdx.y;                        // [0, 2048)
    const float4 w = *(const float4*)(conv_w + (size_t)c * 4);
    float acc = conv_b[c];
    const size_t base = (size_t)INTER + c;
    if (s >= 3) acc += proj[(size_t)(s - 3) * PROJ + base] * w.x;
    if (s >= 2) acc += proj[(size_t)(s - 2) * PROJ + base] * w.y;
    if (s >= 1) acc += proj[(size_t)(s - 1) * PROJ + base] * w.z;
    acc += proj[(size_t)s * PROJ + base] * w.w;
    float sig = 1.f / (1.f + __expf(-acc));
    out[(size_t)s * CONVD + c] = acc * sig;
}

// ---------------------------------------------------------------------------
// dt = softplus(proj[:, PROJ-NH:] + dt_bias)
// ---------------------------------------------------------------------------
__global__ __launch_bounds__(256) void dt_kernel(
    const float* __restrict__ proj, const float* __restrict__ dt_bias,
    float* __restrict__ dtg)
{
    const int i = blockIdx.x * 256 + threadIdx.x;    // 2048*64
    const int s = i >> 6, h = i & 63;
    float x = proj[(size_t)s * PROJ + (INTER + CONVD) + h] + dt_bias[h];
    float sp = (x > 20.f) ? x : log1pf(__expf(x));
    dtg[i] = sp;
}

// ---------------------------------------------------------------------------
// SSM core: one block per (head, chunk). 256 threads.
//  Yd[l,p]   = sum_{s<=l} exp(Acum[l]-Acum[s]) * Gm[l,s] * dt[s]*hid[s,p]
//  st[n,p]   = sum_l  B[l,n]*exp(Acum[end]-Acum[l]) * dt[l]*hid[l,p]
//  Yoff[l,p] = exp(Acum[l]) * sum_n C[l,n]*st[n,p]
//  y = Yd + Yoff + D[h]*hid[l,p]
// ---------------------------------------------------------------------------
__global__ __launch_bounds__(256) void ssm_kernel(
    const float* __restrict__ hBC,   // (2048, 4352) post conv+silu
    const float* __restrict__ dtg,   // (2048, 64)
    const float* __restrict__ Gm,    // (8, 256, 256)
    const float* __restrict__ A_log, // (64)
    const float* __restrict__ Dp,    // (64)
    float* __restrict__ y)           // (2048, 4096)
{
    const int h = blockIdx.x;
    const int c = blockIdx.y;
    const int t = threadIdx.x;

    __shared__ float sAcum[CS];          // 1 KB
    __shared__ float sdt[CS];            // 1 KB
    __shared__ float sH[64 * 64];        // 16 KB   Hdt staging tile [l][p]
    __shared__ float sStates[N_DIM * 64];// 32 KB   [n][p]
    __shared__ float sWaveSum[4];

    const float A = -__expf(A_log[h]);
    const int row0 = c * CS;
    const float* hid = hBC + (size_t)row0 * CONVD + h * P_DIM;
    const float* Bp  = hBC + (size_t)row0 * CONVD + INTER;
    const float* Cp  = hBC + (size_t)row0 * CONVD + INTER + N_DIM;
    const float* gm  = Gm + (size_t)c * CS * CS;

    // ---- inclusive cumsum of A*dt over the chunk ----
    float dtv = dtg[(size_t)(row0 + t) * NH + h];
    float v = A * dtv;
    for (int off = 1; off < 64; off <<= 1) {
        float u = __shfl_up(v, off, 64);
        if ((t & 63) >= off) v += u;
    }
    if ((t & 63) == 63) sWaveSum[t >> 6] = v;
    __syncthreads();
    float pre = 0.f;
    const int wv = t >> 6;
    for (int i = 0; i < 4; i++) if (i < wv) pre += sWaveSum[i];
    v += pre;
    sAcum[t] = v;
    sdt[t] = dtv;
    __syncthreads();
    const float AcumEnd = sAcum[CS - 1];

    // ---- phase A: states[n][p] ----
    const int p = t & 63;
    const int g = t >> 6;   // n block of 32
    float accS[32];
#pragma unroll
    for (int j = 0; j < 32; j++) accS[j] = 0.f;

    for (int lt = 0; lt < 4; lt++) {
        __syncthreads();
#pragma unroll
        for (int i = 0; i < 4; i++) {
            int row = (t >> 4) + i * 16;
            int col = (t & 15) * 4;
            float4 hv = *(const float4*)(hid + (size_t)(lt * 64 + row) * CONVD + col);
            float d = sdt[lt * 64 + row];
            hv.x *= d; hv.y *= d; hv.z *= d; hv.w *= d;
            *(float4*)(&sH[row * 64 + col]) = hv;
        }
        __syncthreads();
        for (int l = 0; l < 64; l++) {
            const int lg = lt * 64 + l;
            const float decay = __expf(AcumEnd - sAcum[lg]);
            const float hd = sH[l * 64 + p] * decay;
            const float4* Brow = (const float4*)(Bp + (size_t)lg * CONVD + g * 32);
#pragma unroll
            for (int j = 0; j < 8; j++) {
                float4 b4 = Brow[j];
                accS[j * 4 + 0] += b4.x * hd;
                accS[j * 4 + 1] += b4.y * hd;
                accS[j * 4 + 2] += b4.z * hd;
                accS[j * 4 + 3] += b4.w * hd;
            }
        }
    }
#pragma unroll
    for (int j = 0; j < 32; j++) sStates[(g * 32 + j) * 64 + p] = accS[j];
    // visibility of sStates guaranteed by the __syncthreads at top of phase-B tiles

    // ---- phase B: Yd (triangular) ----
    float acc[64];
#pragma unroll
    for (int i = 0; i < 64; i++) acc[i] = 0.f;
    const int l = t;
    const float myAcum = sAcum[l];

    for (int st = 0; st < 4; st++) {
        __syncthreads();
#pragma unroll
        for (int i = 0; i < 4; i++) {
            int row = (t >> 4) + i * 16;
            int col = (t & 15) * 4;
            float4 hv = *(const float4*)(hid + (size_t)(st * 64 + row) * CONVD + col);
            float d = sdt[st * 64 + row];
            hv.x *= d; hv.y *= d; hv.z *= d; hv.w *= d;
            *(float4*)(&sH[row * 64 + col]) = hv;
        }
        __syncthreads();
        if (st * 64 <= l) {
            const int smax = min(64, l - st * 64 + 1);
            for (int s = 0; s < smax; s++) {
                const int sg = st * 64 + s;
                const float wgt = __expf(myAcum - sAcum[sg]) * gm[(size_t)l * CS + sg];
                const float4* hrow = (const float4*)(&sH[s * 64]);
#pragma unroll
                for (int j = 0; j < 16; j++) {
                    float4 h4 = hrow[j];
                    acc[j * 4 + 0] += wgt * h4.x;
                    acc[j * 4 + 1] += wgt * h4.y;
                    acc[j * 4 + 2] += wgt * h4.z;
                    acc[j * 4 + 3] += wgt * h4.w;
                }
            }
        }
    }

    // ---- phase C: Yoff ----
    const float scl = __expf(myAcum);
    const float* Crow = Cp + (size_t)l * CONVD;
    for (int n = 0; n < N_DIM; n++) {
        const float cv = Crow[n] * scl;
        const float4* srow = (const float4*)(&sStates[n * 64]);
#pragma unroll
        for (int j = 0; j < 16; j++) {
            float4 s4 = srow[j];
            acc[j * 4 + 0] += cv * s4.x;
            acc[j * 4 + 1] += cv * s4.y;
            acc[j * 4 + 2] += cv * s4.z;
            acc[j * 4 + 3] += cv * s4.w;
        }
    }

    // ---- write y = acc + D[h]*hidden ----
    const float Dh = Dp[h];
    float* yrow = y + (size_t)(row0 + l) * INTER + h * P_DIM;
    const float* hrow2 = hid + (size_t)l * CONVD;
#pragma unroll
    for (int j = 0; j < 16; j++) {
        float4 hv = *(const float4*)(hrow2 + j * 4);
        float4 o;
        o.x = acc[j * 4 + 0] + Dh * hv.x;
        o.y = acc[j * 4 + 1] + Dh * hv.y;
        o.z = acc[j * 4 + 2] + Dh * hv.z;
        o.w = acc[j * 4 + 3] + Dh * hv.w;
        *(float4*)(yrow + j * 4) = o;
    }
}

// ---------------------------------------------------------------------------
// Gated RMSNorm: yn = norm_w * (y*silu(gate)) * rsqrt(mean((y*silu(gate))^2)+eps)
// ---------------------------------------------------------------------------
__global__ __launch_bounds__(256) void norm_kernel(
    const float* __restrict__ y, const float* __restrict__ proj,
    const float* __restrict__ norm_w, float* __restrict__ yn)
{
    const int s = blockIdx.x;
    const int t = threadIdx.x;
    __shared__ float sYf[INTER];   // 16 KB
    __shared__ float sW[4];
    const float* yrow = y + (size_t)s * INTER;
    const float* grow = proj + (size_t)s * PROJ;   // gate = first INTER cols
    float sum = 0.f;
    for (int j0 = 0; j0 < INTER; j0 += 1024) {
        int j = j0 + t * 4;
        float4 yv = *(const float4*)(yrow + j);
        float4 gv = *(const float4*)(grow + j);
        float4 f;
        f.x = yv.x * (gv.x / (1.f + __expf(-gv.x)));
        f.y = yv.y * (gv.y / (1.f + __expf(-gv.y)));
        f.z = yv.z * (gv.z / (1.f + __expf(-gv.z)));
        f.w = yv.w * (gv.w / (1.f + __expf(-gv.w)));
        sum += f.x * f.x + f.y * f.y + f.z * f.z + f.w * f.w;
        *(float4*)(&sYf[j]) = f;
    }
    for (int off = 32; off > 0; off >>= 1) sum += __shfl_down(sum, off, 64);
    if ((t & 63) == 0) sW[t >> 6] = sum;
    __syncthreads();
    const float var = (sW[0] + sW[1] + sW[2] + sW[3]) * (1.f / (float)INTER);
    const float rs = rsqrtf(var + EPS);
    for (int j0 = 0; j0 < INTER; j0 += 1024) {
        int j = j0 + t * 4;
        float4 f = *(const float4*)(&sYf[j]);
        float4 w = *(const float4*)(norm_w + j);
        float4 o = make_float4(f.x * w.x * rs, f.y * w.y * rs,
                               f.z * w.z * rs, f.w * w.w * rs);
        *(float4*)(yn + (size_t)s * INTER + j) = o;
    }
}

// ---------------------------------------------------------------------------
extern "C" void kernel_launch(void* const* d_in, const int* in_sizes, int n_in,
                              void* d_out, int out_size, void* d_ws, size_t ws_size,
                              hipStream_t stream)
{
    const float* X       = (const float*)d_in[0];
    // d_in[1] = mask (unused by reference)
    const float* W_in    = (const float*)d_in[2];
    const float* conv_w  = (const float*)d_in[3];
    const float* conv_b  = (const float*)d_in[4];
    const float* dt_bias = (const float*)d_in[5];
    const float* A_log   = (const float*)d_in[6];
    const float* Dp      = (const float*)d_in[7];
    const float* norm_w  = (const float*)d_in[8];
    const float* W_out   = (const float*)d_in[9];
    float* out = (float*)d_out;
    float* ws  = (float*)d_ws;

    float* proj = ws + OFF_PROJ;
    float* hbc  = ws + OFF_HBC;
    float* dtg  = ws + OFF_DT;
    float* gm   = ws + OFF_GM;
    float* yv   = ws + OFF_Y;
    float* yn   = ws + OFF_YN;

    // 1) proj = X @ W_in^T   (2048 x 8512, K=2048)
    gemm_nt<<<dim3(PROJ / 64, S_LEN / 128, 1), 256, 0, stream>>>(
        X, E_DIM, 0LL, W_in, E_DIM, 0LL, proj, PROJ, 0LL, E_DIM);

    // 2) conv + silu
    conv_silu_kernel<<<dim3(CONVD / 256, S_LEN), 256, 0, stream>>>(
        proj, conv_w, conv_b, hbc);

    // 3) dt
    dt_kernel<<<dim3((S_LEN * NH) / 256), 256, 0, stream>>>(proj, dt_bias, dtg);

    // 4) Gm[c] = Cm_c @ Bm_c^T  (256 x 256, K=128, batch 8)
    gemm_nt<<<dim3(CS / 64, CS / 128, NCHUNK), 256, 0, stream>>>(
        hbc + INTER + N_DIM, CONVD, (long long)CS * CONVD,
        hbc + INTER,         CONVD, (long long)CS * CONVD,
        gm, CS, (long long)CS * CS, N_DIM);

    // 5) SSM core
    ssm_kernel<<<dim3(NH, NCHUNK), 256, 0, stream>>>(hbc, dtg, gm, A_log, Dp, yv);

    // 6) gated RMSNorm
    norm_kernel<<<dim3(S_LEN), 256, 0, stream>>>(yv, proj, norm_w, yn);

    // 7) out = yn @ W_out^T  (2048 x 2048, K=4096)
    gemm_nt<<<dim3(E_DIM / 64, S_LEN / 128, 1), 256, 0, stream>>>(
        yn, INTER, 0LL, W_out, INTER, 0LL, out, E_DIM, 0LL, INTER);
}

// Round 2
// 692.717 us; speedup vs baseline: 2.8787x; 2.8787x over previous
//
#include <hip/hip_runtime.h>
#include <math.h>

// Problem constants
#define S_LEN   2048
#define E_DIM   2048
#define NH      64
#define P_DIM   64
#define N_DIM   128
#define CS      256
#define NCHUNK  8
#define INTER   4096
#define CONVD   4352
#define PROJ    8512
#define GEMM1N  8448       // INTER + CONVD = 66*128 exactly
#define EPS     1e-5f

// Workspace layout (float units)
#define OFF_PROJBF 0ull                        // bf16 2048*8448 = 8,650,752 fl
#define OFF_HBC    8650752ull                  // fp32 2048*4352 = 8,912,896 fl
#define OFF_DTG    17563648ull                 // fp32 2048*64
#define OFF_DTPART 17694720ull                 // fp32 8*2048*64
#define OFF_GM     18743296ull                 // fp32 8*256*256
#define OFF_YV     19267584ull                 // fp32 2048*4096
#define OFF_R      27656192ull                 // shared region, 10,747,904 fl
// region R:  Xbf = R+0 (2,097,152 fl) | Winbf = R+2,097,152 (8,650,752 fl)
// aliased:   ynbf = R+0 (4,194,304 fl) | Woutbf = R+4,194,304 (4,194,304 fl)
// ynbf/Woutbf written only AFTER GEMM1 (last reader of Xbf/Winbf). Total 153.6 MB.

typedef __bf16 bf16x8 __attribute__((ext_vector_type(8)));
typedef float  f32x4  __attribute__((ext_vector_type(4)));

__device__ __forceinline__ float bf2f(unsigned short u) {
    union { unsigned int i; float f; } v; v.i = ((unsigned int)u) << 16; return v.f;
}
__device__ __forceinline__ unsigned short f2bf(float f) {
    union { float f; unsigned int i; } v; v.f = f;
    unsigned int r = v.i + 0x7FFFu + ((v.i >> 16) & 1u);
    return (unsigned short)(r >> 16);
}
__device__ __forceinline__ void gl_lds16(const void* g, void* l) {
    __builtin_amdgcn_global_load_lds(
        (const __attribute__((address_space(1))) void*)g,
        (__attribute__((address_space(3))) void*)l, 16, 0, 0);
}

// ---------------------------------------------------------------------------
// fp32 -> bf16 cast, 8 elems/thread, exact grids (n % 2048 == 0)
// ---------------------------------------------------------------------------
__global__ __launch_bounds__(256) void cast_bf16_kernel(
    const float* __restrict__ in, unsigned short* __restrict__ out)
{
    size_t i = ((size_t)blockIdx.x * 256 + threadIdx.x) * 8;
    float4 a = *(const float4*)(in + i);
    float4 b = *(const float4*)(in + i + 4);
    uint4 o;
    o.x = (unsigned int)f2bf(a.x) | ((unsigned int)f2bf(a.y) << 16);
    o.y = (unsigned int)f2bf(a.z) | ((unsigned int)f2bf(a.w) << 16);
    o.z = (unsigned int)f2bf(b.x) | ((unsigned int)f2bf(b.y) << 16);
    o.w = (unsigned int)f2bf(b.z) | ((unsigned int)f2bf(b.w) << 16);
    *(uint4*)(out + i) = o;
}

// ---------------------------------------------------------------------------
// bf16 MFMA NT GEMM (m97 structure): C[m][n] = sum_k A[m][k]*B[n][k]
// 128x128 tile, BK=32, 256 threads (4 waves, each 64x64 via 4x4 MFMA grid),
// global_load_lds width-16 staging. Output fp32 (Cf) or bf16 (Cb).
// M%128==0, N%128==0, K%32==0.
// ---------------------------------------------------------------------------
__global__ __launch_bounds__(256) void gemm_bt_mfma(
    const unsigned short* __restrict__ A, int lda,
    const unsigned short* __restrict__ B, int ldb,
    float* __restrict__ Cf, unsigned short* __restrict__ Cb, int ldc, int K)
{
    __shared__ unsigned short As[128 * 32];
    __shared__ unsigned short Bs[128 * 32];
    const int t    = threadIdx.x;
    const int m0   = blockIdx.y * 128;
    const int n0   = blockIdx.x * 128;
    const int w    = t >> 6;
    const int lane = t & 63;
    const int lo   = lane & 15;
    const int q    = lane >> 4;
    const int wm   = (w & 1) * 64;
    const int wn   = (w >> 1) * 64;

    // staging: thread t covers row t>>2 (of each 64-row half), 8 bf16 at (t&3)*8
    const int sr = t >> 2;
    const int sc = (t & 3) * 8;
    const unsigned short* Ag  = A + (size_t)(m0 + sr) * lda + sc;
    const unsigned short* Ag2 = Ag + (size_t)64 * lda;
    const unsigned short* Bg  = B + (size_t)(n0 + sr) * ldb + sc;
    const unsigned short* Bg2 = Bg + (size_t)64 * ldb;
    unsigned short* Asl  = &As[t * 8];          // byte addr = wave_base + lane*16
    unsigned short* Asl2 = Asl + 64 * 32;
    unsigned short* Bsl  = &Bs[t * 8];
    unsigned short* Bsl2 = Bsl + 64 * 32;

    f32x4 acc[4][4];
#pragma unroll
    for (int i = 0; i < 4; i++)
#pragma unroll
        for (int j = 0; j < 4; j++) acc[i][j] = (f32x4){0.f, 0.f, 0.f, 0.f};

    for (int k0 = 0; k0 < K; k0 += 32) {
        __syncthreads();
        gl_lds16(Ag + k0, Asl);
        gl_lds16(Ag2 + k0, Asl2);
        gl_lds16(Bg + k0, Bsl);
        gl_lds16(Bg2 + k0, Bsl2);
        __syncthreads();   // compiler emits vmcnt(0) drain -> LDS data visible
        bf16x8 af[4], bfr[4];
#pragma unroll
        for (int i = 0; i < 4; i++)
            af[i] = *(const bf16x8*)(&As[(wm + i * 16 + lo) * 32 + q * 8]);
#pragma unroll
        for (int i = 0; i < 4; i++)
            bfr[i] = *(const bf16x8*)(&Bs[(wn + i * 16 + lo) * 32 + q * 8]);
#pragma unroll
        for (int mi = 0; mi < 4; mi++)
#pragma unroll
            for (int ni = 0; ni < 4; ni++)
                acc[mi][ni] = __builtin_amdgcn_mfma_f32_16x16x32_bf16(
                    af[mi], bfr[ni], acc[mi][ni], 0, 0, 0);
    }

    // Epilogue. C/D layout: col = lane&15, row = (lane>>4)*4 + reg  [m89]
    if (Cb) {
#pragma unroll
        for (int mi = 0; mi < 4; mi++) {
            const int r = m0 + wm + mi * 16 + q * 4;
#pragma unroll
            for (int ni = 0; ni < 4; ni++) {
                const int cc = n0 + wn + ni * 16 + lo;
#pragma unroll
                for (int rr = 0; rr < 4; rr++)
                    Cb[(size_t)(r + rr) * ldc + cc] = f2bf(acc[mi][ni][rr]);
            }
        }
    } else {
#pragma unroll
        for (int mi = 0; mi < 4; mi++) {
            const int r = m0 + wm + mi * 16 + q * 4;
#pragma unroll
            for (int ni = 0; ni < 4; ni++) {
                const int cc = n0 + wn + ni * 16 + lo;
#pragma unroll
                for (int rr = 0; rr < 4; rr++)
                    Cf[(size_t)(r + rr) * ldc + cc] = acc[mi][ni][rr];
            }
        }
    }
}

// ---------------------------------------------------------------------------
// fp32 NT GEMM (round-1 kernel, kept for Gm and the dt split-K slices).
// blockIdx.z shifts A/B/C by sA/sB/sC — used as batch OR K-slice stride.
// ---------------------------------------------------------------------------
__global__ __launch_bounds__(256) void gemm_nt(
    const float* __restrict__ A, int lda, long long sA,
    const float* __restrict__ B, int ldb, long long sB,
    float* __restrict__ C, int ldc, long long sC, int K)
{
    A += (long long)blockIdx.z * sA;
    B += (long long)blockIdx.z * sB;
    C += (long long)blockIdx.z * sC;
    const int t  = threadIdx.x;
    const int m0 = blockIdx.y * 128;
    const int n0 = blockIdx.x * 64;
    __shared__ float As[16][132];
    __shared__ float Bs[16][68];
    const int tx = t & 15;
    const int ty = t >> 4;

    const int arow = t & 127;
    const int akh  = (t >> 7) * 8;
    const float* Aload = A + (size_t)(m0 + arow) * (size_t)lda + akh;
    const int brow = t & 63;
    const int bk4  = (t >> 6) * 4;
    const float* Bload = B + (size_t)(n0 + brow) * (size_t)ldb + bk4;

    float acc[8][4];
#pragma unroll
    for (int i = 0; i < 8; i++)
#pragma unroll
        for (int j = 0; j < 4; j++) acc[i][j] = 0.f;

    for (int k0 = 0; k0 < K; k0 += 16) {
        __syncthreads();
        float4 a0 = *(const float4*)(Aload + k0);
        float4 a1 = *(const float4*)(Aload + k0 + 4);
        float4 b0 = *(const float4*)(Bload + k0);
        As[akh + 0][arow] = a0.x; As[akh + 1][arow] = a0.y;
        As[akh + 2][arow] = a0.z; As[akh + 3][arow] = a0.w;
        As[akh + 4][arow] = a1.x; As[akh + 5][arow] = a1.y;
        As[akh + 6][arow] = a1.z; As[akh + 7][arow] = a1.w;
        Bs[bk4 + 0][brow] = b0.x; Bs[bk4 + 1][brow] = b0.y;
        Bs[bk4 + 2][brow] = b0.z; Bs[bk4 + 3][brow] = b0.w;
        __syncthreads();
#pragma unroll
        for (int k = 0; k < 16; k++) {
            float4 a4 = *(const float4*)(&As[k][ty * 8]);
            float4 a5 = *(const float4*)(&As[k][ty * 8 + 4]);
            float4 b4 = *(const float4*)(&Bs[k][tx * 4]);
            float am[8] = {a4.x, a4.y, a4.z, a4.w, a5.x, a5.y, a5.z, a5.w};
            float bn[4] = {b4.x, b4.y, b4.z, b4.w};
#pragma unroll
            for (int i = 0; i < 8; i++)
#pragma unroll
                for (int j = 0; j < 4; j++) acc[i][j] += am[i] * bn[j];
        }
    }
#pragma unroll
    for (int i = 0; i < 8; i++) {
        float4 o = make_float4(acc[i][0], acc[i][1], acc[i][2], acc[i][3]);
        *(float4*)(C + (size_t)(m0 + ty * 8 + i) * (size_t)ldc + n0 + tx * 4) = o;
    }
}

// ---------------------------------------------------------------------------
// dt reduce: dtg = softplus(sum_z part[z] + dt_bias)
// ---------------------------------------------------------------------------
__global__ __launch_bounds__(256) void dt_reduce_kernel(
    const float* __restrict__ part, const float* __restrict__ dt_bias,
    float* __restrict__ dtg)
{
    const int i = blockIdx.x * 256 + threadIdx.x;   // 2048*64
    float x = dt_bias[i & 63];
#pragma unroll
    for (int z = 0; z < 8; z++) x += part[(size_t)z * 131072 + i];
    dtg[i] = (x > 20.f) ? x : log1pf(__expf(x));
}

// ---------------------------------------------------------------------------
// Causal depthwise conv (K=4) + bias + SiLU, reads bf16 proj cols [4096,8448)
// ---------------------------------------------------------------------------
__global__ __launch_bounds__(256) void conv_silu_kernel(
    const unsigned short* __restrict__ projbf, const float* __restrict__ conv_w,
    const float* __restrict__ conv_b, float* __restrict__ out)
{
    const int c = blockIdx.x * 256 + threadIdx.x;   // [0, 4352)
    const int s = blockIdx.y;
    const float4 w = *(const float4*)(conv_w + (size_t)c * 4);
    float acc = conv_b[c];
    const size_t base = 4096 + (size_t)c;
    if (s >= 3) acc += bf2f(projbf[(size_t)(s - 3) * GEMM1N + base]) * w.x;
    if (s >= 2) acc += bf2f(projbf[(size_t)(s - 2) * GEMM1N + base]) * w.y;
    if (s >= 1) acc += bf2f(projbf[(size_t)(s - 1) * GEMM1N + base]) * w.z;
    acc += bf2f(projbf[(size_t)s * GEMM1N + base]) * w.w;
    float sig = 1.f / (1.f + __expf(-acc));
    out[(size_t)s * CONVD + c] = acc * sig;
}

// ---------------------------------------------------------------------------
// SSM core (unchanged from round 1): one block per (head, chunk)
// ---------------------------------------------------------------------------
__global__ __launch_bounds__(256) void ssm_kernel(
    const float* __restrict__ hBC, const float* __restrict__ dtg,
    const float* __restrict__ Gm, const float* __restrict__ A_log,
    const float* __restrict__ Dp, float* __restrict__ y)
{
    const int h = blockIdx.x;
    const int c = blockIdx.y;
    const int t = threadIdx.x;

    __shared__ float sAcum[CS];
    __shared__ float sdt[CS];
    __shared__ float sH[64 * 64];
    __shared__ float sStates[N_DIM * 64];
    __shared__ float sWaveSum[4];

    const float A = -__expf(A_log[h]);
    const int row0 = c * CS;
    const float* hid = hBC + (size_t)row0 * CONVD + h * P_DIM;
    const float* Bp  = hBC + (size_t)row0 * CONVD + INTER;
    const float* Cp  = hBC + (size_t)row0 * CONVD + INTER + N_DIM;
    const float* gm  = Gm + (size_t)c * CS * CS;

    float dtv = dtg[(size_t)(row0 + t) * NH + h];
    float v = A * dtv;
    for (int off = 1; off < 64; off <<= 1) {
        float u = __shfl_up(v, off, 64);
        if ((t & 63) >= off) v += u;
    }
    if ((t & 63) == 63) sWaveSum[t >> 6] = v;
    __syncthreads();
    float pre = 0.f;
    const int wv = t >> 6;
    for (int i = 0; i < 4; i++) if (i < wv) pre += sWaveSum[i];
    v += pre;
    sAcum[t] = v;
    sdt[t] = dtv;
    __syncthreads();
    const float AcumEnd = sAcum[CS - 1];

    const int p = t & 63;
    const int g = t >> 6;
    float accS[32];
#pragma unroll
    for (int j = 0; j < 32; j++) accS[j] = 0.f;

    for (int lt = 0; lt < 4; lt++) {
        __syncthreads();
#pragma unroll
        for (int i = 0; i < 4; i++) {
            int row = (t >> 4) + i * 16;
            int col = (t & 15) * 4;
            float4 hv = *(const float4*)(hid + (size_t)(lt * 64 + row) * CONVD + col);
            float d = sdt[lt * 64 + row];
            hv.x *= d; hv.y *= d; hv.z *= d; hv.w *= d;
            *(float4*)(&sH[row * 64 + col]) = hv;
        }
        __syncthreads();
        for (int l = 0; l < 64; l++) {
            const int lg = lt * 64 + l;
            const float decay = __expf(AcumEnd - sAcum[lg]);
            const float hd = sH[l * 64 + p] * decay;
            const float4* Brow = (const float4*)(Bp + (size_t)lg * CONVD + g * 32);
#pragma unroll
            for (int j = 0; j < 8; j++) {
                float4 b4 = Brow[j];
                accS[j * 4 + 0] += b4.x * hd;
                accS[j * 4 + 1] += b4.y * hd;
                accS[j * 4 + 2] += b4.z * hd;
                accS[j * 4 + 3] += b4.w * hd;
            }
        }
    }
#pragma unroll
    for (int j = 0; j < 32; j++) sStates[(g * 32 + j) * 64 + p] = accS[j];

    float acc[64];
#pragma unroll
    for (int i = 0; i < 64; i++) acc[i] = 0.f;
    const int l = t;
    const float myAcum = sAcum[l];

    for (int st = 0; st < 4; st++) {
        __syncthreads();
#pragma unroll
        for (int i = 0; i < 4; i++) {
            int row = (t >> 4) + i * 16;
            int col = (t & 15) * 4;
            float4 hv = *(const float4*)(hid + (size_t)(st * 64 + row) * CONVD + col);
            float d = sdt[st * 64 + row];
            hv.x *= d; hv.y *= d; hv.z *= d; hv.w *= d;
            *(float4*)(&sH[row * 64 + col]) = hv;
        }
        __syncthreads();
        if (st * 64 <= l) {
            const int smax = min(64, l - st * 64 + 1);
            for (int s = 0; s < smax; s++) {
                const int sg = st * 64 + s;
                const float wgt = __expf(myAcum - sAcum[sg]) * gm[(size_t)l * CS + sg];
                const float4* hrow = (const float4*)(&sH[s * 64]);
#pragma unroll
                for (int j = 0; j < 16; j++) {
                    float4 h4 = hrow[j];
                    acc[j * 4 + 0] += wgt * h4.x;
                    acc[j * 4 + 1] += wgt * h4.y;
                    acc[j * 4 + 2] += wgt * h4.z;
                    acc[j * 4 + 3] += wgt * h4.w;
                }
            }
        }
    }

    const float scl = __expf(myAcum);
    const float* Crow = Cp + (size_t)l * CONVD;
    for (int n = 0; n < N_DIM; n++) {
        const float cv = Crow[n] * scl;
        const float4* srow = (const float4*)(&sStates[n * 64]);
#pragma unroll
        for (int j = 0; j < 16; j++) {
            float4 s4 = srow[j];
            acc[j * 4 + 0] += cv * s4.x;
            acc[j * 4 + 1] += cv * s4.y;
            acc[j * 4 + 2] += cv * s4.z;
            acc[j * 4 + 3] += cv * s4.w;
        }
    }

    const float Dh = Dp[h];
    float* yrow = y + (size_t)(row0 + l) * INTER + h * P_DIM;
    const float* hrow2 = hid + (size_t)l * CONVD;
#pragma unroll
    for (int j = 0; j < 16; j++) {
        float4 hv = *(const float4*)(hrow2 + j * 4);
        float4 o;
        o.x = acc[j * 4 + 0] + Dh * hv.x;
        o.y = acc[j * 4 + 1] + Dh * hv.y;
        o.z = acc[j * 4 + 2] + Dh * hv.z;
        o.w = acc[j * 4 + 3] + Dh * hv.w;
        *(float4*)(yrow + j * 4) = o;
    }
}

// ---------------------------------------------------------------------------
// Gated RMSNorm: reads yv fp32 + bf16 gate (proj cols [0,4096)), writes bf16 yn
// ---------------------------------------------------------------------------
__global__ __launch_bounds__(256) void norm_kernel(
    const float* __restrict__ y, const unsigned short* __restrict__ projbf,
    const float* __restrict__ norm_w, unsigned short* __restrict__ yn)
{
    const int s = blockIdx.x;
    const int t = threadIdx.x;
    __shared__ float sYf[INTER];
    __shared__ float sW[4];
    const float* yrow = y + (size_t)s * INTER;
    const unsigned short* grow = projbf + (size_t)s * GEMM1N;
    float sum = 0.f;
    for (int j0 = 0; j0 < INTER; j0 += 2048) {
        int j = j0 + t * 8;
        float4 y0 = *(const float4*)(yrow + j);
        float4 y1 = *(const float4*)(yrow + j + 4);
        uint4 gp = *(const uint4*)(grow + j);
        float gv[8] = {
            bf2f((unsigned short)(gp.x & 0xffff)), bf2f((unsigned short)(gp.x >> 16)),
            bf2f((unsigned short)(gp.y & 0xffff)), bf2f((unsigned short)(gp.y >> 16)),
            bf2f((unsigned short)(gp.z & 0xffff)), bf2f((unsigned short)(gp.z >> 16)),
            bf2f((unsigned short)(gp.w & 0xffff)), bf2f((unsigned short)(gp.w >> 16))};
        float yv8[8] = {y0.x, y0.y, y0.z, y0.w, y1.x, y1.y, y1.z, y1.w};
#pragma unroll
        for (int e = 0; e < 8; e++) {
            float f = yv8[e] * (gv[e] / (1.f + __expf(-gv[e])));
            sum += f * f;
            sYf[j + e] = f;
        }
    }
    for (int off = 32; off > 0; off >>= 1) sum += __shfl_down(sum, off, 64);
    if ((t & 63) == 0) sW[t >> 6] = sum;
    __syncthreads();
    const float var = (sW[0] + sW[1] + sW[2] + sW[3]) * (1.f / (float)INTER);
    const float rs = rsqrtf(var + EPS);
    for (int j0 = 0; j0 < INTER; j0 += 2048) {
        int j = j0 + t * 8;
        float4 w0 = *(const float4*)(norm_w + j);
        float4 w1 = *(const float4*)(norm_w + j + 4);
        float wv[8] = {w0.x, w0.y, w0.z, w0.w, w1.x, w1.y, w1.z, w1.w};
        unsigned short o[8];
#pragma unroll
        for (int e = 0; e < 8; e++) o[e] = f2bf(sYf[j + e] * wv[e] * rs);
        uint4 ov;
        ov.x = (unsigned int)o[0] | ((unsigned int)o[1] << 16);
        ov.y = (unsigned int)o[2] | ((unsigned int)o[3] << 16);
        ov.z = (unsigned int)o[4] | ((unsigned int)o[5] << 16);
        ov.w = (unsigned int)o[6] | ((unsigned int)o[7] << 16);
        *(uint4*)(yn + (size_t)s * INTER + j) = ov;
    }
}

// ---------------------------------------------------------------------------
extern "C" void kernel_launch(void* const* d_in, const int* in_sizes, int n_in,
                              void* d_out, int out_size, void* d_ws, size_t ws_size,
                              hipStream_t stream)
{
    const float* X       = (const float*)d_in[0];
    const float* W_in    = (const float*)d_in[2];
    const float* conv_w  = (const float*)d_in[3];
    const float* conv_b  = (const float*)d_in[4];
    const float* dt_bias = (const float*)d_in[5];
    const float* A_log   = (const float*)d_in[6];
    const float* Dp      = (const float*)d_in[7];
    const float* norm_w  = (const float*)d_in[8];
    const float* W_out   = (const float*)d_in[9];
    float* out = (float*)d_out;
    float* ws  = (float*)d_ws;

    unsigned short* projbf = (unsigned short*)(ws + OFF_PROJBF);
    float* hbc     = ws + OFF_HBC;
    float* dtg     = ws + OFF_DTG;
    float* dtpart  = ws + OFF_DTPART;
    float* gm      = ws + OFF_GM;
    float* yv      = ws + OFF_YV;
    unsigned short* Xbf    = (unsigned short*)(ws + OFF_R);
    unsigned short* Winbf  = (unsigned short*)(ws + OFF_R + 2097152);
    unsigned short* ynbf   = (unsigned short*)(ws + OFF_R);           // aliases Xbf
    unsigned short* Woutbf = (unsigned short*)(ws + OFF_R + 4194304); // aliases Winbf

    // casts for GEMM1
    cast_bf16_kernel<<<2048, 256, 0, stream>>>(X, Xbf);
    cast_bf16_kernel<<<8448, 256, 0, stream>>>(W_in, Winbf);   // first 8448 rows

    // GEMM1: proj[:, 0:8448] bf16 MFMA -> bf16 out
    gemm_bt_mfma<<<dim3(GEMM1N / 128, S_LEN / 128), 256, 0, stream>>>(
        Xbf, E_DIM, Winbf, E_DIM, nullptr, projbf, GEMM1N, E_DIM);

    // W_out cast (after GEMM1: Woutbf aliases Winbf region)
    cast_bf16_kernel<<<4096, 256, 0, stream>>>(W_out, Woutbf);

    // dt columns in fp32: split-K via blockIdx.z as K-slice (8 slices of 256)
    gemm_nt<<<dim3(1, 16, 8), 256, 0, stream>>>(
        X, E_DIM, 256LL, W_in + (size_t)GEMM1N * E_DIM, E_DIM, 256LL,
        dtpart, NH, 131072LL, 256);
    dt_reduce_kernel<<<512, 256, 0, stream>>>(dtpart, dt_bias, dtg);

    // conv + silu
    conv_silu_kernel<<<dim3(CONVD / 256, S_LEN), 256, 0, stream>>>(
        projbf, conv_w, conv_b, hbc);

    // Gm[c] = Cm_c @ Bm_c^T (fp32, head-shared)
    gemm_nt<<<dim3(CS / 64, CS / 128, NCHUNK), 256, 0, stream>>>(
        hbc + INTER + N_DIM, CONVD, (long long)CS * CONVD,
        hbc + INTER,         CONVD, (long long)CS * CONVD,
        gm, CS, (long long)CS * CS, N_DIM);

    // SSM core
    ssm_kernel<<<dim3(NH, NCHUNK), 256, 0, stream>>>(hbc, dtg, gm, A_log, Dp, yv);

    // gated RMSNorm -> bf16 (ynbf aliases Xbf region; safe, GEMM1 done)
    norm_kernel<<<dim3(S_LEN), 256, 0, stream>>>(yv, projbf, norm_w, ynbf);

    // GEMM2: out = yn @ W_out^T, fp32 out
    gemm_bt_mfma<<<dim3(E_DIM / 128, S_LEN / 128), 256, 0, stream>>>(
        ynbf, INTER, Woutbf, INTER, out, nullptr, E_DIM, INTER);
}

// Round 3
// 528.279 us; speedup vs baseline: 3.7747x; 1.3113x over previous
//
#include <hip/hip_runtime.h>
#include <math.h>

// Problem constants
#define S_LEN   2048
#define E_DIM   2048
#define NH      64
#define P_DIM   64
#define N_DIM   128
#define CS      256
#define NCHUNK  8
#define INTER   4096
#define CONVD   4352
#define PROJ    8512
#define GEMM1N  8448       // INTER + CONVD = 66*128 exactly
#define EPS     1e-5f

// Workspace layout (float units)
#define OFF_PROJBF 0ull                        // bf16 2048*8448 = 8,650,752 fl
#define OFF_HBC    8650752ull                  // fp32 2048*4352 = 8,912,896 fl
#define OFF_DTG    17563648ull                 // fp32 2048*64
#define OFF_DTPART 17694720ull                 // fp32 8*2048*64
#define OFF_GM     18743296ull                 // fp32 8*256*256
#define OFF_YV     19267584ull                 // fp32 2048*4096
#define OFF_R      27656192ull                 // shared region
// region R:  Xbf = R+0 | Winbf = R+2,097,152 ; aliased after GEMM1:
// ynbf = R+0 | Woutbf = R+4,194,304.

typedef __bf16 bf16x8 __attribute__((ext_vector_type(8)));
typedef float  f32x4  __attribute__((ext_vector_type(4)));

__device__ __forceinline__ float bf2f(unsigned short u) {
    union { unsigned int i; float f; } v; v.i = ((unsigned int)u) << 16; return v.f;
}
__device__ __forceinline__ unsigned short f2bf(float f) {
    union { float f; unsigned int i; } v; v.f = f;
    unsigned int r = v.i + 0x7FFFu + ((v.i >> 16) & 1u);
    return (unsigned short)(r >> 16);
}
__device__ __forceinline__ void gl_lds16(const void* g, void* l) {
    __builtin_amdgcn_global_load_lds(
        (const __attribute__((address_space(1))) void*)g,
        (__attribute__((address_space(3))) void*)l, 16, 0, 0);
}

// ---------------------------------------------------------------------------
// fp32 -> bf16 cast, 8 elems/thread
// ---------------------------------------------------------------------------
__global__ __launch_bounds__(256) void cast_bf16_kernel(
    const float* __restrict__ in, unsigned short* __restrict__ out)
{
    size_t i = ((size_t)blockIdx.x * 256 + threadIdx.x) * 8;
    float4 a = *(const float4*)(in + i);
    float4 b = *(const float4*)(in + i + 4);
    uint4 o;
    o.x = (unsigned int)f2bf(a.x) | ((unsigned int)f2bf(a.y) << 16);
    o.y = (unsigned int)f2bf(a.z) | ((unsigned int)f2bf(a.w) << 16);
    o.z = (unsigned int)f2bf(b.x) | ((unsigned int)f2bf(b.y) << 16);
    o.w = (unsigned int)f2bf(b.z) | ((unsigned int)f2bf(b.w) << 16);
    *(uint4*)(out + i) = o;
}

// ---------------------------------------------------------------------------
// bf16 MFMA NT GEMM (m97 structure), unchanged from round 2
// ---------------------------------------------------------------------------
__global__ __launch_bounds__(256) void gemm_bt_mfma(
    const unsigned short* __restrict__ A, int lda,
    const unsigned short* __restrict__ B, int ldb,
    float* __restrict__ Cf, unsigned short* __restrict__ Cb, int ldc, int K)
{
    __shared__ unsigned short As[128 * 32];
    __shared__ unsigned short Bs[128 * 32];
    const int t    = threadIdx.x;
    const int m0   = blockIdx.y * 128;
    const int n0   = blockIdx.x * 128;
    const int w    = t >> 6;
    const int lane = t & 63;
    const int lo   = lane & 15;
    const int q    = lane >> 4;
    const int wm   = (w & 1) * 64;
    const int wn   = (w >> 1) * 64;

    const int sr = t >> 2;
    const int sc = (t & 3) * 8;
    const unsigned short* Ag  = A + (size_t)(m0 + sr) * lda + sc;
    const unsigned short* Ag2 = Ag + (size_t)64 * lda;
    const unsigned short* Bg  = B + (size_t)(n0 + sr) * ldb + sc;
    const unsigned short* Bg2 = Bg + (size_t)64 * ldb;
    unsigned short* Asl  = &As[t * 8];
    unsigned short* Asl2 = Asl + 64 * 32;
    unsigned short* Bsl  = &Bs[t * 8];
    unsigned short* Bsl2 = Bsl + 64 * 32;

    f32x4 acc[4][4];
#pragma unroll
    for (int i = 0; i < 4; i++)
#pragma unroll
        for (int j = 0; j < 4; j++) acc[i][j] = (f32x4){0.f, 0.f, 0.f, 0.f};

    for (int k0 = 0; k0 < K; k0 += 32) {
        __syncthreads();
        gl_lds16(Ag + k0, Asl);
        gl_lds16(Ag2 + k0, Asl2);
        gl_lds16(Bg + k0, Bsl);
        gl_lds16(Bg2 + k0, Bsl2);
        __syncthreads();
        bf16x8 af[4], bfr[4];
#pragma unroll
        for (int i = 0; i < 4; i++)
            af[i] = *(const bf16x8*)(&As[(wm + i * 16 + lo) * 32 + q * 8]);
#pragma unroll
        for (int i = 0; i < 4; i++)
            bfr[i] = *(const bf16x8*)(&Bs[(wn + i * 16 + lo) * 32 + q * 8]);
#pragma unroll
        for (int mi = 0; mi < 4; mi++)
#pragma unroll
            for (int ni = 0; ni < 4; ni++)
                acc[mi][ni] = __builtin_amdgcn_mfma_f32_16x16x32_bf16(
                    af[mi], bfr[ni], acc[mi][ni], 0, 0, 0);
    }

    if (Cb) {
#pragma unroll
        for (int mi = 0; mi < 4; mi++) {
            const int r = m0 + wm + mi * 16 + q * 4;
#pragma unroll
            for (int ni = 0; ni < 4; ni++) {
                const int cc = n0 + wn + ni * 16 + lo;
#pragma unroll
                for (int rr = 0; rr < 4; rr++)
                    Cb[(size_t)(r + rr) * ldc + cc] = f2bf(acc[mi][ni][rr]);
            }
        }
    } else {
#pragma unroll
        for (int mi = 0; mi < 4; mi++) {
            const int r = m0 + wm + mi * 16 + q * 4;
#pragma unroll
            for (int ni = 0; ni < 4; ni++) {
                const int cc = n0 + wn + ni * 16 + lo;
#pragma unroll
                for (int rr = 0; rr < 4; rr++)
                    Cf[(size_t)(r + rr) * ldc + cc] = acc[mi][ni][rr];
            }
        }
    }
}

// ---------------------------------------------------------------------------
// fp32 NT GEMM (for Gm and dt split-K)
// ---------------------------------------------------------------------------
__global__ __launch_bounds__(256) void gemm_nt(
    const float* __restrict__ A, int lda, long long sA,
    const float* __restrict__ B, int ldb, long long sB,
    float* __restrict__ C, int ldc, long long sC, int K)
{
    A += (long long)blockIdx.z * sA;
    B += (long long)blockIdx.z * sB;
    C += (long long)blockIdx.z * sC;
    const int t  = threadIdx.x;
    const int m0 = blockIdx.y * 128;
    const int n0 = blockIdx.x * 64;
    __shared__ float As[16][132];
    __shared__ float Bs[16][68];
    const int tx = t & 15;
    const int ty = t >> 4;

    const int arow = t & 127;
    const int akh  = (t >> 7) * 8;
    const float* Aload = A + (size_t)(m0 + arow) * (size_t)lda + akh;
    const int brow = t & 63;
    const int bk4  = (t >> 6) * 4;
    const float* Bload = B + (size_t)(n0 + brow) * (size_t)ldb + bk4;

    float acc[8][4];
#pragma unroll
    for (int i = 0; i < 8; i++)
#pragma unroll
        for (int j = 0; j < 4; j++) acc[i][j] = 0.f;

    for (int k0 = 0; k0 < K; k0 += 16) {
        __syncthreads();
        float4 a0 = *(const float4*)(Aload + k0);
        float4 a1 = *(const float4*)(Aload + k0 + 4);
        float4 b0 = *(const float4*)(Bload + k0);
        As[akh + 0][arow] = a0.x; As[akh + 1][arow] = a0.y;
        As[akh + 2][arow] = a0.z; As[akh + 3][arow] = a0.w;
        As[akh + 4][arow] = a1.x; As[akh + 5][arow] = a1.y;
        As[akh + 6][arow] = a1.z; As[akh + 7][arow] = a1.w;
        Bs[bk4 + 0][brow] = b0.x; Bs[bk4 + 1][brow] = b0.y;
        Bs[bk4 + 2][brow] = b0.z; Bs[bk4 + 3][brow] = b0.w;
        __syncthreads();
#pragma unroll
        for (int k = 0; k < 16; k++) {
            float4 a4 = *(const float4*)(&As[k][ty * 8]);
            float4 a5 = *(const float4*)(&As[k][ty * 8 + 4]);
            float4 b4 = *(const float4*)(&Bs[k][tx * 4]);
            float am[8] = {a4.x, a4.y, a4.z, a4.w, a5.x, a5.y, a5.z, a5.w};
            float bn[4] = {b4.x, b4.y, b4.z, b4.w};
#pragma unroll
            for (int i = 0; i < 8; i++)
#pragma unroll
                for (int j = 0; j < 4; j++) acc[i][j] += am[i] * bn[j];
        }
    }
#pragma unroll
    for (int i = 0; i < 8; i++) {
        float4 o = make_float4(acc[i][0], acc[i][1], acc[i][2], acc[i][3]);
        *(float4*)(C + (size_t)(m0 + ty * 8 + i) * (size_t)ldc + n0 + tx * 4) = o;
    }
}

// ---------------------------------------------------------------------------
__global__ __launch_bounds__(256) void dt_reduce_kernel(
    const float* __restrict__ part, const float* __restrict__ dt_bias,
    float* __restrict__ dtg)
{
    const int i = blockIdx.x * 256 + threadIdx.x;
    float x = dt_bias[i & 63];
#pragma unroll
    for (int z = 0; z < 8; z++) x += part[(size_t)z * 131072 + i];
    dtg[i] = (x > 20.f) ? x : log1pf(__expf(x));
}

// ---------------------------------------------------------------------------
__global__ __launch_bounds__(256) void conv_silu_kernel(
    const unsigned short* __restrict__ projbf, const float* __restrict__ conv_w,
    const float* __restrict__ conv_b, float* __restrict__ out)
{
    const int c = blockIdx.x * 256 + threadIdx.x;
    const int s = blockIdx.y;
    const float4 w = *(const float4*)(conv_w + (size_t)c * 4);
    float acc = conv_b[c];
    const size_t base = 4096 + (size_t)c;
    if (s >= 3) acc += bf2f(projbf[(size_t)(s - 3) * GEMM1N + base]) * w.x;
    if (s >= 2) acc += bf2f(projbf[(size_t)(s - 2) * GEMM1N + base]) * w.y;
    if (s >= 1) acc += bf2f(projbf[(size_t)(s - 1) * GEMM1N + base]) * w.z;
    acc += bf2f(projbf[(size_t)s * GEMM1N + base]) * w.w;
    float sig = 1.f / (1.f + __expf(-acc));
    out[(size_t)s * CONVD + c] = acc * sig;
}

// ---------------------------------------------------------------------------
// SSM core, MFMA version. One block per (head h, chunk c), 256 thr = 4 waves.
//   statesT[p][n] = sum_l HdtT[p][l] * BdT[n][l]      (MFMA, k=256)
//   Yoff[l][p]    = sum_n Cscl[l][n] * statesT[p][n]  (MFMA, k=128)
//   Yd[l][p]      = sum_s M[l][s] * HdtT[p][s]        (MFMA, triangular)
// M built per 64x64 tile: off-diagonal tiles use rank-1 factorization
// exp(Acum[l]-Acum[s]) = D_i[l] * prod(T_m) * es[s] (all factors <= 1,
// Acum monotone decreasing -> no overflow; underflow -> 0 is exact).
// Only diagonal tiles need per-entry exp.
// ---------------------------------------------------------------------------
__global__ __launch_bounds__(256, 2) void ssm_mfma_kernel(
    const float* __restrict__ hBC, const float* __restrict__ dtg,
    const float* __restrict__ Gm, const float* __restrict__ A_log,
    const float* __restrict__ Dp, float* __restrict__ y)
{
    const int h    = blockIdx.x;
    const int c    = blockIdx.y;
    const int t    = threadIdx.x;
    const int wid  = t >> 6;
    const int lane = t & 63;
    const int lo   = lane & 15;
    const int q    = lane >> 4;

    __shared__ float sAcum[CS], sdt[CS], sD[CS], sEs[CS], sDecay[CS], sScl[CS];
    __shared__ float sWaveSum[4];
    __shared__ unsigned short sHdtT[64 * 264];   // [p][s] bf16  (33792 B)
    __shared__ unsigned short sStT[64 * 136];    // statesT [p][n] bf16 / f32 staging (17408 B)
    __shared__ unsigned short sBufB[128 * 72];   // BdT quarter / Cs tile / M half (18432 B)

    const float A = -__expf(A_log[h]);
    const int row0 = c * CS;
    const float* hid = hBC + (size_t)row0 * CONVD + h * P_DIM;
    const float* Bp  = hBC + (size_t)row0 * CONVD + INTER;
    const float* Cp  = hBC + (size_t)row0 * CONVD + INTER + N_DIM;
    const float* gm  = Gm + (size_t)c * CS * CS;

    // ---- cumsum of A*dt ----
    float dtv = dtg[(size_t)(row0 + t) * NH + h];
    float v = A * dtv;
    for (int off = 1; off < 64; off <<= 1) {
        float u = __shfl_up(v, off, 64);
        if (lane >= off) v += u;
    }
    if (lane == 63) sWaveSum[wid] = v;
    __syncthreads();
    float pre = 0.f;
    for (int i = 0; i < 4; i++) if (i < wid) pre += sWaveSum[i];
    v += pre;
    sAcum[t] = v;
    sdt[t] = dtv;
    __syncthreads();
    const float AcumEnd = sAcum[CS - 1];
    {
        float ac   = sAcum[t];
        float apre = (t < 64) ? 0.f : sAcum[(t & ~63) - 1];
        sD[t]     = __expf(ac - apre);           // decay from own tile start boundary
        sEs[t]    = __expf(sAcum[t | 63] - ac);  // decay to own tile end
        sDecay[t] = __expf(AcumEnd - ac);
        sScl[t]   = __expf(ac);
    }
    // next __syncthreads (inside HdtT loop) publishes these

    // ---- build HdtT (bf16 [p][s], row pitch 264) via fp32 LDS staging ----
    float* stg = (float*)sStT;   // 16 KB staging overlay
    for (int lt = 0; lt < 4; lt++) {
        __syncthreads();
        {
            const int p4 = (t & 15) * 4;
#pragma unroll
            for (int j = 0; j < 4; j++) {
                int l = (t >> 4) + j * 16;
                *(float4*)&stg[l * 64 + p4] =
                    *(const float4*)(hid + (size_t)(lt * 64 + l) * CONVD + p4);
            }
        }
        __syncthreads();
        {
            const int p = t & 63, lq = (t >> 6) * 16;
#pragma unroll
            for (int j = 0; j < 4; j++) {
                ushort4 pk;
                int l0 = lq + j * 4;
                pk.x = f2bf(stg[(l0 + 0) * 64 + p] * sdt[lt * 64 + l0 + 0]);
                pk.y = f2bf(stg[(l0 + 1) * 64 + p] * sdt[lt * 64 + l0 + 1]);
                pk.z = f2bf(stg[(l0 + 2) * 64 + p] * sdt[lt * 64 + l0 + 2]);
                pk.w = f2bf(stg[(l0 + 3) * 64 + p] * sdt[lt * 64 + l0 + 3]);
                *(uint2*)&sHdtT[p * 264 + lt * 64 + l0] = *(uint2*)&pk;
            }
        }
    }

    // ---- matmul-2: statesT[p][n], k = l in quarters of 64 ----
    f32x4 acc2[2][4];
#pragma unroll
    for (int mi = 0; mi < 2; mi++)
#pragma unroll
        for (int ni = 0; ni < 4; ni++) acc2[mi][ni] = (f32x4){0.f, 0.f, 0.f, 0.f};
    const int psub = (wid & 1) * 32;
    const int nsub = (wid >> 1) * 64;

    for (int qt = 0; qt < 4; qt++) {
        for (int hf = 0; hf < 2; hf++) {
            __syncthreads();
            {
                const int n4 = (t & 31) * 4;
#pragma unroll
                for (int j = 0; j < 4; j++) {
                    int r = (t >> 5) + j * 8;
                    *(float4*)&stg[r * 128 + n4] =
                        *(const float4*)(Bp + (size_t)(qt * 64 + hf * 32 + r) * CONVD + n4);
                }
            }
            __syncthreads();
            {
                const int n = t & 127, lc = (t >> 7) * 16;
#pragma unroll
                for (int j = 0; j < 4; j++) {
                    int l0 = lc + j * 4;
                    ushort4 pk;
                    pk.x = f2bf(stg[(l0 + 0) * 128 + n] * sDecay[qt * 64 + hf * 32 + l0 + 0]);
                    pk.y = f2bf(stg[(l0 + 1) * 128 + n] * sDecay[qt * 64 + hf * 32 + l0 + 1]);
                    pk.z = f2bf(stg[(l0 + 2) * 128 + n] * sDecay[qt * 64 + hf * 32 + l0 + 2]);
                    pk.w = f2bf(stg[(l0 + 3) * 128 + n] * sDecay[qt * 64 + hf * 32 + l0 + 3]);
                    *(uint2*)&sBufB[n * 72 + hf * 32 + l0] = *(uint2*)&pk;
                }
            }
        }
        __syncthreads();
#pragma unroll
        for (int ks = 0; ks < 2; ks++) {
            const int k0 = qt * 64 + ks * 32;
            const int kq = ks * 32;
            bf16x8 a2[2], b2[4];
#pragma unroll
            for (int mi = 0; mi < 2; mi++)
                a2[mi] = *(const bf16x8*)&sHdtT[(psub + mi * 16 + lo) * 264 + k0 + q * 8];
#pragma unroll
            for (int ni = 0; ni < 4; ni++)
                b2[ni] = *(const bf16x8*)&sBufB[(nsub + ni * 16 + lo) * 72 + kq + q * 8];
#pragma unroll
            for (int mi = 0; mi < 2; mi++)
#pragma unroll
                for (int ni = 0; ni < 4; ni++)
                    acc2[mi][ni] = __builtin_amdgcn_mfma_f32_16x16x32_bf16(
                        a2[mi], b2[ni], acc2[mi][ni], 0, 0, 0);
        }
    }
    __syncthreads();
    // statesT -> LDS bf16 (C/D layout: col = lane&15, row = q*4+reg)
#pragma unroll
    for (int mi = 0; mi < 2; mi++)
#pragma unroll
        for (int ni = 0; ni < 4; ni++)
#pragma unroll
            for (int rr = 0; rr < 4; rr++) {
                int p = psub + mi * 16 + q * 4 + rr;
                int n = nsub + ni * 16 + lo;
                sStT[p * 136 + n] = f2bf(acc2[mi][ni][rr]);
            }

    // ---- matmul-3: Yoff into accY ----
    f32x4 accY[4][2][2];
#pragma unroll
    for (int i = 0; i < 4; i++)
#pragma unroll
        for (int mi = 0; mi < 2; mi++)
#pragma unroll
            for (int pi = 0; pi < 2; pi++) accY[i][mi][pi] = (f32x4){0.f, 0.f, 0.f, 0.f};
    const int pcol = (wid & 1) * 32;   // p-cols of this wave's output
    const int rsub = (wid >> 1) * 16;  // row-offset within 32-row half
    unsigned short* Cs = sBufB;

    for (int i = 0; i < 4; i++) {
        __syncthreads();
        {
            const int n4 = (t & 31) * 4;
#pragma unroll
            for (int j = 0; j < 8; j++) {
                int r = (t >> 5) + j * 8;
                float4 cv = *(const float4*)(Cp + (size_t)(i * 64 + r) * CONVD + n4);
                float scl = sScl[i * 64 + r];
                ushort4 pk;
                pk.x = f2bf(cv.x * scl); pk.y = f2bf(cv.y * scl);
                pk.z = f2bf(cv.z * scl); pk.w = f2bf(cv.w * scl);
                *(uint2*)&Cs[r * 136 + n4] = *(uint2*)&pk;
            }
        }
        __syncthreads();
#pragma unroll
        for (int ks = 0; ks < 4; ks++) {
            const int k0 = ks * 32;
            bf16x8 a3[2], b3[2];
#pragma unroll
            for (int mi = 0; mi < 2; mi++)
                a3[mi] = *(const bf16x8*)&Cs[(mi * 32 + rsub + lo) * 136 + k0 + q * 8];
#pragma unroll
            for (int pi = 0; pi < 2; pi++)
                b3[pi] = *(const bf16x8*)&sStT[(pcol + pi * 16 + lo) * 136 + k0 + q * 8];
#pragma unroll
            for (int mi = 0; mi < 2; mi++)
#pragma unroll
                for (int pi = 0; pi < 2; pi++)
                    accY[i][mi][pi] = __builtin_amdgcn_mfma_f32_16x16x32_bf16(
                        a3[mi], b3[pi], accY[i][mi][pi], 0, 0, 0);
        }
    }

    // ---- matmul-1: Yd (triangular), M built in 32-row halves ----
    unsigned short* Mt = sBufB;
    for (int i = 0; i < 4; i++) {
        const int nk = 2 * (i + 1);
        for (int mi = 0; mi < 2; mi++) {
            __syncthreads();
            if (wid <= i) {   // wave `wid` builds s-tile `wid`
                float P = 1.f;
                for (int m = wid + 1; m <= i - 1; m++) P *= sD[m * 64 + 63];
                const int s4 = wid * 64 + lo * 4;
                float4 es4 = *(const float4*)&sEs[s4];
#pragma unroll
                for (int j = 0; j < 8; j++) {
                    int lr = q + j * 4;              // 0..31
                    int l  = i * 64 + mi * 32 + lr;
                    float4 g4 = *(const float4*)&gm[(size_t)l * CS + s4];
                    float w0, w1, w2, w3;
                    if (wid == i) {
                        float al = sAcum[l];
                        w0 = (s4 + 0 <= l) ? __expf(al - sAcum[s4 + 0]) : 0.f;
                        w1 = (s4 + 1 <= l) ? __expf(al - sAcum[s4 + 1]) : 0.f;
                        w2 = (s4 + 2 <= l) ? __expf(al - sAcum[s4 + 2]) : 0.f;
                        w3 = (s4 + 3 <= l) ? __expf(al - sAcum[s4 + 3]) : 0.f;
                    } else {
                        float rs = sD[l] * P;
                        w0 = rs * es4.x; w1 = rs * es4.y;
                        w2 = rs * es4.z; w3 = rs * es4.w;
                    }
                    ushort4 pk;
                    pk.x = f2bf(g4.x * w0); pk.y = f2bf(g4.y * w1);
                    pk.z = f2bf(g4.z * w2); pk.w = f2bf(g4.w * w3);
                    *(uint2*)&Mt[lr * 264 + s4] = *(uint2*)&pk;
                }
            }
            __syncthreads();
            for (int ks = 0; ks < nk; ks++) {
                const int k0 = ks * 32;
                bf16x8 am = *(const bf16x8*)&Mt[(rsub + lo) * 264 + k0 + q * 8];
                bf16x8 b1[2];
#pragma unroll
                for (int pi = 0; pi < 2; pi++)
                    b1[pi] = *(const bf16x8*)&sHdtT[(pcol + pi * 16 + lo) * 264 + k0 + q * 8];
#pragma unroll
                for (int pi = 0; pi < 2; pi++)
                    accY[i][mi][pi] = __builtin_amdgcn_mfma_f32_16x16x32_bf16(
                        am, b1[pi], accY[i][mi][pi], 0, 0, 0);
            }
        }
    }

    // ---- epilogue: y = Yd + Yoff + D[h]*hid ----
    const float Dh = Dp[h];
#pragma unroll
    for (int i = 0; i < 4; i++)
#pragma unroll
        for (int mi = 0; mi < 2; mi++)
#pragma unroll
            for (int pi = 0; pi < 2; pi++)
#pragma unroll
                for (int rr = 0; rr < 4; rr++) {
                    int l = i * 64 + mi * 32 + rsub + q * 4 + rr;
                    int p = pcol + pi * 16 + lo;
                    float hv = hid[(size_t)l * CONVD + p];
                    y[(size_t)(row0 + l) * INTER + h * P_DIM + p] =
                        accY[i][mi][pi][rr] + Dh * hv;
                }
}

// ---------------------------------------------------------------------------
// Gated RMSNorm (unchanged from round 2)
// ---------------------------------------------------------------------------
__global__ __launch_bounds__(256) void norm_kernel(
    const float* __restrict__ y, const unsigned short* __restrict__ projbf,
    const float* __restrict__ norm_w, unsigned short* __restrict__ yn)
{
    const int s = blockIdx.x;
    const int t = threadIdx.x;
    __shared__ float sYf[INTER];
    __shared__ float sW[4];
    const float* yrow = y + (size_t)s * INTER;
    const unsigned short* grow = projbf + (size_t)s * GEMM1N;
    float sum = 0.f;
    for (int j0 = 0; j0 < INTER; j0 += 2048) {
        int j = j0 + t * 8;
        float4 y0 = *(const float4*)(yrow + j);
        float4 y1 = *(const float4*)(yrow + j + 4);
        uint4 gp = *(const uint4*)(grow + j);
        float gv[8] = {
            bf2f((unsigned short)(gp.x & 0xffff)), bf2f((unsigned short)(gp.x >> 16)),
            bf2f((unsigned short)(gp.y & 0xffff)), bf2f((unsigned short)(gp.y >> 16)),
            bf2f((unsigned short)(gp.z & 0xffff)), bf2f((unsigned short)(gp.z >> 16)),
            bf2f((unsigned short)(gp.w & 0xffff)), bf2f((unsigned short)(gp.w >> 16))};
        float yv8[8] = {y0.x, y0.y, y0.z, y0.w, y1.x, y1.y, y1.z, y1.w};
#pragma unroll
        for (int e = 0; e < 8; e++) {
            float f = yv8[e] * (gv[e] / (1.f + __expf(-gv[e])));
            sum += f * f;
            sYf[j + e] = f;
        }
    }
    for (int off = 32; off > 0; off >>= 1) sum += __shfl_down(sum, off, 64);
    if ((t & 63) == 0) sW[t >> 6] = sum;
    __syncthreads();
    const float var = (sW[0] + sW[1] + sW[2] + sW[3]) * (1.f / (float)INTER);
    const float rs = rsqrtf(var + EPS);
    for (int j0 = 0; j0 < INTER; j0 += 2048) {
        int j = j0 + t * 8;
        float4 w0 = *(const float4*)(norm_w + j);
        float4 w1 = *(const float4*)(norm_w + j + 4);
        float wv[8] = {w0.x, w0.y, w0.z, w0.w, w1.x, w1.y, w1.z, w1.w};
        unsigned short o[8];
#pragma unroll
        for (int e = 0; e < 8; e++) o[e] = f2bf(sYf[j + e] * wv[e] * rs);
        uint4 ov;
        ov.x = (unsigned int)o[0] | ((unsigned int)o[1] << 16);
        ov.y = (unsigned int)o[2] | ((unsigned int)o[3] << 16);
        ov.z = (unsigned int)o[4] | ((unsigned int)o[5] << 16);
        ov.w = (unsigned int)o[6] | ((unsigned int)o[7] << 16);
        *(uint4*)(yn + (size_t)s * INTER + j) = ov;
    }
}

// ---------------------------------------------------------------------------
extern "C" void kernel_launch(void* const* d_in, const int* in_sizes, int n_in,
                              void* d_out, int out_size, void* d_ws, size_t ws_size,
                              hipStream_t stream)
{
    const float* X       = (const float*)d_in[0];
    const float* W_in    = (const float*)d_in[2];
    const float* conv_w  = (const float*)d_in[3];
    const float* conv_b  = (const float*)d_in[4];
    const float* dt_bias = (const float*)d_in[5];
    const float* A_log   = (const float*)d_in[6];
    const float* Dp      = (const float*)d_in[7];
    const float* norm_w  = (const float*)d_in[8];
    const float* W_out   = (const float*)d_in[9];
    float* out = (float*)d_out;
    float* ws  = (float*)d_ws;

    unsigned short* projbf = (unsigned short*)(ws + OFF_PROJBF);
    float* hbc     = ws + OFF_HBC;
    float* dtg     = ws + OFF_DTG;
    float* dtpart  = ws + OFF_DTPART;
    float* gm      = ws + OFF_GM;
    float* yv      = ws + OFF_YV;
    unsigned short* Xbf    = (unsigned short*)(ws + OFF_R);
    unsigned short* Winbf  = (unsigned short*)(ws + OFF_R + 2097152);
    unsigned short* ynbf   = (unsigned short*)(ws + OFF_R);           // aliases Xbf
    unsigned short* Woutbf = (unsigned short*)(ws + OFF_R + 4194304); // aliases Winbf

    cast_bf16_kernel<<<2048, 256, 0, stream>>>(X, Xbf);
    cast_bf16_kernel<<<8448, 256, 0, stream>>>(W_in, Winbf);

    gemm_bt_mfma<<<dim3(GEMM1N / 128, S_LEN / 128), 256, 0, stream>>>(
        Xbf, E_DIM, Winbf, E_DIM, nullptr, projbf, GEMM1N, E_DIM);

    cast_bf16_kernel<<<4096, 256, 0, stream>>>(W_out, Woutbf);

    gemm_nt<<<dim3(1, 16, 8), 256, 0, stream>>>(
        X, E_DIM, 256LL, W_in + (size_t)GEMM1N * E_DIM, E_DIM, 256LL,
        dtpart, NH, 131072LL, 256);
    dt_reduce_kernel<<<512, 256, 0, stream>>>(dtpart, dt_bias, dtg);

    conv_silu_kernel<<<dim3(CONVD / 256, S_LEN), 256, 0, stream>>>(
        projbf, conv_w, conv_b, hbc);

    gemm_nt<<<dim3(CS / 64, CS / 128, NCHUNK), 256, 0, stream>>>(
        hbc + INTER + N_DIM, CONVD, (long long)CS * CONVD,
        hbc + INTER,         CONVD, (long long)CS * CONVD,
        gm, CS, (long long)CS * CS, N_DIM);

    ssm_mfma_kernel<<<dim3(NH, NCHUNK), 256, 0, stream>>>(
        hbc, dtg, gm, A_log, Dp, yv);

    norm_kernel<<<dim3(S_LEN), 256, 0, stream>>>(yv, projbf, norm_w, ynbf);

    gemm_bt_mfma<<<dim3(E_DIM / 128, S_LEN / 128), 256, 0, stream>>>(
        ynbf, INTER, Woutbf, INTER, out, nullptr, E_DIM, INTER);
}

// Round 4
// 493.333 us; speedup vs baseline: 4.0421x; 1.0708x over previous
//
#include <hip/hip_runtime.h>
#include <math.h>

// Problem constants
#define S_LEN   2048
#define E_DIM   2048
#define NH      64
#define P_DIM   64
#define N_DIM   128
#define CS      256
#define NCHUNK  8
#define INTER   4096
#define CONVD   4352
#define PROJ    8512
#define GEMM1N  8448       // INTER + CONVD = 66*128 exactly
#define EPS     1e-5f

// Workspace layout (float units)
#define OFF_PROJBF 0ull                        // bf16 2048*8448 = 8,650,752 fl
#define OFF_HBC    8650752ull                  // fp32 2048*4352 = 8,912,896 fl
#define OFF_DTG    17563648ull                 // fp32 2048*64
#define OFF_DTPART 17694720ull                 // fp32 8*2048*64
#define OFF_GM     18743296ull                 // fp32 8*256*256
#define OFF_YV     19267584ull                 // fp32 2048*4096
#define OFF_R      27656192ull                 // shared region
// region R:  Xbf = R+0 | Winbf = R+2,097,152 ; aliased after GEMM1:
// ynbf = R+0 | Woutbf = R+4,194,304.
// GEMM2 split-K partials (2 x 2048*2048 fp32 = 8,388,608 fl) live in the HBC
// region — hbc's last reader (ssm_mfma) finishes before GEMM2 launches.

typedef __bf16 bf16x8 __attribute__((ext_vector_type(8)));
typedef float  f32x4  __attribute__((ext_vector_type(4)));

__device__ __forceinline__ float bf2f(unsigned short u) {
    union { unsigned int i; float f; } v; v.i = ((unsigned int)u) << 16; return v.f;
}
__device__ __forceinline__ unsigned short f2bf(float f) {
    union { float f; unsigned int i; } v; v.f = f;
    unsigned int r = v.i + 0x7FFFu + ((v.i >> 16) & 1u);
    return (unsigned short)(r >> 16);
}
__device__ __forceinline__ void gl_lds16(const void* g, void* l) {
    __builtin_amdgcn_global_load_lds(
        (const __attribute__((address_space(1))) void*)g,
        (__attribute__((address_space(3))) void*)l, 16, 0, 0);
}

// ---------------------------------------------------------------------------
// fp32 -> bf16 cast, 8 elems/thread
// ---------------------------------------------------------------------------
__global__ __launch_bounds__(256) void cast_bf16_kernel(
    const float* __restrict__ in, unsigned short* __restrict__ out)
{
    size_t i = ((size_t)blockIdx.x * 256 + threadIdx.x) * 8;
    float4 a = *(const float4*)(in + i);
    float4 b = *(const float4*)(in + i + 4);
    uint4 o;
    o.x = (unsigned int)f2bf(a.x) | ((unsigned int)f2bf(a.y) << 16);
    o.y = (unsigned int)f2bf(a.z) | ((unsigned int)f2bf(a.w) << 16);
    o.z = (unsigned int)f2bf(b.x) | ((unsigned int)f2bf(b.y) << 16);
    o.w = (unsigned int)f2bf(b.z) | ((unsigned int)f2bf(b.w) << 16);
    *(uint4*)(out + i) = o;
}

// ---------------------------------------------------------------------------
// bf16 MFMA NT GEMM, BK=64 + XOR bank swizzle.
// C[m][n] = sum_k A[m][k]*B[n][k].  128x128 tile, 256 thr (4 waves, 4x4 MFMA
// grid each).  LDS slot (t&7) of row (t>>3)+32i holds global k-chunk
// (t&7)^(row&7)  -> global_load_lds dest stays lane-contiguous (base+16*lane)
// while fragment ds_read_b128 banks spread over all 8 groups (2-way = free).
// blockIdx.z shifts A/B by sA/sB (shorts) and Cf by sC (floats): split-K.
// M%128==0, N%128==0, K%64==0.
// ---------------------------------------------------------------------------
__global__ __launch_bounds__(256) void gemm_bt_mfma(
    const unsigned short* __restrict__ A, int lda, long long sA,
    const unsigned short* __restrict__ B, int ldb, long long sB,
    float* __restrict__ Cf, unsigned short* __restrict__ Cb, int ldc,
    long long sC, int K)
{
    __shared__ unsigned short As[128 * 64];   // 16 KB
    __shared__ unsigned short Bs[128 * 64];   // 16 KB
    A += (long long)blockIdx.z * sA;
    B += (long long)blockIdx.z * sB;
    const int t    = threadIdx.x;
    const int m0   = blockIdx.y * 128;
    const int n0   = blockIdx.x * 128;
    const int w    = t >> 6;
    const int lane = t & 63;
    const int lo   = lane & 15;
    const int q    = lane >> 4;
    const int wm   = (w & 1) * 64;
    const int wn   = (w >> 1) * 64;

    const int srow   = t >> 3;                 // 0..31
    const int gchunk = (t & 7) ^ (srow & 7);   // global k-chunk staged at slot t&7
    const unsigned short* Ag = A + (size_t)(m0 + srow) * lda + gchunk * 8;
    const unsigned short* Bg = B + (size_t)(n0 + srow) * ldb + gchunk * 8;
    unsigned short* Asl = &As[t * 8];
    unsigned short* Bsl = &Bs[t * 8];

    f32x4 acc[4][4];
#pragma unroll
    for (int i = 0; i < 4; i++)
#pragma unroll
        for (int j = 0; j < 4; j++) acc[i][j] = (f32x4){0.f, 0.f, 0.f, 0.f};

    for (int k0 = 0; k0 < K; k0 += 64) {
        __syncthreads();
#pragma unroll
        for (int i = 0; i < 4; i++) {
            gl_lds16(Ag + k0 + (size_t)(i * 32) * lda, Asl + i * 32 * 64);
            gl_lds16(Bg + k0 + (size_t)(i * 32) * ldb, Bsl + i * 32 * 64);
        }
        __syncthreads();
#pragma unroll
        for (int ks = 0; ks < 2; ks++) {
            bf16x8 af[4], bfr[4];
#pragma unroll
            for (int i = 0; i < 4; i++) {
                const int r = wm + i * 16 + lo;
                const int slot = (ks * 4 + q) ^ (r & 7);
                af[i] = *(const bf16x8*)&As[r * 64 + slot * 8];
            }
#pragma unroll
            for (int i = 0; i < 4; i++) {
                const int r = wn + i * 16 + lo;
                const int slot = (ks * 4 + q) ^ (r & 7);
                bfr[i] = *(const bf16x8*)&Bs[r * 64 + slot * 8];
            }
#pragma unroll
            for (int mi = 0; mi < 4; mi++)
#pragma unroll
                for (int ni = 0; ni < 4; ni++)
                    acc[mi][ni] = __builtin_amdgcn_mfma_f32_16x16x32_bf16(
                        af[mi], bfr[ni], acc[mi][ni], 0, 0, 0);
        }
    }

    // Epilogue. C/D layout: col = lane&15, row = (lane>>4)*4 + reg  [m89]
    if (Cb) {
#pragma unroll
        for (int mi = 0; mi < 4; mi++) {
            const int r = m0 + wm + mi * 16 + q * 4;
#pragma unroll
            for (int ni = 0; ni < 4; ni++) {
                const int cc = n0 + wn + ni * 16 + lo;
#pragma unroll
                for (int rr = 0; rr < 4; rr++)
                    Cb[(size_t)(r + rr) * ldc + cc] = f2bf(acc[mi][ni][rr]);
            }
        }
    } else {
        float* Cz = Cf + (long long)blockIdx.z * sC;
#pragma unroll
        for (int mi = 0; mi < 4; mi++) {
            const int r = m0 + wm + mi * 16 + q * 4;
#pragma unroll
            for (int ni = 0; ni < 4; ni++) {
                const int cc = n0 + wn + ni * 16 + lo;
#pragma unroll
                for (int rr = 0; rr < 4; rr++)
                    Cz[(size_t)(r + rr) * ldc + cc] = acc[mi][ni][rr];
            }
        }
    }
}

// ---------------------------------------------------------------------------
// out = a + b (fp32, 4 elems/thread) — split-K reduce for GEMM2
// ---------------------------------------------------------------------------
__global__ __launch_bounds__(256) void addf_kernel(
    const float* __restrict__ a, const float* __restrict__ b,
    float* __restrict__ o)
{
    size_t i = ((size_t)blockIdx.x * 256 + threadIdx.x) * 4;
    float4 x = *(const float4*)(a + i);
    float4 y = *(const float4*)(b + i);
    float4 r = make_float4(x.x + y.x, x.y + y.y, x.z + y.z, x.w + y.w);
    *(float4*)(o + i) = r;
}

// ---------------------------------------------------------------------------
// fp32 NT GEMM (for Gm and dt split-K)
// ---------------------------------------------------------------------------
__global__ __launch_bounds__(256) void gemm_nt(
    const float* __restrict__ A, int lda, long long sA,
    const float* __restrict__ B, int ldb, long long sB,
    float* __restrict__ C, int ldc, long long sC, int K)
{
    A += (long long)blockIdx.z * sA;
    B += (long long)blockIdx.z * sB;
    C += (long long)blockIdx.z * sC;
    const int t  = threadIdx.x;
    const int m0 = blockIdx.y * 128;
    const int n0 = blockIdx.x * 64;
    __shared__ float As[16][132];
    __shared__ float Bs[16][68];
    const int tx = t & 15;
    const int ty = t >> 4;

    const int arow = t & 127;
    const int akh  = (t >> 7) * 8;
    const float* Aload = A + (size_t)(m0 + arow) * (size_t)lda + akh;
    const int brow = t & 63;
    const int bk4  = (t >> 6) * 4;
    const float* Bload = B + (size_t)(n0 + brow) * (size_t)ldb + bk4;

    float acc[8][4];
#pragma unroll
    for (int i = 0; i < 8; i++)
#pragma unroll
        for (int j = 0; j < 4; j++) acc[i][j] = 0.f;

    for (int k0 = 0; k0 < K; k0 += 16) {
        __syncthreads();
        float4 a0 = *(const float4*)(Aload + k0);
        float4 a1 = *(const float4*)(Aload + k0 + 4);
        float4 b0 = *(const float4*)(Bload + k0);
        As[akh + 0][arow] = a0.x; As[akh + 1][arow] = a0.y;
        As[akh + 2][arow] = a0.z; As[akh + 3][arow] = a0.w;
        As[akh + 4][arow] = a1.x; As[akh + 5][arow] = a1.y;
        As[akh + 6][arow] = a1.z; As[akh + 7][arow] = a1.w;
        Bs[bk4 + 0][brow] = b0.x; Bs[bk4 + 1][brow] = b0.y;
        Bs[bk4 + 2][brow] = b0.z; Bs[bk4 + 3][brow] = b0.w;
        __syncthreads();
#pragma unroll
        for (int k = 0; k < 16; k++) {
            float4 a4 = *(const float4*)(&As[k][ty * 8]);
            float4 a5 = *(const float4*)(&As[k][ty * 8 + 4]);
            float4 b4 = *(const float4*)(&Bs[k][tx * 4]);
            float am[8] = {a4.x, a4.y, a4.z, a4.w, a5.x, a5.y, a5.z, a5.w};
            float bn[4] = {b4.x, b4.y, b4.z, b4.w};
#pragma unroll
            for (int i = 0; i < 8; i++)
#pragma unroll
                for (int j = 0; j < 4; j++) acc[i][j] += am[i] * bn[j];
        }
    }
#pragma unroll
    for (int i = 0; i < 8; i++) {
        float4 o = make_float4(acc[i][0], acc[i][1], acc[i][2], acc[i][3]);
        *(float4*)(C + (size_t)(m0 + ty * 8 + i) * (size_t)ldc + n0 + tx * 4) = o;
    }
}

// ---------------------------------------------------------------------------
__global__ __launch_bounds__(256) void dt_reduce_kernel(
    const float* __restrict__ part, const float* __restrict__ dt_bias,
    float* __restrict__ dtg)
{
    const int i = blockIdx.x * 256 + threadIdx.x;
    float x = dt_bias[i & 63];
#pragma unroll
    for (int z = 0; z < 8; z++) x += part[(size_t)z * 131072 + i];
    dtg[i] = (x > 20.f) ? x : log1pf(__expf(x));
}

// ---------------------------------------------------------------------------
__global__ __launch_bounds__(256) void conv_silu_kernel(
    const unsigned short* __restrict__ projbf, const float* __restrict__ conv_w,
    const float* __restrict__ conv_b, float* __restrict__ out)
{
    const int c = blockIdx.x * 256 + threadIdx.x;
    const int s = blockIdx.y;
    const float4 w = *(const float4*)(conv_w + (size_t)c * 4);
    float acc = conv_b[c];
    const size_t base = 4096 + (size_t)c;
    if (s >= 3) acc += bf2f(projbf[(size_t)(s - 3) * GEMM1N + base]) * w.x;
    if (s >= 2) acc += bf2f(projbf[(size_t)(s - 2) * GEMM1N + base]) * w.y;
    if (s >= 1) acc += bf2f(projbf[(size_t)(s - 1) * GEMM1N + base]) * w.z;
    acc += bf2f(projbf[(size_t)s * GEMM1N + base]) * w.w;
    float sig = 1.f / (1.f + __expf(-acc));
    out[(size_t)s * CONVD + c] = acc * sig;
}

// ---------------------------------------------------------------------------
// SSM core, MFMA version (unchanged from round 3)
// ---------------------------------------------------------------------------
__global__ __launch_bounds__(256, 2) void ssm_mfma_kernel(
    const float* __restrict__ hBC, const float* __restrict__ dtg,
    const float* __restrict__ Gm, const float* __restrict__ A_log,
    const float* __restrict__ Dp, float* __restrict__ y)
{
    const int h    = blockIdx.x;
    const int c    = blockIdx.y;
    const int t    = threadIdx.x;
    const int wid  = t >> 6;
    const int lane = t & 63;
    const int lo   = lane & 15;
    const int q    = lane >> 4;

    __shared__ float sAcum[CS], sdt[CS], sD[CS], sEs[CS], sDecay[CS], sScl[CS];
    __shared__ float sWaveSum[4];
    __shared__ unsigned short sHdtT[64 * 264];
    __shared__ unsigned short sStT[64 * 136];
    __shared__ unsigned short sBufB[128 * 72];

    const float A = -__expf(A_log[h]);
    const int row0 = c * CS;
    const float* hid = hBC + (size_t)row0 * CONVD + h * P_DIM;
    const float* Bp  = hBC + (size_t)row0 * CONVD + INTER;
    const float* Cp  = hBC + (size_t)row0 * CONVD + INTER + N_DIM;
    const float* gm  = Gm + (size_t)c * CS * CS;

    float dtv = dtg[(size_t)(row0 + t) * NH + h];
    float v = A * dtv;
    for (int off = 1; off < 64; off <<= 1) {
        float u = __shfl_up(v, off, 64);
        if (lane >= off) v += u;
    }
    if (lane == 63) sWaveSum[wid] = v;
    __syncthreads();
    float pre = 0.f;
    for (int i = 0; i < 4; i++) if (i < wid) pre += sWaveSum[i];
    v += pre;
    sAcum[t] = v;
    sdt[t] = dtv;
    __syncthreads();
    const float AcumEnd = sAcum[CS - 1];
    {
        float ac   = sAcum[t];
        float apre = (t < 64) ? 0.f : sAcum[(t & ~63) - 1];
        sD[t]     = __expf(ac - apre);
        sEs[t]    = __expf(sAcum[t | 63] - ac);
        sDecay[t] = __expf(AcumEnd - ac);
        sScl[t]   = __expf(ac);
    }

    float* stg = (float*)sStT;
    for (int lt = 0; lt < 4; lt++) {
        __syncthreads();
        {
            const int p4 = (t & 15) * 4;
#pragma unroll
            for (int j = 0; j < 4; j++) {
                int l = (t >> 4) + j * 16;
                *(float4*)&stg[l * 64 + p4] =
                    *(const float4*)(hid + (size_t)(lt * 64 + l) * CONVD + p4);
            }
        }
        __syncthreads();
        {
            const int p = t & 63, lq = (t >> 6) * 16;
#pragma unroll
            for (int j = 0; j < 4; j++) {
                ushort4 pk;
                int l0 = lq + j * 4;
                pk.x = f2bf(stg[(l0 + 0) * 64 + p] * sdt[lt * 64 + l0 + 0]);
                pk.y = f2bf(stg[(l0 + 1) * 64 + p] * sdt[lt * 64 + l0 + 1]);
                pk.z = f2bf(stg[(l0 + 2) * 64 + p] * sdt[lt * 64 + l0 + 2]);
                pk.w = f2bf(stg[(l0 + 3) * 64 + p] * sdt[lt * 64 + l0 + 3]);
                *(uint2*)&sHdtT[p * 264 + lt * 64 + l0] = *(uint2*)&pk;
            }
        }
    }

    f32x4 acc2[2][4];
#pragma unroll
    for (int mi = 0; mi < 2; mi++)
#pragma unroll
        for (int ni = 0; ni < 4; ni++) acc2[mi][ni] = (f32x4){0.f, 0.f, 0.f, 0.f};
    const int psub = (wid & 1) * 32;
    const int nsub = (wid >> 1) * 64;

    for (int qt = 0; qt < 4; qt++) {
        for (int hf = 0; hf < 2; hf++) {
            __syncthreads();
            {
                const int n4 = (t & 31) * 4;
#pragma unroll
                for (int j = 0; j < 4; j++) {
                    int r = (t >> 5) + j * 8;
                    *(float4*)&stg[r * 128 + n4] =
                        *(const float4*)(Bp + (size_t)(qt * 64 + hf * 32 + r) * CONVD + n4);
                }
            }
            __syncthreads();
            {
                const int n = t & 127, lc = (t >> 7) * 16;
#pragma unroll
                for (int j = 0; j < 4; j++) {
                    int l0 = lc + j * 4;
                    ushort4 pk;
                    pk.x = f2bf(stg[(l0 + 0) * 128 + n] * sDecay[qt * 64 + hf * 32 + l0 + 0]);
                    pk.y = f2bf(stg[(l0 + 1) * 128 + n] * sDecay[qt * 64 + hf * 32 + l0 + 1]);
                    pk.z = f2bf(stg[(l0 + 2) * 128 + n] * sDecay[qt * 64 + hf * 32 + l0 + 2]);
                    pk.w = f2bf(stg[(l0 + 3) * 128 + n] * sDecay[qt * 64 + hf * 32 + l0 + 3]);
                    *(uint2*)&sBufB[n * 72 + hf * 32 + l0] = *(uint2*)&pk;
                }
            }
        }
        __syncthreads();
#pragma unroll
        for (int ks = 0; ks < 2; ks++) {
            const int k0 = qt * 64 + ks * 32;
            const int kq = ks * 32;
            bf16x8 a2[2], b2[4];
#pragma unroll
            for (int mi = 0; mi < 2; mi++)
                a2[mi] = *(const bf16x8*)&sHdtT[(psub + mi * 16 + lo) * 264 + k0 + q * 8];
#pragma unroll
            for (int ni = 0; ni < 4; ni++)
                b2[ni] = *(const bf16x8*)&sBufB[(nsub + ni * 16 + lo) * 72 + kq + q * 8];
#pragma unroll
            for (int mi = 0; mi < 2; mi++)
#pragma unroll
                for (int ni = 0; ni < 4; ni++)
                    acc2[mi][ni] = __builtin_amdgcn_mfma_f32_16x16x32_bf16(
                        a2[mi], b2[ni], acc2[mi][ni], 0, 0, 0);
        }
    }
    __syncthreads();
#pragma unroll
    for (int mi = 0; mi < 2; mi++)
#pragma unroll
        for (int ni = 0; ni < 4; ni++)
#pragma unroll
            for (int rr = 0; rr < 4; rr++) {
                int p = psub + mi * 16 + q * 4 + rr;
                int n = nsub + ni * 16 + lo;
                sStT[p * 136 + n] = f2bf(acc2[mi][ni][rr]);
            }

    f32x4 accY[4][2][2];
#pragma unroll
    for (int i = 0; i < 4; i++)
#pragma unroll
        for (int mi = 0; mi < 2; mi++)
#pragma unroll
            for (int pi = 0; pi < 2; pi++) accY[i][mi][pi] = (f32x4){0.f, 0.f, 0.f, 0.f};
    const int pcol = (wid & 1) * 32;
    const int rsub = (wid >> 1) * 16;
    unsigned short* Cs = sBufB;

    for (int i = 0; i < 4; i++) {
        __syncthreads();
        {
            const int n4 = (t & 31) * 4;
#pragma unroll
            for (int j = 0; j < 8; j++) {
                int r = (t >> 5) + j * 8;
                float4 cv = *(const float4*)(Cp + (size_t)(i * 64 + r) * CONVD + n4);
                float scl = sScl[i * 64 + r];
                ushort4 pk;
                pk.x = f2bf(cv.x * scl); pk.y = f2bf(cv.y * scl);
                pk.z = f2bf(cv.z * scl); pk.w = f2bf(cv.w * scl);
                *(uint2*)&Cs[r * 136 + n4] = *(uint2*)&pk;
            }
        }
        __syncthreads();
#pragma unroll
        for (int ks = 0; ks < 4; ks++) {
            const int k0 = ks * 32;
            bf16x8 a3[2], b3[2];
#pragma unroll
            for (int mi = 0; mi < 2; mi++)
                a3[mi] = *(const bf16x8*)&Cs[(mi * 32 + rsub + lo) * 136 + k0 + q * 8];
#pragma unroll
            for (int pi = 0; pi < 2; pi++)
                b3[pi] = *(const bf16x8*)&sStT[(pcol + pi * 16 + lo) * 136 + k0 + q * 8];
#pragma unroll
            for (int mi = 0; mi < 2; mi++)
#pragma unroll
                for (int pi = 0; pi < 2; pi++)
                    accY[i][mi][pi] = __builtin_amdgcn_mfma_f32_16x16x32_bf16(
                        a3[mi], b3[pi], accY[i][mi][pi], 0, 0, 0);
        }
    }

    unsigned short* Mt = sBufB;
    for (int i = 0; i < 4; i++) {
        const int nk = 2 * (i + 1);
        for (int mi = 0; mi < 2; mi++) {
            __syncthreads();
            if (wid <= i) {
                float P = 1.f;
                for (int m = wid + 1; m <= i - 1; m++) P *= sD[m * 64 + 63];
                const int s4 = wid * 64 + lo * 4;
                float4 es4 = *(const float4*)&sEs[s4];
#pragma unroll
                for (int j = 0; j < 8; j++) {
                    int lr = q + j * 4;
                    int l  = i * 64 + mi * 32 + lr;
                    float4 g4 = *(const float4*)&gm[(size_t)l * CS + s4];
                    float w0, w1, w2, w3;
                    if (wid == i) {
                        float al = sAcum[l];
                        w0 = (s4 + 0 <= l) ? __expf(al - sAcum[s4 + 0]) : 0.f;
                        w1 = (s4 + 1 <= l) ? __expf(al - sAcum[s4 + 1]) : 0.f;
                        w2 = (s4 + 2 <= l) ? __expf(al - sAcum[s4 + 2]) : 0.f;
                        w3 = (s4 + 3 <= l) ? __expf(al - sAcum[s4 + 3]) : 0.f;
                    } else {
                        float rs = sD[l] * P;
                        w0 = rs * es4.x; w1 = rs * es4.y;
                        w2 = rs * es4.z; w3 = rs * es4.w;
                    }
                    ushort4 pk;
                    pk.x = f2bf(g4.x * w0); pk.y = f2bf(g4.y * w1);
                    pk.z = f2bf(g4.z * w2); pk.w = f2bf(g4.w * w3);
                    *(uint2*)&Mt[lr * 264 + s4] = *(uint2*)&pk;
                }
            }
            __syncthreads();
            for (int ks = 0; ks < nk; ks++) {
                const int k0 = ks * 32;
                bf16x8 am = *(const bf16x8*)&Mt[(rsub + lo) * 264 + k0 + q * 8];
                bf16x8 b1[2];
#pragma unroll
                for (int pi = 0; pi < 2; pi++)
                    b1[pi] = *(const bf16x8*)&sHdtT[(pcol + pi * 16 + lo) * 264 + k0 + q * 8];
#pragma unroll
                for (int pi = 0; pi < 2; pi++)
                    accY[i][mi][pi] = __builtin_amdgcn_mfma_f32_16x16x32_bf16(
                        am, b1[pi], accY[i][mi][pi], 0, 0, 0);
            }
        }
    }

    const float Dh = Dp[h];
#pragma unroll
    for (int i = 0; i < 4; i++)
#pragma unroll
        for (int mi = 0; mi < 2; mi++)
#pragma unroll
            for (int pi = 0; pi < 2; pi++)
#pragma unroll
                for (int rr = 0; rr < 4; rr++) {
                    int l = i * 64 + mi * 32 + rsub + q * 4 + rr;
                    int p = pcol + pi * 16 + lo;
                    float hv = hid[(size_t)l * CONVD + p];
                    y[(size_t)(row0 + l) * INTER + h * P_DIM + p] =
                        accY[i][mi][pi][rr] + Dh * hv;
                }
}

// ---------------------------------------------------------------------------
// Gated RMSNorm (unchanged)
// ---------------------------------------------------------------------------
__global__ __launch_bounds__(256) void norm_kernel(
    const float* __restrict__ y, const unsigned short* __restrict__ projbf,
    const float* __restrict__ norm_w, unsigned short* __restrict__ yn)
{
    const int s = blockIdx.x;
    const int t = threadIdx.x;
    __shared__ float sYf[INTER];
    __shared__ float sW[4];
    const float* yrow = y + (size_t)s * INTER;
    const unsigned short* grow = projbf + (size_t)s * GEMM1N;
    float sum = 0.f;
    for (int j0 = 0; j0 < INTER; j0 += 2048) {
        int j = j0 + t * 8;
        float4 y0 = *(const float4*)(yrow + j);
        float4 y1 = *(const float4*)(yrow + j + 4);
        uint4 gp = *(const uint4*)(grow + j);
        float gv[8] = {
            bf2f((unsigned short)(gp.x & 0xffff)), bf2f((unsigned short)(gp.x >> 16)),
            bf2f((unsigned short)(gp.y & 0xffff)), bf2f((unsigned short)(gp.y >> 16)),
            bf2f((unsigned short)(gp.z & 0xffff)), bf2f((unsigned short)(gp.z >> 16)),
            bf2f((unsigned short)(gp.w & 0xffff)), bf2f((unsigned short)(gp.w >> 16))};
        float yv8[8] = {y0.x, y0.y, y0.z, y0.w, y1.x, y1.y, y1.z, y1.w};
#pragma unroll
        for (int e = 0; e < 8; e++) {
            float f = yv8[e] * (gv[e] / (1.f + __expf(-gv[e])));
            sum += f * f;
            sYf[j + e] = f;
        }
    }
    for (int off = 32; off > 0; off >>= 1) sum += __shfl_down(sum, off, 64);
    if ((t & 63) == 0) sW[t >> 6] = sum;
    __syncthreads();
    const float var = (sW[0] + sW[1] + sW[2] + sW[3]) * (1.f / (float)INTER);
    const float rs = rsqrtf(var + EPS);
    for (int j0 = 0; j0 < INTER; j0 += 2048) {
        int j = j0 + t * 8;
        float4 w0 = *(const float4*)(norm_w + j);
        float4 w1 = *(const float4*)(norm_w + j + 4);
        float wv[8] = {w0.x, w0.y, w0.z, w0.w, w1.x, w1.y, w1.z, w1.w};
        unsigned short o[8];
#pragma unroll
        for (int e = 0; e < 8; e++) o[e] = f2bf(sYf[j + e] * wv[e] * rs);
        uint4 ov;
        ov.x = (unsigned int)o[0] | ((unsigned int)o[1] << 16);
        ov.y = (unsigned int)o[2] | ((unsigned int)o[3] << 16);
        ov.z = (unsigned int)o[4] | ((unsigned int)o[5] << 16);
        ov.w = (unsigned int)o[6] | ((unsigned int)o[7] << 16);
        *(uint4*)(yn + (size_t)s * INTER + j) = ov;
    }
}

// ---------------------------------------------------------------------------
extern "C" void kernel_launch(void* const* d_in, const int* in_sizes, int n_in,
                              void* d_out, int out_size, void* d_ws, size_t ws_size,
                              hipStream_t stream)
{
    const float* X       = (const float*)d_in[0];
    const float* W_in    = (const float*)d_in[2];
    const float* conv_w  = (const float*)d_in[3];
    const float* conv_b  = (const float*)d_in[4];
    const float* dt_bias = (const float*)d_in[5];
    const float* A_log   = (const float*)d_in[6];
    const float* Dp      = (const float*)d_in[7];
    const float* norm_w  = (const float*)d_in[8];
    const float* W_out   = (const float*)d_in[9];
    float* out = (float*)d_out;
    float* ws  = (float*)d_ws;

    unsigned short* projbf = (unsigned short*)(ws + OFF_PROJBF);
    float* hbc     = ws + OFF_HBC;
    float* dtg     = ws + OFF_DTG;
    float* dtpart  = ws + OFF_DTPART;
    float* gm      = ws + OFF_GM;
    float* yv      = ws + OFF_YV;
    unsigned short* Xbf    = (unsigned short*)(ws + OFF_R);
    unsigned short* Winbf  = (unsigned short*)(ws + OFF_R + 2097152);
    unsigned short* ynbf   = (unsigned short*)(ws + OFF_R);           // aliases Xbf
    unsigned short* Woutbf = (unsigned short*)(ws + OFF_R + 4194304); // aliases Winbf
    float* part0 = hbc;                 // GEMM2 split-K partials reuse hbc region
    float* part1 = hbc + 4194304;       // (ssm_mfma is hbc's last reader)

    cast_bf16_kernel<<<2048, 256, 0, stream>>>(X, Xbf);
    cast_bf16_kernel<<<8448, 256, 0, stream>>>(W_in, Winbf);

    // GEMM1: proj[:, 0:8448] bf16 MFMA -> bf16 out
    gemm_bt_mfma<<<dim3(GEMM1N / 128, S_LEN / 128, 1), 256, 0, stream>>>(
        Xbf, E_DIM, 0LL, Winbf, E_DIM, 0LL, nullptr, projbf, GEMM1N, 0LL, E_DIM);

    cast_bf16_kernel<<<4096, 256, 0, stream>>>(W_out, Woutbf);

    // dt columns fp32 split-K
    gemm_nt<<<dim3(1, 16, 8), 256, 0, stream>>>(
        X, E_DIM, 256LL, W_in + (size_t)GEMM1N * E_DIM, E_DIM, 256LL,
        dtpart, NH, 131072LL, 256);
    dt_reduce_kernel<<<512, 256, 0, stream>>>(dtpart, dt_bias, dtg);

    conv_silu_kernel<<<dim3(CONVD / 256, S_LEN), 256, 0, stream>>>(
        projbf, conv_w, conv_b, hbc);

    gemm_nt<<<dim3(CS / 64, CS / 128, NCHUNK), 256, 0, stream>>>(
        hbc + INTER + N_DIM, CONVD, (long long)CS * CONVD,
        hbc + INTER,         CONVD, (long long)CS * CONVD,
        gm, CS, (long long)CS * CS, N_DIM);

    ssm_mfma_kernel<<<dim3(NH, NCHUNK), 256, 0, stream>>>(
        hbc, dtg, gm, A_log, Dp, yv);

    norm_kernel<<<dim3(S_LEN), 256, 0, stream>>>(yv, projbf, norm_w, ynbf);

    // GEMM2 split-K=2: partials (K-slices of 2048), then reduce to out
    gemm_bt_mfma<<<dim3(E_DIM / 128, S_LEN / 128, 2), 256, 0, stream>>>(
        ynbf, INTER, 2048LL, Woutbf, INTER, 2048LL,
        part0, nullptr, E_DIM, 4194304LL, 2048);
    addf_kernel<<<4096, 256, 0, stream>>>(part0, part1, out);
}

// Round 5
// 467.917 us; speedup vs baseline: 4.2617x; 1.0543x over previous
//
#include <hip/hip_runtime.h>
#include <math.h>

// Problem constants
#define S_LEN   2048
#define E_DIM   2048
#define NH      64
#define P_DIM   64
#define N_DIM   128
#define CS      256
#define NCHUNK  8
#define INTER   4096
#define CONVD   4352
#define PROJ    8512
#define GEMM1N  8448       // INTER + CONVD = 66*128 exactly
#define EPS     1e-5f

// Workspace layout (float units)
#define OFF_PROJBF 0ull                        // bf16 2048*8448 = 8,650,752 fl
#define OFF_HBC    8650752ull                  // fp32 2048*4352 = 8,912,896 fl
#define OFF_DTG    17563648ull                 // fp32 2048*64
#define OFF_DTPART 17694720ull                 // fp32 8*2048*64
#define OFF_GM     18743296ull                 // fp32 8*256*256
#define OFF_YV     19267584ull                 // fp32 2048*4096
#define OFF_R      27656192ull                 // shared region
// region R:  Xbf = R+0 | Winbf = R+2,097,152 ; aliased after GEMM1:
// ynbf = R+0 | Woutbf = R+4,194,304.
// GEMM2 split-K partials (2 x 2048*2048 fp32) live in the HBC region.

typedef __bf16 bf16x8 __attribute__((ext_vector_type(8)));
typedef float  f32x4  __attribute__((ext_vector_type(4)));
typedef float  f32x16 __attribute__((ext_vector_type(16)));

__device__ __forceinline__ float bf2f(unsigned short u) {
    union { unsigned int i; float f; } v; v.i = ((unsigned int)u) << 16; return v.f;
}
__device__ __forceinline__ unsigned short f2bf(float f) {
    union { float f; unsigned int i; } v; v.f = f;
    unsigned int r = v.i + 0x7FFFu + ((v.i >> 16) & 1u);
    return (unsigned short)(r >> 16);
}
__device__ __forceinline__ void gl_lds16(const void* g, void* l) {
    __builtin_amdgcn_global_load_lds(
        (const __attribute__((address_space(1))) void*)g,
        (__attribute__((address_space(3))) void*)l, 16, 0, 0);
}

// ---------------------------------------------------------------------------
// fp32 -> bf16 cast, 8 elems/thread
// ---------------------------------------------------------------------------
__global__ __launch_bounds__(256) void cast_bf16_kernel(
    const float* __restrict__ in, unsigned short* __restrict__ out)
{
    size_t i = ((size_t)blockIdx.x * 256 + threadIdx.x) * 8;
    float4 a = *(const float4*)(in + i);
    float4 b = *(const float4*)(in + i + 4);
    uint4 o;
    o.x = (unsigned int)f2bf(a.x) | ((unsigned int)f2bf(a.y) << 16);
    o.y = (unsigned int)f2bf(a.z) | ((unsigned int)f2bf(a.w) << 16);
    o.z = (unsigned int)f2bf(b.x) | ((unsigned int)f2bf(b.y) << 16);
    o.w = (unsigned int)f2bf(b.z) | ((unsigned int)f2bf(b.w) << 16);
    *(uint4*)(out + i) = o;
}

// ---------------------------------------------------------------------------
// bf16 MFMA NT GEMM, 32x32x16 MFMA, BK=64, XOR bank swizzle.
// C[m][n] = sum_k A[m][k]*B[n][k]. 128x128 tile, 256 thr (4 waves, each a
// 64x64 sub-tile as 2x2 of 32x32 MFMAs).
// LDS layout: row r holds its 8 k-chunks (8 bf16 each) permuted:
//   slot s stores global chunk  s ^ ((r ^ (r>>3)) & 7)
// -> staging DMA dest stays lane-contiguous (base + 16*lane), and fragment
// ds_read_b128 across 32 consecutive rows hits 32 distinct bank groups
// (rows r, r+8, r+16, r+24 differ via the r>>3 term).
// blockIdx.z shifts A/B by sA/sB (shorts) and Cf by sC (floats): split-K.
// M%128==0, N%128==0, K%64==0.
// ---------------------------------------------------------------------------
__global__ __launch_bounds__(256) void gemm_bt_mfma(
    const unsigned short* __restrict__ A, int lda, long long sA,
    const unsigned short* __restrict__ B, int ldb, long long sB,
    float* __restrict__ Cf, unsigned short* __restrict__ Cb, int ldc,
    long long sC, int K)
{
    __shared__ unsigned short As[128 * 64];   // 16 KB
    __shared__ unsigned short Bs[128 * 64];   // 16 KB
    A += (long long)blockIdx.z * sA;
    B += (long long)blockIdx.z * sB;
    const int t     = threadIdx.x;
    const int m0    = blockIdx.y * 128;
    const int n0    = blockIdx.x * 128;
    const int w     = t >> 6;
    const int lane  = t & 63;
    const int col   = lane & 31;    // col within a 32x32 tile
    const int khalf = lane >> 5;    // which 8-wide k-half of the 16-wide k-step
    const int wm    = (w & 1) * 64;
    const int wn    = (w >> 1) * 64;

    // staging: thread t covers rows srow+32i, slot t&7 holds swizzled chunk
    const int srow  = t >> 3;        // 0..31
    const int sslot = t & 7;
    const unsigned short* Agp[4];
    const unsigned short* Bgp[4];
#pragma unroll
    for (int i = 0; i < 4; i++) {
        const int r   = srow + 32 * i;
        const int gch = sslot ^ ((r ^ (r >> 3)) & 7);
        Agp[i] = A + (size_t)(m0 + r) * lda + gch * 8;
        Bgp[i] = B + (size_t)(n0 + r) * ldb + gch * 8;
    }
    unsigned short* Asl = &As[t * 8];
    unsigned short* Bsl = &Bs[t * 8];

    // fragment read offsets (row-dependent part precomputed)
    int aOff[2], aXor[2], bOff[2], bXor[2];
#pragma unroll
    for (int i = 0; i < 2; i++) {
        const int ra = wm + i * 32 + col;
        aOff[i] = ra * 64; aXor[i] = (ra ^ (ra >> 3)) & 7;
        const int rb = wn + i * 32 + col;
        bOff[i] = rb * 64; bXor[i] = (rb ^ (rb >> 3)) & 7;
    }

    f32x16 acc[2][2];
#pragma unroll
    for (int mi = 0; mi < 2; mi++)
#pragma unroll
        for (int ni = 0; ni < 2; ni++)
#pragma unroll
            for (int e = 0; e < 16; e++) acc[mi][ni][e] = 0.f;

    for (int k0 = 0; k0 < K; k0 += 64) {
        __syncthreads();
#pragma unroll
        for (int i = 0; i < 4; i++) {
            gl_lds16(Agp[i] + k0, Asl + i * 2048);
            gl_lds16(Bgp[i] + k0, Bsl + i * 2048);
        }
        __syncthreads();
#pragma unroll
        for (int ks = 0; ks < 4; ks++) {
            const int ch = ks * 2 + khalf;
            bf16x8 af[2], bfr[2];
#pragma unroll
            for (int i = 0; i < 2; i++) {
                af[i]  = *(const bf16x8*)&As[aOff[i] + ((ch ^ aXor[i]) * 8)];
                bfr[i] = *(const bf16x8*)&Bs[bOff[i] + ((ch ^ bXor[i]) * 8)];
            }
#pragma unroll
            for (int mi = 0; mi < 2; mi++)
#pragma unroll
                for (int ni = 0; ni < 2; ni++)
                    acc[mi][ni] = __builtin_amdgcn_mfma_f32_32x32x16_bf16(
                        af[mi], bfr[ni], acc[mi][ni], 0, 0, 0);
        }
    }

    // Epilogue. 32x32 C/D layout [m74/m101]:
    //   col = lane&31, row = (reg&3) + 8*(reg>>2) + 4*(lane>>5)
    if (Cb) {
#pragma unroll
        for (int mi = 0; mi < 2; mi++)
#pragma unroll
            for (int ni = 0; ni < 2; ni++) {
                const int rbase = m0 + wm + mi * 32 + 4 * khalf;
                const int cc    = n0 + wn + ni * 32 + col;
#pragma unroll
                for (int g = 0; g < 4; g++)
#pragma unroll
                    for (int rr = 0; rr < 4; rr++)
                        Cb[(size_t)(rbase + 8 * g + rr) * ldc + cc] =
                            f2bf(acc[mi][ni][4 * g + rr]);
            }
    } else {
        float* Cz = Cf + (long long)blockIdx.z * sC;
#pragma unroll
        for (int mi = 0; mi < 2; mi++)
#pragma unroll
            for (int ni = 0; ni < 2; ni++) {
                const int rbase = m0 + wm + mi * 32 + 4 * khalf;
                const int cc    = n0 + wn + ni * 32 + col;
#pragma unroll
                for (int g = 0; g < 4; g++)
#pragma unroll
                    for (int rr = 0; rr < 4; rr++)
                        Cz[(size_t)(rbase + 8 * g + rr) * ldc + cc] =
                            acc[mi][ni][4 * g + rr];
            }
    }
}

// ---------------------------------------------------------------------------
// out = a + b (fp32) — split-K reduce for GEMM2
// ---------------------------------------------------------------------------
__global__ __launch_bounds__(256) void addf_kernel(
    const float* __restrict__ a, const float* __restrict__ b,
    float* __restrict__ o)
{
    size_t i = ((size_t)blockIdx.x * 256 + threadIdx.x) * 4;
    float4 x = *(const float4*)(a + i);
    float4 y = *(const float4*)(b + i);
    float4 r = make_float4(x.x + y.x, x.y + y.y, x.z + y.z, x.w + y.w);
    *(float4*)(o + i) = r;
}

// ---------------------------------------------------------------------------
// fp32 NT GEMM (for Gm and dt split-K)
// ---------------------------------------------------------------------------
__global__ __launch_bounds__(256) void gemm_nt(
    const float* __restrict__ A, int lda, long long sA,
    const float* __restrict__ B, int ldb, long long sB,
    float* __restrict__ C, int ldc, long long sC, int K)
{
    A += (long long)blockIdx.z * sA;
    B += (long long)blockIdx.z * sB;
    C += (long long)blockIdx.z * sC;
    const int t  = threadIdx.x;
    const int m0 = blockIdx.y * 128;
    const int n0 = blockIdx.x * 64;
    __shared__ float As[16][132];
    __shared__ float Bs[16][68];
    const int tx = t & 15;
    const int ty = t >> 4;

    const int arow = t & 127;
    const int akh  = (t >> 7) * 8;
    const float* Aload = A + (size_t)(m0 + arow) * (size_t)lda + akh;
    const int brow = t & 63;
    const int bk4  = (t >> 6) * 4;
    const float* Bload = B + (size_t)(n0 + brow) * (size_t)ldb + bk4;

    float acc[8][4];
#pragma unroll
    for (int i = 0; i < 8; i++)
#pragma unroll
        for (int j = 0; j < 4; j++) acc[i][j] = 0.f;

    for (int k0 = 0; k0 < K; k0 += 16) {
        __syncthreads();
        float4 a0 = *(const float4*)(Aload + k0);
        float4 a1 = *(const float4*)(Aload + k0 + 4);
        float4 b0 = *(const float4*)(Bload + k0);
        As[akh + 0][arow] = a0.x; As[akh + 1][arow] = a0.y;
        As[akh + 2][arow] = a0.z; As[akh + 3][arow] = a0.w;
        As[akh + 4][arow] = a1.x; As[akh + 5][arow] = a1.y;
        As[akh + 6][arow] = a1.z; As[akh + 7][arow] = a1.w;
        Bs[bk4 + 0][brow] = b0.x; Bs[bk4 + 1][brow] = b0.y;
        Bs[bk4 + 2][brow] = b0.z; Bs[bk4 + 3][brow] = b0.w;
        __syncthreads();
#pragma unroll
        for (int k = 0; k < 16; k++) {
            float4 a4 = *(const float4*)(&As[k][ty * 8]);
            float4 a5 = *(const float4*)(&As[k][ty * 8 + 4]);
            float4 b4 = *(const float4*)(&Bs[k][tx * 4]);
            float am[8] = {a4.x, a4.y, a4.z, a4.w, a5.x, a5.y, a5.z, a5.w};
            float bn[4] = {b4.x, b4.y, b4.z, b4.w};
#pragma unroll
            for (int i = 0; i < 8; i++)
#pragma unroll
                for (int j = 0; j < 4; j++) acc[i][j] += am[i] * bn[j];
        }
    }
#pragma unroll
    for (int i = 0; i < 8; i++) {
        float4 o = make_float4(acc[i][0], acc[i][1], acc[i][2], acc[i][3]);
        *(float4*)(C + (size_t)(m0 + ty * 8 + i) * (size_t)ldc + n0 + tx * 4) = o;
    }
}

// ---------------------------------------------------------------------------
__global__ __launch_bounds__(256) void dt_reduce_kernel(
    const float* __restrict__ part, const float* __restrict__ dt_bias,
    float* __restrict__ dtg)
{
    const int i = blockIdx.x * 256 + threadIdx.x;
    float x = dt_bias[i & 63];
#pragma unroll
    for (int z = 0; z < 8; z++) x += part[(size_t)z * 131072 + i];
    dtg[i] = (x > 20.f) ? x : log1pf(__expf(x));
}

// ---------------------------------------------------------------------------
__global__ __launch_bounds__(256) void conv_silu_kernel(
    const unsigned short* __restrict__ projbf, const float* __restrict__ conv_w,
    const float* __restrict__ conv_b, float* __restrict__ out)
{
    const int c = blockIdx.x * 256 + threadIdx.x;
    const int s = blockIdx.y;
    const float4 w = *(const float4*)(conv_w + (size_t)c * 4);
    float acc = conv_b[c];
    const size_t base = 4096 + (size_t)c;
    if (s >= 3) acc += bf2f(projbf[(size_t)(s - 3) * GEMM1N + base]) * w.x;
    if (s >= 2) acc += bf2f(projbf[(size_t)(s - 2) * GEMM1N + base]) * w.y;
    if (s >= 1) acc += bf2f(projbf[(size_t)(s - 1) * GEMM1N + base]) * w.z;
    acc += bf2f(projbf[(size_t)s * GEMM1N + base]) * w.w;
    float sig = 1.f / (1.f + __expf(-acc));
    out[(size_t)s * CONVD + c] = acc * sig;
}

// ---------------------------------------------------------------------------
// SSM core, MFMA version (unchanged from round 3)
// ---------------------------------------------------------------------------
__global__ __launch_bounds__(256, 2) void ssm_mfma_kernel(
    const float* __restrict__ hBC, const float* __restrict__ dtg,
    const float* __restrict__ Gm, const float* __restrict__ A_log,
    const float* __restrict__ Dp, float* __restrict__ y)
{
    const int h    = blockIdx.x;
    const int c    = blockIdx.y;
    const int t    = threadIdx.x;
    const int wid  = t >> 6;
    const int lane = t & 63;
    const int lo   = lane & 15;
    const int q    = lane >> 4;

    __shared__ float sAcum[CS], sdt[CS], sD[CS], sEs[CS], sDecay[CS], sScl[CS];
    __shared__ float sWaveSum[4];
    __shared__ unsigned short sHdtT[64 * 264];
    __shared__ unsigned short sStT[64 * 136];
    __shared__ unsigned short sBufB[128 * 72];

    const float A = -__expf(A_log[h]);
    const int row0 = c * CS;
    const float* hid = hBC + (size_t)row0 * CONVD + h * P_DIM;
    const float* Bp  = hBC + (size_t)row0 * CONVD + INTER;
    const float* Cp  = hBC + (size_t)row0 * CONVD + INTER + N_DIM;
    const float* gm  = Gm + (size_t)c * CS * CS;

    float dtv = dtg[(size_t)(row0 + t) * NH + h];
    float v = A * dtv;
    for (int off = 1; off < 64; off <<= 1) {
        float u = __shfl_up(v, off, 64);
        if (lane >= off) v += u;
    }
    if (lane == 63) sWaveSum[wid] = v;
    __syncthreads();
    float pre = 0.f;
    for (int i = 0; i < 4; i++) if (i < wid) pre += sWaveSum[i];
    v += pre;
    sAcum[t] = v;
    sdt[t] = dtv;
    __syncthreads();
    const float AcumEnd = sAcum[CS - 1];
    {
        float ac   = sAcum[t];
        float apre = (t < 64) ? 0.f : sAcum[(t & ~63) - 1];
        sD[t]     = __expf(ac - apre);
        sEs[t]    = __expf(sAcum[t | 63] - ac);
        sDecay[t] = __expf(AcumEnd - ac);
        sScl[t]   = __expf(ac);
    }

    float* stg = (float*)sStT;
    for (int lt = 0; lt < 4; lt++) {
        __syncthreads();
        {
            const int p4 = (t & 15) * 4;
#pragma unroll
            for (int j = 0; j < 4; j++) {
                int l = (t >> 4) + j * 16;
                *(float4*)&stg[l * 64 + p4] =
                    *(const float4*)(hid + (size_t)(lt * 64 + l) * CONVD + p4);
            }
        }
        __syncthreads();
        {
            const int p = t & 63, lq = (t >> 6) * 16;
#pragma unroll
            for (int j = 0; j < 4; j++) {
                ushort4 pk;
                int l0 = lq + j * 4;
                pk.x = f2bf(stg[(l0 + 0) * 64 + p] * sdt[lt * 64 + l0 + 0]);
                pk.y = f2bf(stg[(l0 + 1) * 64 + p] * sdt[lt * 64 + l0 + 1]);
                pk.z = f2bf(stg[(l0 + 2) * 64 + p] * sdt[lt * 64 + l0 + 2]);
                pk.w = f2bf(stg[(l0 + 3) * 64 + p] * sdt[lt * 64 + l0 + 3]);
                *(uint2*)&sHdtT[p * 264 + lt * 64 + l0] = *(uint2*)&pk;
            }
        }
    }

    f32x4 acc2[2][4];
#pragma unroll
    for (int mi = 0; mi < 2; mi++)
#pragma unroll
        for (int ni = 0; ni < 4; ni++) acc2[mi][ni] = (f32x4){0.f, 0.f, 0.f, 0.f};
    const int psub = (wid & 1) * 32;
    const int nsub = (wid >> 1) * 64;

    for (int qt = 0; qt < 4; qt++) {
        for (int hf = 0; hf < 2; hf++) {
            __syncthreads();
            {
                const int n4 = (t & 31) * 4;
#pragma unroll
                for (int j = 0; j < 4; j++) {
                    int r = (t >> 5) + j * 8;
                    *(float4*)&stg[r * 128 + n4] =
                        *(const float4*)(Bp + (size_t)(qt * 64 + hf * 32 + r) * CONVD + n4);
                }
            }
            __syncthreads();
            {
                const int n = t & 127, lc = (t >> 7) * 16;
#pragma unroll
                for (int j = 0; j < 4; j++) {
                    int l0 = lc + j * 4;
                    ushort4 pk;
                    pk.x = f2bf(stg[(l0 + 0) * 128 + n] * sDecay[qt * 64 + hf * 32 + l0 + 0]);
                    pk.y = f2bf(stg[(l0 + 1) * 128 + n] * sDecay[qt * 64 + hf * 32 + l0 + 1]);
                    pk.z = f2bf(stg[(l0 + 2) * 128 + n] * sDecay[qt * 64 + hf * 32 + l0 + 2]);
                    pk.w = f2bf(stg[(l0 + 3) * 128 + n] * sDecay[qt * 64 + hf * 32 + l0 + 3]);
                    *(uint2*)&sBufB[n * 72 + hf * 32 + l0] = *(uint2*)&pk;
                }
            }
        }
        __syncthreads();
#pragma unroll
        for (int ks = 0; ks < 2; ks++) {
            const int k0 = qt * 64 + ks * 32;
            const int kq = ks * 32;
            bf16x8 a2[2], b2[4];
#pragma unroll
            for (int mi = 0; mi < 2; mi++)
                a2[mi] = *(const bf16x8*)&sHdtT[(psub + mi * 16 + lo) * 264 + k0 + q * 8];
#pragma unroll
            for (int ni = 0; ni < 4; ni++)
                b2[ni] = *(const bf16x8*)&sBufB[(nsub + ni * 16 + lo) * 72 + kq + q * 8];
#pragma unroll
            for (int mi = 0; mi < 2; mi++)
#pragma unroll
                for (int ni = 0; ni < 4; ni++)
                    acc2[mi][ni] = __builtin_amdgcn_mfma_f32_16x16x32_bf16(
                        a2[mi], b2[ni], acc2[mi][ni], 0, 0, 0);
        }
    }
    __syncthreads();
#pragma unroll
    for (int mi = 0; mi < 2; mi++)
#pragma unroll
        for (int ni = 0; ni < 4; ni++)
#pragma unroll
            for (int rr = 0; rr < 4; rr++) {
                int p = psub + mi * 16 + q * 4 + rr;
                int n = nsub + ni * 16 + lo;
                sStT[p * 136 + n] = f2bf(acc2[mi][ni][rr]);
            }

    f32x4 accY[4][2][2];
#pragma unroll
    for (int i = 0; i < 4; i++)
#pragma unroll
        for (int mi = 0; mi < 2; mi++)
#pragma unroll
            for (int pi = 0; pi < 2; pi++) accY[i][mi][pi] = (f32x4){0.f, 0.f, 0.f, 0.f};
    const int pcol = (wid & 1) * 32;
    const int rsub = (wid >> 1) * 16;
    unsigned short* Cs = sBufB;

    for (int i = 0; i < 4; i++) {
        __syncthreads();
        {
            const int n4 = (t & 31) * 4;
#pragma unroll
            for (int j = 0; j < 8; j++) {
                int r = (t >> 5) + j * 8;
                float4 cv = *(const float4*)(Cp + (size_t)(i * 64 + r) * CONVD + n4);
                float scl = sScl[i * 64 + r];
                ushort4 pk;
                pk.x = f2bf(cv.x * scl); pk.y = f2bf(cv.y * scl);
                pk.z = f2bf(cv.z * scl); pk.w = f2bf(cv.w * scl);
                *(uint2*)&Cs[r * 136 + n4] = *(uint2*)&pk;
            }
        }
        __syncthreads();
#pragma unroll
        for (int ks = 0; ks < 4; ks++) {
            const int k0 = ks * 32;
            bf16x8 a3[2], b3[2];
#pragma unroll
            for (int mi = 0; mi < 2; mi++)
                a3[mi] = *(const bf16x8*)&Cs[(mi * 32 + rsub + lo) * 136 + k0 + q * 8];
#pragma unroll
            for (int pi = 0; pi < 2; pi++)
                b3[pi] = *(const bf16x8*)&sStT[(pcol + pi * 16 + lo) * 136 + k0 + q * 8];
#pragma unroll
            for (int mi = 0; mi < 2; mi++)
#pragma unroll
                for (int pi = 0; pi < 2; pi++)
                    accY[i][mi][pi] = __builtin_amdgcn_mfma_f32_16x16x32_bf16(
                        a3[mi], b3[pi], accY[i][mi][pi], 0, 0, 0);
        }
    }

    unsigned short* Mt = sBufB;
    for (int i = 0; i < 4; i++) {
        const int nk = 2 * (i + 1);
        for (int mi = 0; mi < 2; mi++) {
            __syncthreads();
            if (wid <= i) {
                float P = 1.f;
                for (int m = wid + 1; m <= i - 1; m++) P *= sD[m * 64 + 63];
                const int s4 = wid * 64 + lo * 4;
                float4 es4 = *(const float4*)&sEs[s4];
#pragma unroll
                for (int j = 0; j < 8; j++) {
                    int lr = q + j * 4;
                    int l  = i * 64 + mi * 32 + lr;
                    float4 g4 = *(const float4*)&gm[(size_t)l * CS + s4];
                    float w0, w1, w2, w3;
                    if (wid == i) {
                        float al = sAcum[l];
                        w0 = (s4 + 0 <= l) ? __expf(al - sAcum[s4 + 0]) : 0.f;
                        w1 = (s4 + 1 <= l) ? __expf(al - sAcum[s4 + 1]) : 0.f;
                        w2 = (s4 + 2 <= l) ? __expf(al - sAcum[s4 + 2]) : 0.f;
                        w3 = (s4 + 3 <= l) ? __expf(al - sAcum[s4 + 3]) : 0.f;
                    } else {
                        float rs = sD[l] * P;
                        w0 = rs * es4.x; w1 = rs * es4.y;
                        w2 = rs * es4.z; w3 = rs * es4.w;
                    }
                    ushort4 pk;
                    pk.x = f2bf(g4.x * w0); pk.y = f2bf(g4.y * w1);
                    pk.z = f2bf(g4.z * w2); pk.w = f2bf(g4.w * w3);
                    *(uint2*)&Mt[lr * 264 + s4] = *(uint2*)&pk;
                }
            }
            __syncthreads();
            for (int ks = 0; ks < nk; ks++) {
                const int k0 = ks * 32;
                bf16x8 am = *(const bf16x8*)&Mt[(rsub + lo) * 264 + k0 + q * 8];
                bf16x8 b1[2];
#pragma unroll
                for (int pi = 0; pi < 2; pi++)
                    b1[pi] = *(const bf16x8*)&sHdtT[(pcol + pi * 16 + lo) * 264 + k0 + q * 8];
#pragma unroll
                for (int pi = 0; pi < 2; pi++)
                    accY[i][mi][pi] = __builtin_amdgcn_mfma_f32_16x16x32_bf16(
                        am, b1[pi], accY[i][mi][pi], 0, 0, 0);
            }
        }
    }

    const float Dh = Dp[h];
#pragma unroll
    for (int i = 0; i < 4; i++)
#pragma unroll
        for (int mi = 0; mi < 2; mi++)
#pragma unroll
            for (int pi = 0; pi < 2; pi++)
#pragma unroll
                for (int rr = 0; rr < 4; rr++) {
                    int l = i * 64 + mi * 32 + rsub + q * 4 + rr;
                    int p = pcol + pi * 16 + lo;
                    float hv = hid[(size_t)l * CONVD + p];
                    y[(size_t)(row0 + l) * INTER + h * P_DIM + p] =
                        accY[i][mi][pi][rr] + Dh * hv;
                }
}

// ---------------------------------------------------------------------------
// Gated RMSNorm (unchanged)
// ---------------------------------------------------------------------------
__global__ __launch_bounds__(256) void norm_kernel(
    const float* __restrict__ y, const unsigned short* __restrict__ projbf,
    const float* __restrict__ norm_w, unsigned short* __restrict__ yn)
{
    const int s = blockIdx.x;
    const int t = threadIdx.x;
    __shared__ float sYf[INTER];
    __shared__ float sW[4];
    const float* yrow = y + (size_t)s * INTER;
    const unsigned short* grow = projbf + (size_t)s * GEMM1N;
    float sum = 0.f;
    for (int j0 = 0; j0 < INTER; j0 += 2048) {
        int j = j0 + t * 8;
        float4 y0 = *(const float4*)(yrow + j);
        float4 y1 = *(const float4*)(yrow + j + 4);
        uint4 gp = *(const uint4*)(grow + j);
        float gv[8] = {
            bf2f((unsigned short)(gp.x & 0xffff)), bf2f((unsigned short)(gp.x >> 16)),
            bf2f((unsigned short)(gp.y & 0xffff)), bf2f((unsigned short)(gp.y >> 16)),
            bf2f((unsigned short)(gp.z & 0xffff)), bf2f((unsigned short)(gp.z >> 16)),
            bf2f((unsigned short)(gp.w & 0xffff)), bf2f((unsigned short)(gp.w >> 16))};
        float yv8[8] = {y0.x, y0.y, y0.z, y0.w, y1.x, y1.y, y1.z, y1.w};
#pragma unroll
        for (int e = 0; e < 8; e++) {
            float f = yv8[e] * (gv[e] / (1.f + __expf(-gv[e])));
            sum += f * f;
            sYf[j + e] = f;
        }
    }
    for (int off = 32; off > 0; off >>= 1) sum += __shfl_down(sum, off, 64);
    if ((t & 63) == 0) sW[t >> 6] = sum;
    __syncthreads();
    const float var = (sW[0] + sW[1] + sW[2] + sW[3]) * (1.f / (float)INTER);
    const float rs = rsqrtf(var + EPS);
    for (int j0 = 0; j0 < INTER; j0 += 2048) {
        int j = j0 + t * 8;
        float4 w0 = *(const float4*)(norm_w + j);
        float4 w1 = *(const float4*)(norm_w + j + 4);
        float wv[8] = {w0.x, w0.y, w0.z, w0.w, w1.x, w1.y, w1.z, w1.w};
        unsigned short o[8];
#pragma unroll
        for (int e = 0; e < 8; e++) o[e] = f2bf(sYf[j + e] * wv[e] * rs);
        uint4 ov;
        ov.x = (unsigned int)o[0] | ((unsigned int)o[1] << 16);
        ov.y = (unsigned int)o[2] | ((unsigned int)o[3] << 16);
        ov.z = (unsigned int)o[4] | ((unsigned int)o[5] << 16);
        ov.w = (unsigned int)o[6] | ((unsigned int)o[7] << 16);
        *(uint4*)(yn + (size_t)s * INTER + j) = ov;
    }
}

// ---------------------------------------------------------------------------
extern "C" void kernel_launch(void* const* d_in, const int* in_sizes, int n_in,
                              void* d_out, int out_size, void* d_ws, size_t ws_size,
                              hipStream_t stream)
{
    const float* X       = (const float*)d_in[0];
    const float* W_in    = (const float*)d_in[2];
    const float* conv_w  = (const float*)d_in[3];
    const float* conv_b  = (const float*)d_in[4];
    const float* dt_bias = (const float*)d_in[5];
    const float* A_log   = (const float*)d_in[6];
    const float* Dp      = (const float*)d_in[7];
    const float* norm_w  = (const float*)d_in[8];
    const float* W_out   = (const float*)d_in[9];
    float* out = (float*)d_out;
    float* ws  = (float*)d_ws;

    unsigned short* projbf = (unsigned short*)(ws + OFF_PROJBF);
    float* hbc     = ws + OFF_HBC;
    float* dtg     = ws + OFF_DTG;
    float* dtpart  = ws + OFF_DTPART;
    float* gm      = ws + OFF_GM;
    float* yv      = ws + OFF_YV;
    unsigned short* Xbf    = (unsigned short*)(ws + OFF_R);
    unsigned short* Winbf  = (unsigned short*)(ws + OFF_R + 2097152);
    unsigned short* ynbf   = (unsigned short*)(ws + OFF_R);           // aliases Xbf
    unsigned short* Woutbf = (unsigned short*)(ws + OFF_R + 4194304); // aliases Winbf
    float* part0 = hbc;                 // GEMM2 split-K partials reuse hbc region
    float* part1 = hbc + 4194304;       // (ssm_mfma is hbc's last reader)

    cast_bf16_kernel<<<2048, 256, 0, stream>>>(X, Xbf);
    cast_bf16_kernel<<<8448, 256, 0, stream>>>(W_in, Winbf);

    // GEMM1: proj[:, 0:8448] bf16 MFMA -> bf16 out
    gemm_bt_mfma<<<dim3(GEMM1N / 128, S_LEN / 128, 1), 256, 0, stream>>>(
        Xbf, E_DIM, 0LL, Winbf, E_DIM, 0LL, nullptr, projbf, GEMM1N, 0LL, E_DIM);

    cast_bf16_kernel<<<4096, 256, 0, stream>>>(W_out, Woutbf);

    // dt columns fp32 split-K
    gemm_nt<<<dim3(1, 16, 8), 256, 0, stream>>>(
        X, E_DIM, 256LL, W_in + (size_t)GEMM1N * E_DIM, E_DIM, 256LL,
        dtpart, NH, 131072LL, 256);
    dt_reduce_kernel<<<512, 256, 0, stream>>>(dtpart, dt_bias, dtg);

    conv_silu_kernel<<<dim3(CONVD / 256, S_LEN), 256, 0, stream>>>(
        projbf, conv_w, conv_b, hbc);

    gemm_nt<<<dim3(CS / 64, CS / 128, NCHUNK), 256, 0, stream>>>(
        hbc + INTER + N_DIM, CONVD, (long long)CS * CONVD,
        hbc + INTER,         CONVD, (long long)CS * CONVD,
        gm, CS, (long long)CS * CS, N_DIM);

    ssm_mfma_kernel<<<dim3(NH, NCHUNK), 256, 0, stream>>>(
        hbc, dtg, gm, A_log, Dp, yv);

    norm_kernel<<<dim3(S_LEN), 256, 0, stream>>>(yv, projbf, norm_w, ynbf);

    // GEMM2 split-K=2: partials (K-slices of 2048), then reduce to out
    gemm_bt_mfma<<<dim3(E_DIM / 128, S_LEN / 128, 2), 256, 0, stream>>>(
        ynbf, INTER, 2048LL, Woutbf, INTER, 2048LL,
        part0, nullptr, E_DIM, 4194304LL, 2048);
    addf_kernel<<<4096, 256, 0, stream>>>(part0, part1, out);
}

// Round 6
// 424.431 us; speedup vs baseline: 4.6983x; 1.1025x over previous
//
#include <hip/hip_runtime.h>
#include <math.h>

// Problem constants
#define S_LEN   2048
#define E_DIM   2048
#define NH      64
#define P_DIM   64
#define N_DIM   128
#define CS      256
#define NCHUNK  8
#define INTER   4096
#define CONVD   4352
#define PROJ    8512
#define GEMM1N  8448       // INTER + CONVD = 66*128 exactly
#define EPS     1e-5f

// Workspace layout (float units)
#define OFF_PROJBF 0ull                        // bf16 2048*8448 = 8,650,752 fl
#define OFF_HBC    8650752ull                  // bf16 2048*4352 = 4,456,448 fl
#define OFF_DTG    13107200ull                 // fp32 2048*64   =   131,072 fl
#define OFF_DTPART 13238272ull                 // fp32 32*2048*64 = 4,194,304 fl
#define OFF_GM     17432576ull                 // fp32 8*256*256 =   524,288 fl
#define OFF_YV     17956864ull                 // fp32 2048*4096 = 8,388,608 fl
#define OFF_R      26345472ull                 // shared region, 10,747,904 fl
// region R: Xbf = R+0 | Winbf = R+2,097,152 ; aliased after GEMM1:
// ynbf = R+0 | Woutbf = R+4,194,304.
// GEMM2 split-K partials (2 x 4,194,304 fl) reuse the PROJBF region
// (last reader of projbf is norm_kernel, which precedes GEMM2).
// ws end = 37,093,376 fl = 148.4 MB (R1 proved >= 175 MB available).

typedef __bf16 bf16x8 __attribute__((ext_vector_type(8)));
typedef float  f32x4  __attribute__((ext_vector_type(4)));
typedef float  f32x16 __attribute__((ext_vector_type(16)));

__device__ __forceinline__ float bf2f(unsigned short u) {
    union { unsigned int i; float f; } v; v.i = ((unsigned int)u) << 16; return v.f;
}
__device__ __forceinline__ unsigned short f2bf(float f) {
    union { float f; unsigned int i; } v; v.f = f;
    unsigned int r = v.i + 0x7FFFu + ((v.i >> 16) & 1u);
    return (unsigned short)(r >> 16);
}
__device__ __forceinline__ void gl_lds16(const void* g, void* l) {
    __builtin_amdgcn_global_load_lds(
        (const __attribute__((address_space(1))) void*)g,
        (__attribute__((address_space(3))) void*)l, 16, 0, 0);
}

// ---------------------------------------------------------------------------
// fp32 -> bf16 cast, 8 elems/thread
// ---------------------------------------------------------------------------
__global__ __launch_bounds__(256) void cast_bf16_kernel(
    const float* __restrict__ in, unsigned short* __restrict__ out)
{
    size_t i = ((size_t)blockIdx.x * 256 + threadIdx.x) * 8;
    float4 a = *(const float4*)(in + i);
    float4 b = *(const float4*)(in + i + 4);
    uint4 o;
    o.x = (unsigned int)f2bf(a.x) | ((unsigned int)f2bf(a.y) << 16);
    o.y = (unsigned int)f2bf(a.z) | ((unsigned int)f2bf(a.w) << 16);
    o.z = (unsigned int)f2bf(b.x) | ((unsigned int)f2bf(b.y) << 16);
    o.w = (unsigned int)f2bf(b.z) | ((unsigned int)f2bf(b.w) << 16);
    *(uint4*)(out + i) = o;
}

// ---------------------------------------------------------------------------
// bf16 MFMA NT GEMM, 32x32x16 MFMA, BK=64, XOR bank swizzle (round-5 kernel).
// C[m][n] = sum_k A[m][k]*B[n][k]. blockIdx.z shifts A/B by sA/sB (shorts)
// and Cf by sC (floats): split-K or batch. M%128==0, N%128==0, K%64==0.
// ---------------------------------------------------------------------------
__global__ __launch_bounds__(256) void gemm_bt_mfma(
    const unsigned short* __restrict__ A, int lda, long long sA,
    const unsigned short* __restrict__ B, int ldb, long long sB,
    float* __restrict__ Cf, unsigned short* __restrict__ Cb, int ldc,
    long long sC, int K)
{
    __shared__ unsigned short As[128 * 64];   // 16 KB
    __shared__ unsigned short Bs[128 * 64];   // 16 KB
    A += (long long)blockIdx.z * sA;
    B += (long long)blockIdx.z * sB;
    const int t     = threadIdx.x;
    const int m0    = blockIdx.y * 128;
    const int n0    = blockIdx.x * 128;
    const int w     = t >> 6;
    const int lane  = t & 63;
    const int col   = lane & 31;
    const int khalf = lane >> 5;
    const int wm    = (w & 1) * 64;
    const int wn    = (w >> 1) * 64;

    const int srow  = t >> 3;
    const int sslot = t & 7;
    const unsigned short* Agp[4];
    const unsigned short* Bgp[4];
#pragma unroll
    for (int i = 0; i < 4; i++) {
        const int r   = srow + 32 * i;
        const int gch = sslot ^ ((r ^ (r >> 3)) & 7);
        Agp[i] = A + (size_t)(m0 + r) * lda + gch * 8;
        Bgp[i] = B + (size_t)(n0 + r) * ldb + gch * 8;
    }
    unsigned short* Asl = &As[t * 8];
    unsigned short* Bsl = &Bs[t * 8];

    int aOff[2], aXor[2], bOff[2], bXor[2];
#pragma unroll
    for (int i = 0; i < 2; i++) {
        const int ra = wm + i * 32 + col;
        aOff[i] = ra * 64; aXor[i] = (ra ^ (ra >> 3)) & 7;
        const int rb = wn + i * 32 + col;
        bOff[i] = rb * 64; bXor[i] = (rb ^ (rb >> 3)) & 7;
    }

    f32x16 acc[2][2];
#pragma unroll
    for (int mi = 0; mi < 2; mi++)
#pragma unroll
        for (int ni = 0; ni < 2; ni++)
#pragma unroll
            for (int e = 0; e < 16; e++) acc[mi][ni][e] = 0.f;

    for (int k0 = 0; k0 < K; k0 += 64) {
        __syncthreads();
#pragma unroll
        for (int i = 0; i < 4; i++) {
            gl_lds16(Agp[i] + k0, Asl + i * 2048);
            gl_lds16(Bgp[i] + k0, Bsl + i * 2048);
        }
        __syncthreads();
#pragma unroll
        for (int ks = 0; ks < 4; ks++) {
            const int ch = ks * 2 + khalf;
            bf16x8 af[2], bfr[2];
#pragma unroll
            for (int i = 0; i < 2; i++) {
                af[i]  = *(const bf16x8*)&As[aOff[i] + ((ch ^ aXor[i]) * 8)];
                bfr[i] = *(const bf16x8*)&Bs[bOff[i] + ((ch ^ bXor[i]) * 8)];
            }
#pragma unroll
            for (int mi = 0; mi < 2; mi++)
#pragma unroll
                for (int ni = 0; ni < 2; ni++)
                    acc[mi][ni] = __builtin_amdgcn_mfma_f32_32x32x16_bf16(
                        af[mi], bfr[ni], acc[mi][ni], 0, 0, 0);
        }
    }

    // Epilogue. 32x32 C/D: col = lane&31, row = (reg&3) + 8*(reg>>2) + 4*(lane>>5)
    if (Cb) {
#pragma unroll
        for (int mi = 0; mi < 2; mi++)
#pragma unroll
            for (int ni = 0; ni < 2; ni++) {
                const int rbase = m0 + wm + mi * 32 + 4 * khalf;
                const int cc    = n0 + wn + ni * 32 + col;
#pragma unroll
                for (int g = 0; g < 4; g++)
#pragma unroll
                    for (int rr = 0; rr < 4; rr++)
                        Cb[(size_t)(rbase + 8 * g + rr) * ldc + cc] =
                            f2bf(acc[mi][ni][4 * g + rr]);
            }
    } else {
        float* Cz = Cf + (long long)blockIdx.z * sC;
#pragma unroll
        for (int mi = 0; mi < 2; mi++)
#pragma unroll
            for (int ni = 0; ni < 2; ni++) {
                const int rbase = m0 + wm + mi * 32 + 4 * khalf;
                const int cc    = n0 + wn + ni * 32 + col;
#pragma unroll
                for (int g = 0; g < 4; g++)
#pragma unroll
                    for (int rr = 0; rr < 4; rr++)
                        Cz[(size_t)(rbase + 8 * g + rr) * ldc + cc] =
                            acc[mi][ni][4 * g + rr];
            }
    }
}

// ---------------------------------------------------------------------------
// out = a + b (fp32) — split-K reduce for GEMM2
// ---------------------------------------------------------------------------
__global__ __launch_bounds__(256) void addf_kernel(
    const float* __restrict__ a, const float* __restrict__ b,
    float* __restrict__ o)
{
    size_t i = ((size_t)blockIdx.x * 256 + threadIdx.x) * 4;
    float4 x = *(const float4*)(a + i);
    float4 y = *(const float4*)(b + i);
    float4 r = make_float4(x.x + y.x, x.y + y.y, x.z + y.z, x.w + y.w);
    *(float4*)(o + i) = r;
}

// ---------------------------------------------------------------------------
// fp32 NT GEMM (dt split-K only now)
// ---------------------------------------------------------------------------
__global__ __launch_bounds__(256) void gemm_nt(
    const float* __restrict__ A, int lda, long long sA,
    const float* __restrict__ B, int ldb, long long sB,
    float* __restrict__ C, int ldc, long long sC, int K)
{
    A += (long long)blockIdx.z * sA;
    B += (long long)blockIdx.z * sB;
    C += (long long)blockIdx.z * sC;
    const int t  = threadIdx.x;
    const int m0 = blockIdx.y * 128;
    const int n0 = blockIdx.x * 64;
    __shared__ float As[16][132];
    __shared__ float Bs[16][68];
    const int tx = t & 15;
    const int ty = t >> 4;

    const int arow = t & 127;
    const int akh  = (t >> 7) * 8;
    const float* Aload = A + (size_t)(m0 + arow) * (size_t)lda + akh;
    const int brow = t & 63;
    const int bk4  = (t >> 6) * 4;
    const float* Bload = B + (size_t)(n0 + brow) * (size_t)ldb + bk4;

    float acc[8][4];
#pragma unroll
    for (int i = 0; i < 8; i++)
#pragma unroll
        for (int j = 0; j < 4; j++) acc[i][j] = 0.f;

    for (int k0 = 0; k0 < K; k0 += 16) {
        __syncthreads();
        float4 a0 = *(const float4*)(Aload + k0);
        float4 a1 = *(const float4*)(Aload + k0 + 4);
        float4 b0 = *(const float4*)(Bload + k0);
        As[akh + 0][arow] = a0.x; As[akh + 1][arow] = a0.y;
        As[akh + 2][arow] = a0.z; As[akh + 3][arow] = a0.w;
        As[akh + 4][arow] = a1.x; As[akh + 5][arow] = a1.y;
        As[akh + 6][arow] = a1.z; As[akh + 7][arow] = a1.w;
        Bs[bk4 + 0][brow] = b0.x; Bs[bk4 + 1][brow] = b0.y;
        Bs[bk4 + 2][brow] = b0.z; Bs[bk4 + 3][brow] = b0.w;
        __syncthreads();
#pragma unroll
        for (int k = 0; k < 16; k++) {
            float4 a4 = *(const float4*)(&As[k][ty * 8]);
            float4 a5 = *(const float4*)(&As[k][ty * 8 + 4]);
            float4 b4 = *(const float4*)(&Bs[k][tx * 4]);
            float am[8] = {a4.x, a4.y, a4.z, a4.w, a5.x, a5.y, a5.z, a5.w};
            float bn[4] = {b4.x, b4.y, b4.z, b4.w};
#pragma unroll
            for (int i = 0; i < 8; i++)
#pragma unroll
                for (int j = 0; j < 4; j++) acc[i][j] += am[i] * bn[j];
        }
    }
#pragma unroll
    for (int i = 0; i < 8; i++) {
        float4 o = make_float4(acc[i][0], acc[i][1], acc[i][2], acc[i][3]);
        *(float4*)(C + (size_t)(m0 + ty * 8 + i) * (size_t)ldc + n0 + tx * 4) = o;
    }
}

// ---------------------------------------------------------------------------
// dt reduce over 32 K-slices
// ---------------------------------------------------------------------------
__global__ __launch_bounds__(256) void dt_reduce_kernel(
    const float* __restrict__ part, const float* __restrict__ dt_bias,
    float* __restrict__ dtg)
{
    const int i = blockIdx.x * 256 + threadIdx.x;
    float x = dt_bias[i & 63];
#pragma unroll
    for (int z = 0; z < 32; z++) x += part[(size_t)z * 131072 + i];
    dtg[i] = (x > 20.f) ? x : log1pf(__expf(x));
}

// ---------------------------------------------------------------------------
// Causal depthwise conv (K=4) + bias + SiLU, 8 outputs/thread along s.
// Reads bf16 proj cols [4096,8448), writes bf16 hBC (pitch CONVD).
// ---------------------------------------------------------------------------
__global__ __launch_bounds__(256) void conv_silu8_kernel(
    const unsigned short* __restrict__ projbf, const float* __restrict__ conv_w,
    const float* __restrict__ conv_b, unsigned short* __restrict__ out)
{
    const int c  = blockIdx.x * 256 + threadIdx.x;   // [0, 4352)
    const int s0 = blockIdx.y * 8;
    const float4 w = *(const float4*)(conv_w + (size_t)c * 4);
    const float b = conv_b[c];
    const size_t base = 4096 + (size_t)c;
    float v[11];
#pragma unroll
    for (int m = 0; m < 11; m++) {
        int s = s0 - 3 + m;
        v[m] = (s >= 0) ? bf2f(projbf[(size_t)s * GEMM1N + base]) : 0.f;
    }
#pragma unroll
    for (int j = 0; j < 8; j++) {
        float acc = b + v[j] * w.x + v[j + 1] * w.y + v[j + 2] * w.z + v[j + 3] * w.w;
        float sig = 1.f / (1.f + __expf(-acc));
        out[(size_t)(s0 + j) * CONVD + c] = f2bf(acc * sig);
    }
}

// ---------------------------------------------------------------------------
// SSM core, MFMA, bf16 hBC input. One block per (head h, chunk c).
// ---------------------------------------------------------------------------
__global__ __launch_bounds__(256, 2) void ssm_mfma_kernel(
    const unsigned short* __restrict__ hBC, const float* __restrict__ dtg,
    const float* __restrict__ Gm, const float* __restrict__ A_log,
    const float* __restrict__ Dp, float* __restrict__ y)
{
    const int h    = blockIdx.x;
    const int c    = blockIdx.y;
    const int t    = threadIdx.x;
    const int wid  = t >> 6;
    const int lane = t & 63;
    const int lo   = lane & 15;
    const int q    = lane >> 4;

    __shared__ float sAcum[CS], sdt[CS], sD[CS], sEs[CS], sDecay[CS], sScl[CS];
    __shared__ float sWaveSum[4];
    __shared__ unsigned short sHdtT[64 * 264];   // 33792 B
    __shared__ unsigned short sStT[64 * 136];    // 17408 B (doubles as staging)
    __shared__ unsigned short sBufB[128 * 72];   // 18432 B

    const float A = -__expf(A_log[h]);
    const int row0 = c * CS;
    const unsigned short* hid = hBC + (size_t)row0 * CONVD + h * P_DIM;
    const unsigned short* Bp  = hBC + (size_t)row0 * CONVD + INTER;
    const unsigned short* Cp  = hBC + (size_t)row0 * CONVD + INTER + N_DIM;
    const float* gm = Gm + (size_t)c * CS * CS;

    float dtv = dtg[(size_t)(row0 + t) * NH + h];
    float v = A * dtv;
    for (int off = 1; off < 64; off <<= 1) {
        float u = __shfl_up(v, off, 64);
        if (lane >= off) v += u;
    }
    if (lane == 63) sWaveSum[wid] = v;
    __syncthreads();
    float pre = 0.f;
    for (int i = 0; i < 4; i++) if (i < wid) pre += sWaveSum[i];
    v += pre;
    sAcum[t] = v;
    sdt[t] = dtv;
    __syncthreads();
    const float AcumEnd = sAcum[CS - 1];
    {
        float ac   = sAcum[t];
        float apre = (t < 64) ? 0.f : sAcum[(t & ~63) - 1];
        sD[t]     = __expf(ac - apre);
        sEs[t]    = __expf(sAcum[t | 63] - ac);
        sDecay[t] = __expf(AcumEnd - ac);
        sScl[t]   = __expf(ac);
    }

    // ---- build HdtT (bf16 [p][s], pitch 264) via bf16 LDS staging ----
    unsigned short* stgu = sStT;   // staging overlay (<= 16 KB used)
    for (int lt = 0; lt < 4; lt++) {
        __syncthreads();
        {
            const int c8 = (t & 7) * 8;
#pragma unroll
            for (int j = 0; j < 2; j++) {
                int l = (t >> 3) + 32 * j;
                *(uint4*)&stgu[l * 64 + c8] =
                    *(const uint4*)(hid + (size_t)(lt * 64 + l) * CONVD + c8);
            }
        }
        __syncthreads();
        {
            const int p = t & 63, lq = (t >> 6) * 16;
#pragma unroll
            for (int j = 0; j < 4; j++) {
                ushort4 pk;
                int l0 = lq + j * 4;
                pk.x = f2bf(bf2f(stgu[(l0 + 0) * 64 + p]) * sdt[lt * 64 + l0 + 0]);
                pk.y = f2bf(bf2f(stgu[(l0 + 1) * 64 + p]) * sdt[lt * 64 + l0 + 1]);
                pk.z = f2bf(bf2f(stgu[(l0 + 2) * 64 + p]) * sdt[lt * 64 + l0 + 2]);
                pk.w = f2bf(bf2f(stgu[(l0 + 3) * 64 + p]) * sdt[lt * 64 + l0 + 3]);
                *(uint2*)&sHdtT[p * 264 + lt * 64 + l0] = *(uint2*)&pk;
            }
        }
    }

    // ---- matmul-2: statesT[p][n] ----
    f32x4 acc2[2][4];
#pragma unroll
    for (int mi = 0; mi < 2; mi++)
#pragma unroll
        for (int ni = 0; ni < 4; ni++) acc2[mi][ni] = (f32x4){0.f, 0.f, 0.f, 0.f};
    const int psub = (wid & 1) * 32;
    const int nsub = (wid >> 1) * 64;

    for (int qt = 0; qt < 4; qt++) {
        for (int hf = 0; hf < 2; hf++) {
            __syncthreads();
            {
                const int n8 = (t & 15) * 8;
#pragma unroll
                for (int j = 0; j < 2; j++) {
                    int r = (t >> 4) + 16 * j;   // 0..31
                    *(uint4*)&stgu[r * 128 + n8] =
                        *(const uint4*)(Bp + (size_t)(qt * 64 + hf * 32 + r) * CONVD + n8);
                }
            }
            __syncthreads();
            {
                const int n = t & 127, lc = (t >> 7) * 16;
#pragma unroll
                for (int j = 0; j < 4; j++) {
                    int l0 = lc + j * 4;
                    ushort4 pk;
                    pk.x = f2bf(bf2f(stgu[(l0 + 0) * 128 + n]) * sDecay[qt * 64 + hf * 32 + l0 + 0]);
                    pk.y = f2bf(bf2f(stgu[(l0 + 1) * 128 + n]) * sDecay[qt * 64 + hf * 32 + l0 + 1]);
                    pk.z = f2bf(bf2f(stgu[(l0 + 2) * 128 + n]) * sDecay[qt * 64 + hf * 32 + l0 + 2]);
                    pk.w = f2bf(bf2f(stgu[(l0 + 3) * 128 + n]) * sDecay[qt * 64 + hf * 32 + l0 + 3]);
                    *(uint2*)&sBufB[n * 72 + hf * 32 + l0] = *(uint2*)&pk;
                }
            }
        }
        __syncthreads();
#pragma unroll
        for (int ks = 0; ks < 2; ks++) {
            const int k0 = qt * 64 + ks * 32;
            const int kq = ks * 32;
            bf16x8 a2[2], b2[4];
#pragma unroll
            for (int mi = 0; mi < 2; mi++)
                a2[mi] = *(const bf16x8*)&sHdtT[(psub + mi * 16 + lo) * 264 + k0 + q * 8];
#pragma unroll
            for (int ni = 0; ni < 4; ni++)
                b2[ni] = *(const bf16x8*)&sBufB[(nsub + ni * 16 + lo) * 72 + kq + q * 8];
#pragma unroll
            for (int mi = 0; mi < 2; mi++)
#pragma unroll
                for (int ni = 0; ni < 4; ni++)
                    acc2[mi][ni] = __builtin_amdgcn_mfma_f32_16x16x32_bf16(
                        a2[mi], b2[ni], acc2[mi][ni], 0, 0, 0);
        }
    }
    __syncthreads();
#pragma unroll
    for (int mi = 0; mi < 2; mi++)
#pragma unroll
        for (int ni = 0; ni < 4; ni++)
#pragma unroll
            for (int rr = 0; rr < 4; rr++) {
                int p = psub + mi * 16 + q * 4 + rr;
                int n = nsub + ni * 16 + lo;
                sStT[p * 136 + n] = f2bf(acc2[mi][ni][rr]);
            }

    // ---- matmul-3: Yoff ----
    f32x4 accY[4][2][2];
#pragma unroll
    for (int i = 0; i < 4; i++)
#pragma unroll
        for (int mi = 0; mi < 2; mi++)
#pragma unroll
            for (int pi = 0; pi < 2; pi++) accY[i][mi][pi] = (f32x4){0.f, 0.f, 0.f, 0.f};
    const int pcol = (wid & 1) * 32;
    const int rsub = (wid >> 1) * 16;
    unsigned short* Cs = sBufB;

    for (int i = 0; i < 4; i++) {
        __syncthreads();
        {
            const int n8 = (t & 15) * 8;
#pragma unroll
            for (int j = 0; j < 4; j++) {
                int r = (t >> 4) + 16 * j;   // 0..63
                uint4 cv = *(const uint4*)(Cp + (size_t)(i * 64 + r) * CONVD + n8);
                float scl = sScl[i * 64 + r];
                const unsigned short* cu = (const unsigned short*)&cv;
                ushort4 p0, p1;
                p0.x = f2bf(bf2f(cu[0]) * scl); p0.y = f2bf(bf2f(cu[1]) * scl);
                p0.z = f2bf(bf2f(cu[2]) * scl); p0.w = f2bf(bf2f(cu[3]) * scl);
                p1.x = f2bf(bf2f(cu[4]) * scl); p1.y = f2bf(bf2f(cu[5]) * scl);
                p1.z = f2bf(bf2f(cu[6]) * scl); p1.w = f2bf(bf2f(cu[7]) * scl);
                *(uint2*)&Cs[r * 136 + n8]     = *(uint2*)&p0;
                *(uint2*)&Cs[r * 136 + n8 + 4] = *(uint2*)&p1;
            }
        }
        __syncthreads();
#pragma unroll
        for (int ks = 0; ks < 4; ks++) {
            const int k0 = ks * 32;
            bf16x8 a3[2], b3[2];
#pragma unroll
            for (int mi = 0; mi < 2; mi++)
                a3[mi] = *(const bf16x8*)&Cs[(mi * 32 + rsub + lo) * 136 + k0 + q * 8];
#pragma unroll
            for (int pi = 0; pi < 2; pi++)
                b3[pi] = *(const bf16x8*)&sStT[(pcol + pi * 16 + lo) * 136 + k0 + q * 8];
#pragma unroll
            for (int mi = 0; mi < 2; mi++)
#pragma unroll
                for (int pi = 0; pi < 2; pi++)
                    accY[i][mi][pi] = __builtin_amdgcn_mfma_f32_16x16x32_bf16(
                        a3[mi], b3[pi], accY[i][mi][pi], 0, 0, 0);
        }
    }

    // ---- matmul-1: Yd (triangular) ----
    unsigned short* Mt = sBufB;
    for (int i = 0; i < 4; i++) {
        const int nk = 2 * (i + 1);
        for (int mi = 0; mi < 2; mi++) {
            __syncthreads();
            if (wid <= i) {
                float P = 1.f;
                for (int m = wid + 1; m <= i - 1; m++) P *= sD[m * 64 + 63];
                const int s4 = wid * 64 + lo * 4;
                float4 es4 = *(const float4*)&sEs[s4];
#pragma unroll
                for (int j = 0; j < 8; j++) {
                    int lr = q + j * 4;
                    int l  = i * 64 + mi * 32 + lr;
                    float4 g4 = *(const float4*)&gm[(size_t)l * CS + s4];
                    float w0, w1, w2, w3;
                    if (wid == i) {
                        float al = sAcum[l];
                        w0 = (s4 + 0 <= l) ? __expf(al - sAcum[s4 + 0]) : 0.f;
                        w1 = (s4 + 1 <= l) ? __expf(al - sAcum[s4 + 1]) : 0.f;
                        w2 = (s4 + 2 <= l) ? __expf(al - sAcum[s4 + 2]) : 0.f;
                        w3 = (s4 + 3 <= l) ? __expf(al - sAcum[s4 + 3]) : 0.f;
                    } else {
                        float rs = sD[l] * P;
                        w0 = rs * es4.x; w1 = rs * es4.y;
                        w2 = rs * es4.z; w3 = rs * es4.w;
                    }
                    ushort4 pk;
                    pk.x = f2bf(g4.x * w0); pk.y = f2bf(g4.y * w1);
                    pk.z = f2bf(g4.z * w2); pk.w = f2bf(g4.w * w3);
                    *(uint2*)&Mt[lr * 264 + s4] = *(uint2*)&pk;
                }
            }
            __syncthreads();
            for (int ks = 0; ks < nk; ks++) {
                const int k0 = ks * 32;
                bf16x8 am = *(const bf16x8*)&Mt[(rsub + lo) * 264 + k0 + q * 8];
                bf16x8 b1[2];
#pragma unroll
                for (int pi = 0; pi < 2; pi++)
                    b1[pi] = *(const bf16x8*)&sHdtT[(pcol + pi * 16 + lo) * 264 + k0 + q * 8];
#pragma unroll
                for (int pi = 0; pi < 2; pi++)
                    accY[i][mi][pi] = __builtin_amdgcn_mfma_f32_16x16x32_bf16(
                        am, b1[pi], accY[i][mi][pi], 0, 0, 0);
            }
        }
    }

    // ---- epilogue ----
    const float Dh = Dp[h];
#pragma unroll
    for (int i = 0; i < 4; i++)
#pragma unroll
        for (int mi = 0; mi < 2; mi++)
#pragma unroll
            for (int pi = 0; pi < 2; pi++)
#pragma unroll
                for (int rr = 0; rr < 4; rr++) {
                    int l = i * 64 + mi * 32 + rsub + q * 4 + rr;
                    int p = pcol + pi * 16 + lo;
                    float hv = bf2f(hid[(size_t)l * CONVD + p]);
                    y[(size_t)(row0 + l) * INTER + h * P_DIM + p] =
                        accY[i][mi][pi][rr] + Dh * hv;
                }
}

// ---------------------------------------------------------------------------
// Gated RMSNorm (unchanged)
// ---------------------------------------------------------------------------
__global__ __launch_bounds__(256) void norm_kernel(
    const float* __restrict__ y, const unsigned short* __restrict__ projbf,
    const float* __restrict__ norm_w, unsigned short* __restrict__ yn)
{
    const int s = blockIdx.x;
    const int t = threadIdx.x;
    __shared__ float sYf[INTER];
    __shared__ float sW[4];
    const float* yrow = y + (size_t)s * INTER;
    const unsigned short* grow = projbf + (size_t)s * GEMM1N;
    float sum = 0.f;
    for (int j0 = 0; j0 < INTER; j0 += 2048) {
        int j = j0 + t * 8;
        float4 y0 = *(const float4*)(yrow + j);
        float4 y1 = *(const float4*)(yrow + j + 4);
        uint4 gp = *(const uint4*)(grow + j);
        float gv[8] = {
            bf2f((unsigned short)(gp.x & 0xffff)), bf2f((unsigned short)(gp.x >> 16)),
            bf2f((unsigned short)(gp.y & 0xffff)), bf2f((unsigned short)(gp.y >> 16)),
            bf2f((unsigned short)(gp.z & 0xffff)), bf2f((unsigned short)(gp.z >> 16)),
            bf2f((unsigned short)(gp.w & 0xffff)), bf2f((unsigned short)(gp.w >> 16))};
        float yv8[8] = {y0.x, y0.y, y0.z, y0.w, y1.x, y1.y, y1.z, y1.w};
#pragma unroll
        for (int e = 0; e < 8; e++) {
            float f = yv8[e] * (gv[e] / (1.f + __expf(-gv[e])));
            sum += f * f;
            sYf[j + e] = f;
        }
    }
    for (int off = 32; off > 0; off >>= 1) sum += __shfl_down(sum, off, 64);
    if ((t & 63) == 0) sW[t >> 6] = sum;
    __syncthreads();
    const float var = (sW[0] + sW[1] + sW[2] + sW[3]) * (1.f / (float)INTER);
    const float rs = rsqrtf(var + EPS);
    for (int j0 = 0; j0 < INTER; j0 += 2048) {
        int j = j0 + t * 8;
        float4 w0 = *(const float4*)(norm_w + j);
        float4 w1 = *(const float4*)(norm_w + j + 4);
        float wv[8] = {w0.x, w0.y, w0.z, w0.w, w1.x, w1.y, w1.z, w1.w};
        unsigned short o[8];
#pragma unroll
        for (int e = 0; e < 8; e++) o[e] = f2bf(sYf[j + e] * wv[e] * rs);
        uint4 ov;
        ov.x = (unsigned int)o[0] | ((unsigned int)o[1] << 16);
        ov.y = (unsigned int)o[2] | ((unsigned int)o[3] << 16);
        ov.z = (unsigned int)o[4] | ((unsigned int)o[5] << 16);
        ov.w = (unsigned int)o[6] | ((unsigned int)o[7] << 16);
        *(uint4*)(yn + (size_t)s * INTER + j) = ov;
    }
}

// ---------------------------------------------------------------------------
extern "C" void kernel_launch(void* const* d_in, const int* in_sizes, int n_in,
                              void* d_out, int out_size, void* d_ws, size_t ws_size,
                              hipStream_t stream)
{
    const float* X       = (const float*)d_in[0];
    const float* W_in    = (const float*)d_in[2];
    const float* conv_w  = (const float*)d_in[3];
    const float* conv_b  = (const float*)d_in[4];
    const float* dt_bias = (const float*)d_in[5];
    const float* A_log   = (const float*)d_in[6];
    const float* Dp      = (const float*)d_in[7];
    const float* norm_w  = (const float*)d_in[8];
    const float* W_out   = (const float*)d_in[9];
    float* out = (float*)d_out;
    float* ws  = (float*)d_ws;

    unsigned short* projbf = (unsigned short*)(ws + OFF_PROJBF);
    unsigned short* hbc16  = (unsigned short*)(ws + OFF_HBC);
    float* dtg     = ws + OFF_DTG;
    float* dtpart  = ws + OFF_DTPART;
    float* gm      = ws + OFF_GM;
    float* yv      = ws + OFF_YV;
    unsigned short* Xbf    = (unsigned short*)(ws + OFF_R);
    unsigned short* Winbf  = (unsigned short*)(ws + OFF_R + 2097152);
    unsigned short* ynbf   = (unsigned short*)(ws + OFF_R);           // aliases Xbf
    unsigned short* Woutbf = (unsigned short*)(ws + OFF_R + 4194304); // aliases Winbf
    float* part0 = ws + OFF_PROJBF;       // GEMM2 partials reuse projbf region
    float* part1 = part0 + 4194304;       // (norm is projbf's last reader)

    cast_bf16_kernel<<<2048, 256, 0, stream>>>(X, Xbf);
    cast_bf16_kernel<<<8448, 256, 0, stream>>>(W_in, Winbf);

    // GEMM1: proj[:, 0:8448] bf16 MFMA -> bf16 out
    gemm_bt_mfma<<<dim3(GEMM1N / 128, S_LEN / 128, 1), 256, 0, stream>>>(
        Xbf, E_DIM, 0LL, Winbf, E_DIM, 0LL, nullptr, projbf, GEMM1N, 0LL, E_DIM);

    cast_bf16_kernel<<<4096, 256, 0, stream>>>(W_out, Woutbf);

    // dt columns fp32, split-K=32 (512 blocks)
    gemm_nt<<<dim3(1, 16, 32), 256, 0, stream>>>(
        X, E_DIM, 64LL, W_in + (size_t)GEMM1N * E_DIM, E_DIM, 64LL,
        dtpart, NH, 131072LL, 64);
    dt_reduce_kernel<<<512, 256, 0, stream>>>(dtpart, dt_bias, dtg);

    // conv + silu -> bf16 hBC (8 outputs/thread)
    conv_silu8_kernel<<<dim3(CONVD / 256, S_LEN / 8), 256, 0, stream>>>(
        projbf, conv_w, conv_b, hbc16);

    // Gm[c] = Cm_c @ Bm_c^T via bf16 MFMA (fp32 out)
    gemm_bt_mfma<<<dim3(CS / 128, CS / 128, NCHUNK), 256, 0, stream>>>(
        hbc16 + INTER + N_DIM, CONVD, (long long)CS * CONVD,
        hbc16 + INTER,         CONVD, (long long)CS * CONVD,
        gm, nullptr, CS, (long long)CS * CS, N_DIM);

    ssm_mfma_kernel<<<dim3(NH, NCHUNK), 256, 0, stream>>>(
        hbc16, dtg, gm, A_log, Dp, yv);

    norm_kernel<<<dim3(S_LEN), 256, 0, stream>>>(yv, projbf, norm_w, ynbf);

    // GEMM2 split-K=2: partials, then reduce to out
    gemm_bt_mfma<<<dim3(E_DIM / 128, S_LEN / 128, 2), 256, 0, stream>>>(
        ynbf, INTER, 2048LL, Woutbf, INTER, 2048LL,
        part0, nullptr, E_DIM, 4194304LL, 2048);
    addf_kernel<<<4096, 256, 0, stream>>>(part0, part1, out);
}

// Round 7
// 421.572 us; speedup vs baseline: 4.7302x; 1.0068x over previous
//
#include <hip/hip_runtime.h>
#include <math.h>

// Problem constants
#define S_LEN   2048
#define E_DIM   2048
#define NH      64
#define P_DIM   64
#define N_DIM   128
#define CS      256
#define NCHUNK  8
#define INTER   4096
#define CONVD   4352
#define PROJ    8512
#define GEMM1N  8448       // INTER + CONVD = 66*128 exactly
#define EPS     1e-5f

// Workspace layout (float units)
#define OFF_PROJBF 0ull                        // bf16 2048*8448 = 8,650,752 fl
#define OFF_HBC    8650752ull                  // bf16 2048*4352 = 4,456,448 fl
#define OFF_DTG    13107200ull                 // fp32 2048*64   =   131,072 fl
#define OFF_DTPART 13238272ull                 // fp32 32*2048*64 = 4,194,304 fl
#define OFF_GM     17432576ull                 // fp32 8*256*256 =   524,288 fl
#define OFF_YV     17956864ull                 // fp32 2048*4096 = 8,388,608 fl
#define OFF_R      26345472ull                 // Xbf(2,097,152 fl) + Winbf(8,650,752 fl)
#define OFF_WOUT   37093376ull                 // bf16 2048*4096 = 2,097,152 fl
// ws end = 39,190,528 fl = 156.8 MB (R1 proved >= 175 MB available).
// ynbf aliases Xbf (R+0) — written by norm, after GEMM1's last read of Xbf.
// GEMM2 split-K=4 partials: 4 x 4,194,304 fl at ws[0 .. 16,777,216) — the
// projbf/hbc/dtg/dtpart regions, all dead before GEMM2 launches.

typedef __bf16 bf16x8 __attribute__((ext_vector_type(8)));
typedef float  f32x4  __attribute__((ext_vector_type(4)));
typedef float  f32x16 __attribute__((ext_vector_type(16)));

__device__ __forceinline__ float bf2f(unsigned short u) {
    union { unsigned int i; float f; } v; v.i = ((unsigned int)u) << 16; return v.f;
}
__device__ __forceinline__ unsigned short f2bf(float f) {
    union { float f; unsigned int i; } v; v.f = f;
    unsigned int r = v.i + 0x7FFFu + ((v.i >> 16) & 1u);
    return (unsigned short)(r >> 16);
}
__device__ __forceinline__ void gl_lds16(const void* g, void* l) {
    __builtin_amdgcn_global_load_lds(
        (const __attribute__((address_space(1))) void*)g,
        (__attribute__((address_space(3))) void*)l, 16, 0, 0);
}

// ---------------------------------------------------------------------------
// merged fp32 -> bf16 cast of X / W_in[0:8448] / W_out (one launch)
// 2048 elems per block.
// ---------------------------------------------------------------------------
__global__ __launch_bounds__(256) void cast3_kernel(
    const float* __restrict__ X, const float* __restrict__ Win,
    const float* __restrict__ Wout, unsigned short* __restrict__ Xbf,
    unsigned short* __restrict__ Winbf, unsigned short* __restrict__ Woutbf)
{
    const int blk = blockIdx.x;
    const float* src; unsigned short* dst; size_t off;
    if (blk < 2048)       { src = X;    dst = Xbf;    off = (size_t)blk * 2048; }
    else if (blk < 10496) { src = Win;  dst = Winbf;  off = (size_t)(blk - 2048) * 2048; }
    else                  { src = Wout; dst = Woutbf; off = (size_t)(blk - 10496) * 2048; }
    size_t i = off + (size_t)threadIdx.x * 8;
    float4 a = *(const float4*)(src + i);
    float4 b = *(const float4*)(src + i + 4);
    uint4 o;
    o.x = (unsigned int)f2bf(a.x) | ((unsigned int)f2bf(a.y) << 16);
    o.y = (unsigned int)f2bf(a.z) | ((unsigned int)f2bf(a.w) << 16);
    o.z = (unsigned int)f2bf(b.x) | ((unsigned int)f2bf(b.y) << 16);
    o.w = (unsigned int)f2bf(b.z) | ((unsigned int)f2bf(b.w) << 16);
    *(uint4*)(dst + i) = o;
}

// ---------------------------------------------------------------------------
// bf16 MFMA NT GEMM, 32x32x16 MFMA, BK=64, XOR bank swizzle.
// C[m][n] = sum_k A[m][k]*B[n][k]. blockIdx.z shifts A/B by sA/sB (shorts)
// and Cf by sC (floats). mswap=1: m-tile = blockIdx.x (m-fastest dispatch ->
// square co-resident set -> L3/HBM fetch ~working-set not ~streams).
// M%128==0, N%128==0, K%64==0.
// ---------------------------------------------------------------------------
__global__ __launch_bounds__(256) void gemm_bt_mfma(
    const unsigned short* __restrict__ A, int lda, long long sA,
    const unsigned short* __restrict__ B, int ldb, long long sB,
    float* __restrict__ Cf, unsigned short* __restrict__ Cb, int ldc,
    long long sC, int K, int mswap)
{
    __shared__ unsigned short As[128 * 64];   // 16 KB
    __shared__ unsigned short Bs[128 * 64];   // 16 KB
    A += (long long)blockIdx.z * sA;
    B += (long long)blockIdx.z * sB;
    const int t     = threadIdx.x;
    const int m0    = (mswap ? blockIdx.x : blockIdx.y) * 128;
    const int n0    = (mswap ? blockIdx.y : blockIdx.x) * 128;
    const int w     = t >> 6;
    const int lane  = t & 63;
    const int col   = lane & 31;
    const int khalf = lane >> 5;
    const int wm    = (w & 1) * 64;
    const int wn    = (w >> 1) * 64;

    const int srow  = t >> 3;
    const int sslot = t & 7;
    const unsigned short* Agp[4];
    const unsigned short* Bgp[4];
#pragma unroll
    for (int i = 0; i < 4; i++) {
        const int r   = srow + 32 * i;
        const int gch = sslot ^ ((r ^ (r >> 3)) & 7);
        Agp[i] = A + (size_t)(m0 + r) * lda + gch * 8;
        Bgp[i] = B + (size_t)(n0 + r) * ldb + gch * 8;
    }
    unsigned short* Asl = &As[t * 8];
    unsigned short* Bsl = &Bs[t * 8];

    int aOff[2], aXor[2], bOff[2], bXor[2];
#pragma unroll
    for (int i = 0; i < 2; i++) {
        const int ra = wm + i * 32 + col;
        aOff[i] = ra * 64; aXor[i] = (ra ^ (ra >> 3)) & 7;
        const int rb = wn + i * 32 + col;
        bOff[i] = rb * 64; bXor[i] = (rb ^ (rb >> 3)) & 7;
    }

    f32x16 acc[2][2];
#pragma unroll
    for (int mi = 0; mi < 2; mi++)
#pragma unroll
        for (int ni = 0; ni < 2; ni++)
#pragma unroll
            for (int e = 0; e < 16; e++) acc[mi][ni][e] = 0.f;

    for (int k0 = 0; k0 < K; k0 += 64) {
        __syncthreads();
#pragma unroll
        for (int i = 0; i < 4; i++) {
            gl_lds16(Agp[i] + k0, Asl + i * 2048);
            gl_lds16(Bgp[i] + k0, Bsl + i * 2048);
        }
        __syncthreads();
#pragma unroll
        for (int ks = 0; ks < 4; ks++) {
            const int ch = ks * 2 + khalf;
            bf16x8 af[2], bfr[2];
#pragma unroll
            for (int i = 0; i < 2; i++) {
                af[i]  = *(const bf16x8*)&As[aOff[i] + ((ch ^ aXor[i]) * 8)];
                bfr[i] = *(const bf16x8*)&Bs[bOff[i] + ((ch ^ bXor[i]) * 8)];
            }
#pragma unroll
            for (int mi = 0; mi < 2; mi++)
#pragma unroll
                for (int ni = 0; ni < 2; ni++)
                    acc[mi][ni] = __builtin_amdgcn_mfma_f32_32x32x16_bf16(
                        af[mi], bfr[ni], acc[mi][ni], 0, 0, 0);
        }
    }

    // Epilogue. 32x32 C/D: col = lane&31, row = (reg&3) + 8*(reg>>2) + 4*(lane>>5)
    if (Cb) {
#pragma unroll
        for (int mi = 0; mi < 2; mi++)
#pragma unroll
            for (int ni = 0; ni < 2; ni++) {
                const int rbase = m0 + wm + mi * 32 + 4 * khalf;
                const int cc    = n0 + wn + ni * 32 + col;
#pragma unroll
                for (int g = 0; g < 4; g++)
#pragma unroll
                    for (int rr = 0; rr < 4; rr++)
                        Cb[(size_t)(rbase + 8 * g + rr) * ldc + cc] =
                            f2bf(acc[mi][ni][4 * g + rr]);
            }
    } else {
        float* Cz = Cf + (long long)blockIdx.z * sC;
#pragma unroll
        for (int mi = 0; mi < 2; mi++)
#pragma unroll
            for (int ni = 0; ni < 2; ni++) {
                const int rbase = m0 + wm + mi * 32 + 4 * khalf;
                const int cc    = n0 + wn + ni * 32 + col;
#pragma unroll
                for (int g = 0; g < 4; g++)
#pragma unroll
                    for (int rr = 0; rr < 4; rr++)
                        Cz[(size_t)(rbase + 8 * g + rr) * ldc + cc] =
                            acc[mi][ni][4 * g + rr];
            }
    }
}

// ---------------------------------------------------------------------------
// out = p0+p1+p2+p3 (fp32) — split-K=4 reduce for GEMM2
// ---------------------------------------------------------------------------
__global__ __launch_bounds__(256) void addf4_kernel(
    const float* __restrict__ p, float* __restrict__ o)
{
    size_t i = ((size_t)blockIdx.x * 256 + threadIdx.x) * 4;
    float4 a = *(const float4*)(p + i);
    float4 b = *(const float4*)(p + i + 4194304);
    float4 c = *(const float4*)(p + i + 8388608);
    float4 d = *(const float4*)(p + i + 12582912);
    float4 r = make_float4(a.x + b.x + c.x + d.x, a.y + b.y + c.y + d.y,
                           a.z + b.z + c.z + d.z, a.w + b.w + c.w + d.w);
    *(float4*)(o + i) = r;
}

// ---------------------------------------------------------------------------
// fp32 NT GEMM (dt split-K only)
// ---------------------------------------------------------------------------
__global__ __launch_bounds__(256) void gemm_nt(
    const float* __restrict__ A, int lda, long long sA,
    const float* __restrict__ B, int ldb, long long sB,
    float* __restrict__ C, int ldc, long long sC, int K)
{
    A += (long long)blockIdx.z * sA;
    B += (long long)blockIdx.z * sB;
    C += (long long)blockIdx.z * sC;
    const int t  = threadIdx.x;
    const int m0 = blockIdx.y * 128;
    const int n0 = blockIdx.x * 64;
    __shared__ float As[16][132];
    __shared__ float Bs[16][68];
    const int tx = t & 15;
    const int ty = t >> 4;

    const int arow = t & 127;
    const int akh  = (t >> 7) * 8;
    const float* Aload = A + (size_t)(m0 + arow) * (size_t)lda + akh;
    const int brow = t & 63;
    const int bk4  = (t >> 6) * 4;
    const float* Bload = B + (size_t)(n0 + brow) * (size_t)ldb + bk4;

    float acc[8][4];
#pragma unroll
    for (int i = 0; i < 8; i++)
#pragma unroll
        for (int j = 0; j < 4; j++) acc[i][j] = 0.f;

    for (int k0 = 0; k0 < K; k0 += 16) {
        __syncthreads();
        float4 a0 = *(const float4*)(Aload + k0);
        float4 a1 = *(const float4*)(Aload + k0 + 4);
        float4 b0 = *(const float4*)(Bload + k0);
        As[akh + 0][arow] = a0.x; As[akh + 1][arow] = a0.y;
        As[akh + 2][arow] = a0.z; As[akh + 3][arow] = a0.w;
        As[akh + 4][arow] = a1.x; As[akh + 5][arow] = a1.y;
        As[akh + 6][arow] = a1.z; As[akh + 7][arow] = a1.w;
        Bs[bk4 + 0][brow] = b0.x; Bs[bk4 + 1][brow] = b0.y;
        Bs[bk4 + 2][brow] = b0.z; Bs[bk4 + 3][brow] = b0.w;
        __syncthreads();
#pragma unroll
        for (int k = 0; k < 16; k++) {
            float4 a4 = *(const float4*)(&As[k][ty * 8]);
            float4 a5 = *(const float4*)(&As[k][ty * 8 + 4]);
            float4 b4 = *(const float4*)(&Bs[k][tx * 4]);
            float am[8] = {a4.x, a4.y, a4.z, a4.w, a5.x, a5.y, a5.z, a5.w};
            float bn[4] = {b4.x, b4.y, b4.z, b4.w};
#pragma unroll
            for (int i = 0; i < 8; i++)
#pragma unroll
                for (int j = 0; j < 4; j++) acc[i][j] += am[i] * bn[j];
        }
    }
#pragma unroll
    for (int i = 0; i < 8; i++) {
        float4 o = make_float4(acc[i][0], acc[i][1], acc[i][2], acc[i][3]);
        *(float4*)(C + (size_t)(m0 + ty * 8 + i) * (size_t)ldc + n0 + tx * 4) = o;
    }
}

// ---------------------------------------------------------------------------
__global__ __launch_bounds__(256) void dt_reduce_kernel(
    const float* __restrict__ part, const float* __restrict__ dt_bias,
    float* __restrict__ dtg)
{
    const int i = blockIdx.x * 256 + threadIdx.x;
    float x = dt_bias[i & 63];
#pragma unroll
    for (int z = 0; z < 32; z++) x += part[(size_t)z * 131072 + i];
    dtg[i] = (x > 20.f) ? x : log1pf(__expf(x));
}

// ---------------------------------------------------------------------------
// Causal depthwise conv (K=4) + bias + SiLU, 8 outputs/thread along s.
// ---------------------------------------------------------------------------
__global__ __launch_bounds__(256) void conv_silu8_kernel(
    const unsigned short* __restrict__ projbf, const float* __restrict__ conv_w,
    const float* __restrict__ conv_b, unsigned short* __restrict__ out)
{
    const int c  = blockIdx.x * 256 + threadIdx.x;   // [0, 4352)
    const int s0 = blockIdx.y * 8;
    const float4 w = *(const float4*)(conv_w + (size_t)c * 4);
    const float b = conv_b[c];
    const size_t base = 4096 + (size_t)c;
    float v[11];
#pragma unroll
    for (int m = 0; m < 11; m++) {
        int s = s0 - 3 + m;
        v[m] = (s >= 0) ? bf2f(projbf[(size_t)s * GEMM1N + base]) : 0.f;
    }
#pragma unroll
    for (int j = 0; j < 8; j++) {
        float acc = b + v[j] * w.x + v[j + 1] * w.y + v[j + 2] * w.z + v[j + 3] * w.w;
        float sig = 1.f / (1.f + __expf(-acc));
        out[(size_t)(s0 + j) * CONVD + c] = f2bf(acc * sig);
    }
}

// ---------------------------------------------------------------------------
// SSM core, MFMA, bf16 hBC input (unchanged from round 6)
// ---------------------------------------------------------------------------
__global__ __launch_bounds__(256, 2) void ssm_mfma_kernel(
    const unsigned short* __restrict__ hBC, const float* __restrict__ dtg,
    const float* __restrict__ Gm, const float* __restrict__ A_log,
    const float* __restrict__ Dp, float* __restrict__ y)
{
    const int h    = blockIdx.x;
    const int c    = blockIdx.y;
    const int t    = threadIdx.x;
    const int wid  = t >> 6;
    const int lane = t & 63;
    const int lo   = lane & 15;
    const int q    = lane >> 4;

    __shared__ float sAcum[CS], sdt[CS], sD[CS], sEs[CS], sDecay[CS], sScl[CS];
    __shared__ float sWaveSum[4];
    __shared__ unsigned short sHdtT[64 * 264];
    __shared__ unsigned short sStT[64 * 136];
    __shared__ unsigned short sBufB[128 * 72];

    const float A = -__expf(A_log[h]);
    const int row0 = c * CS;
    const unsigned short* hid = hBC + (size_t)row0 * CONVD + h * P_DIM;
    const unsigned short* Bp  = hBC + (size_t)row0 * CONVD + INTER;
    const unsigned short* Cp  = hBC + (size_t)row0 * CONVD + INTER + N_DIM;
    const float* gm = Gm + (size_t)c * CS * CS;

    float dtv = dtg[(size_t)(row0 + t) * NH + h];
    float v = A * dtv;
    for (int off = 1; off < 64; off <<= 1) {
        float u = __shfl_up(v, off, 64);
        if (lane >= off) v += u;
    }
    if (lane == 63) sWaveSum[wid] = v;
    __syncthreads();
    float pre = 0.f;
    for (int i = 0; i < 4; i++) if (i < wid) pre += sWaveSum[i];
    v += pre;
    sAcum[t] = v;
    sdt[t] = dtv;
    __syncthreads();
    const float AcumEnd = sAcum[CS - 1];
    {
        float ac   = sAcum[t];
        float apre = (t < 64) ? 0.f : sAcum[(t & ~63) - 1];
        sD[t]     = __expf(ac - apre);
        sEs[t]    = __expf(sAcum[t | 63] - ac);
        sDecay[t] = __expf(AcumEnd - ac);
        sScl[t]   = __expf(ac);
    }

    unsigned short* stgu = sStT;
    for (int lt = 0; lt < 4; lt++) {
        __syncthreads();
        {
            const int c8 = (t & 7) * 8;
#pragma unroll
            for (int j = 0; j < 2; j++) {
                int l = (t >> 3) + 32 * j;
                *(uint4*)&stgu[l * 64 + c8] =
                    *(const uint4*)(hid + (size_t)(lt * 64 + l) * CONVD + c8);
            }
        }
        __syncthreads();
        {
            const int p = t & 63, lq = (t >> 6) * 16;
#pragma unroll
            for (int j = 0; j < 4; j++) {
                ushort4 pk;
                int l0 = lq + j * 4;
                pk.x = f2bf(bf2f(stgu[(l0 + 0) * 64 + p]) * sdt[lt * 64 + l0 + 0]);
                pk.y = f2bf(bf2f(stgu[(l0 + 1) * 64 + p]) * sdt[lt * 64 + l0 + 1]);
                pk.z = f2bf(bf2f(stgu[(l0 + 2) * 64 + p]) * sdt[lt * 64 + l0 + 2]);
                pk.w = f2bf(bf2f(stgu[(l0 + 3) * 64 + p]) * sdt[lt * 64 + l0 + 3]);
                *(uint2*)&sHdtT[p * 264 + lt * 64 + l0] = *(uint2*)&pk;
            }
        }
    }

    f32x4 acc2[2][4];
#pragma unroll
    for (int mi = 0; mi < 2; mi++)
#pragma unroll
        for (int ni = 0; ni < 4; ni++) acc2[mi][ni] = (f32x4){0.f, 0.f, 0.f, 0.f};
    const int psub = (wid & 1) * 32;
    const int nsub = (wid >> 1) * 64;

    for (int qt = 0; qt < 4; qt++) {
        for (int hf = 0; hf < 2; hf++) {
            __syncthreads();
            {
                const int n8 = (t & 15) * 8;
#pragma unroll
                for (int j = 0; j < 2; j++) {
                    int r = (t >> 4) + 16 * j;
                    *(uint4*)&stgu[r * 128 + n8] =
                        *(const uint4*)(Bp + (size_t)(qt * 64 + hf * 32 + r) * CONVD + n8);
                }
            }
            __syncthreads();
            {
                const int n = t & 127, lc = (t >> 7) * 16;
#pragma unroll
                for (int j = 0; j < 4; j++) {
                    int l0 = lc + j * 4;
                    ushort4 pk;
                    pk.x = f2bf(bf2f(stgu[(l0 + 0) * 128 + n]) * sDecay[qt * 64 + hf * 32 + l0 + 0]);
                    pk.y = f2bf(bf2f(stgu[(l0 + 1) * 128 + n]) * sDecay[qt * 64 + hf * 32 + l0 + 1]);
                    pk.z = f2bf(bf2f(stgu[(l0 + 2) * 128 + n]) * sDecay[qt * 64 + hf * 32 + l0 + 2]);
                    pk.w = f2bf(bf2f(stgu[(l0 + 3) * 128 + n]) * sDecay[qt * 64 + hf * 32 + l0 + 3]);
                    *(uint2*)&sBufB[n * 72 + hf * 32 + l0] = *(uint2*)&pk;
                }
            }
        }
        __syncthreads();
#pragma unroll
        for (int ks = 0; ks < 2; ks++) {
            const int k0 = qt * 64 + ks * 32;
            const int kq = ks * 32;
            bf16x8 a2[2], b2[4];
#pragma unroll
            for (int mi = 0; mi < 2; mi++)
                a2[mi] = *(const bf16x8*)&sHdtT[(psub + mi * 16 + lo) * 264 + k0 + q * 8];
#pragma unroll
            for (int ni = 0; ni < 4; ni++)
                b2[ni] = *(const bf16x8*)&sBufB[(nsub + ni * 16 + lo) * 72 + kq + q * 8];
#pragma unroll
            for (int mi = 0; mi < 2; mi++)
#pragma unroll
                for (int ni = 0; ni < 4; ni++)
                    acc2[mi][ni] = __builtin_amdgcn_mfma_f32_16x16x32_bf16(
                        a2[mi], b2[ni], acc2[mi][ni], 0, 0, 0);
        }
    }
    __syncthreads();
#pragma unroll
    for (int mi = 0; mi < 2; mi++)
#pragma unroll
        for (int ni = 0; ni < 4; ni++)
#pragma unroll
            for (int rr = 0; rr < 4; rr++) {
                int p = psub + mi * 16 + q * 4 + rr;
                int n = nsub + ni * 16 + lo;
                sStT[p * 136 + n] = f2bf(acc2[mi][ni][rr]);
            }

    f32x4 accY[4][2][2];
#pragma unroll
    for (int i = 0; i < 4; i++)
#pragma unroll
        for (int mi = 0; mi < 2; mi++)
#pragma unroll
            for (int pi = 0; pi < 2; pi++) accY[i][mi][pi] = (f32x4){0.f, 0.f, 0.f, 0.f};
    const int pcol = (wid & 1) * 32;
    const int rsub = (wid >> 1) * 16;
    unsigned short* Cs = sBufB;

    for (int i = 0; i < 4; i++) {
        __syncthreads();
        {
            const int n8 = (t & 15) * 8;
#pragma unroll
            for (int j = 0; j < 4; j++) {
                int r = (t >> 4) + 16 * j;
                uint4 cv = *(const uint4*)(Cp + (size_t)(i * 64 + r) * CONVD + n8);
                float scl = sScl[i * 64 + r];
                const unsigned short* cu = (const unsigned short*)&cv;
                ushort4 p0, p1;
                p0.x = f2bf(bf2f(cu[0]) * scl); p0.y = f2bf(bf2f(cu[1]) * scl);
                p0.z = f2bf(bf2f(cu[2]) * scl); p0.w = f2bf(bf2f(cu[3]) * scl);
                p1.x = f2bf(bf2f(cu[4]) * scl); p1.y = f2bf(bf2f(cu[5]) * scl);
                p1.z = f2bf(bf2f(cu[6]) * scl); p1.w = f2bf(bf2f(cu[7]) * scl);
                *(uint2*)&Cs[r * 136 + n8]     = *(uint2*)&p0;
                *(uint2*)&Cs[r * 136 + n8 + 4] = *(uint2*)&p1;
            }
        }
        __syncthreads();
#pragma unroll
        for (int ks = 0; ks < 4; ks++) {
            const int k0 = ks * 32;
            bf16x8 a3[2], b3[2];
#pragma unroll
            for (int mi = 0; mi < 2; mi++)
                a3[mi] = *(const bf16x8*)&Cs[(mi * 32 + rsub + lo) * 136 + k0 + q * 8];
#pragma unroll
            for (int pi = 0; pi < 2; pi++)
                b3[pi] = *(const bf16x8*)&sStT[(pcol + pi * 16 + lo) * 136 + k0 + q * 8];
#pragma unroll
            for (int mi = 0; mi < 2; mi++)
#pragma unroll
                for (int pi = 0; pi < 2; pi++)
                    accY[i][mi][pi] = __builtin_amdgcn_mfma_f32_16x16x32_bf16(
                        a3[mi], b3[pi], accY[i][mi][pi], 0, 0, 0);
        }
    }

    unsigned short* Mt = sBufB;
    for (int i = 0; i < 4; i++) {
        const int nk = 2 * (i + 1);
        for (int mi = 0; mi < 2; mi++) {
            __syncthreads();
            if (wid <= i) {
                float P = 1.f;
                for (int m = wid + 1; m <= i - 1; m++) P *= sD[m * 64 + 63];
                const int s4 = wid * 64 + lo * 4;
                float4 es4 = *(const float4*)&sEs[s4];
#pragma unroll
                for (int j = 0; j < 8; j++) {
                    int lr = q + j * 4;
                    int l  = i * 64 + mi * 32 + lr;
                    float4 g4 = *(const float4*)&gm[(size_t)l * CS + s4];
                    float w0, w1, w2, w3;
                    if (wid == i) {
                        float al = sAcum[l];
                        w0 = (s4 + 0 <= l) ? __expf(al - sAcum[s4 + 0]) : 0.f;
                        w1 = (s4 + 1 <= l) ? __expf(al - sAcum[s4 + 1]) : 0.f;
                        w2 = (s4 + 2 <= l) ? __expf(al - sAcum[s4 + 2]) : 0.f;
                        w3 = (s4 + 3 <= l) ? __expf(al - sAcum[s4 + 3]) : 0.f;
                    } else {
                        float rs = sD[l] * P;
                        w0 = rs * es4.x; w1 = rs * es4.y;
                        w2 = rs * es4.z; w3 = rs * es4.w;
                    }
                    ushort4 pk;
                    pk.x = f2bf(g4.x * w0); pk.y = f2bf(g4.y * w1);
                    pk.z = f2bf(g4.z * w2); pk.w = f2bf(g4.w * w3);
                    *(uint2*)&Mt[lr * 264 + s4] = *(uint2*)&pk;
                }
            }
            __syncthreads();
            for (int ks = 0; ks < nk; ks++) {
                const int k0 = ks * 32;
                bf16x8 am = *(const bf16x8*)&Mt[(rsub + lo) * 264 + k0 + q * 8];
                bf16x8 b1[2];
#pragma unroll
                for (int pi = 0; pi < 2; pi++)
                    b1[pi] = *(const bf16x8*)&sHdtT[(pcol + pi * 16 + lo) * 264 + k0 + q * 8];
#pragma unroll
                for (int pi = 0; pi < 2; pi++)
                    accY[i][mi][pi] = __builtin_amdgcn_mfma_f32_16x16x32_bf16(
                        am, b1[pi], accY[i][mi][pi], 0, 0, 0);
            }
        }
    }

    const float Dh = Dp[h];
#pragma unroll
    for (int i = 0; i < 4; i++)
#pragma unroll
        for (int mi = 0; mi < 2; mi++)
#pragma unroll
            for (int pi = 0; pi < 2; pi++)
#pragma unroll
                for (int rr = 0; rr < 4; rr++) {
                    int l = i * 64 + mi * 32 + rsub + q * 4 + rr;
                    int p = pcol + pi * 16 + lo;
                    float hv = bf2f(hid[(size_t)l * CONVD + p]);
                    y[(size_t)(row0 + l) * INTER + h * P_DIM + p] =
                        accY[i][mi][pi][rr] + Dh * hv;
                }
}

// ---------------------------------------------------------------------------
// Gated RMSNorm (unchanged)
// ---------------------------------------------------------------------------
__global__ __launch_bounds__(256) void norm_kernel(
    const float* __restrict__ y, const unsigned short* __restrict__ projbf,
    const float* __restrict__ norm_w, unsigned short* __restrict__ yn)
{
    const int s = blockIdx.x;
    const int t = threadIdx.x;
    __shared__ float sYf[INTER];
    __shared__ float sW[4];
    const float* yrow = y + (size_t)s * INTER;
    const unsigned short* grow = projbf + (size_t)s * GEMM1N;
    float sum = 0.f;
    for (int j0 = 0; j0 < INTER; j0 += 2048) {
        int j = j0 + t * 8;
        float4 y0 = *(const float4*)(yrow + j);
        float4 y1 = *(const float4*)(yrow + j + 4);
        uint4 gp = *(const uint4*)(grow + j);
        float gv[8] = {
            bf2f((unsigned short)(gp.x & 0xffff)), bf2f((unsigned short)(gp.x >> 16)),
            bf2f((unsigned short)(gp.y & 0xffff)), bf2f((unsigned short)(gp.y >> 16)),
            bf2f((unsigned short)(gp.z & 0xffff)), bf2f((unsigned short)(gp.z >> 16)),
            bf2f((unsigned short)(gp.w & 0xffff)), bf2f((unsigned short)(gp.w >> 16))};
        float yv8[8] = {y0.x, y0.y, y0.z, y0.w, y1.x, y1.y, y1.z, y1.w};
#pragma unroll
        for (int e = 0; e < 8; e++) {
            float f = yv8[e] * (gv[e] / (1.f + __expf(-gv[e])));
            sum += f * f;
            sYf[j + e] = f;
        }
    }
    for (int off = 32; off > 0; off >>= 1) sum += __shfl_down(sum, off, 64);
    if ((t & 63) == 0) sW[t >> 6] = sum;
    __syncthreads();
    const float var = (sW[0] + sW[1] + sW[2] + sW[3]) * (1.f / (float)INTER);
    const float rs = rsqrtf(var + EPS);
    for (int j0 = 0; j0 < INTER; j0 += 2048) {
        int j = j0 + t * 8;
        float4 w0 = *(const float4*)(norm_w + j);
        float4 w1 = *(const float4*)(norm_w + j + 4);
        float wv[8] = {w0.x, w0.y, w0.z, w0.w, w1.x, w1.y, w1.z, w1.w};
        unsigned short o[8];
#pragma unroll
        for (int e = 0; e < 8; e++) o[e] = f2bf(sYf[j + e] * wv[e] * rs);
        uint4 ov;
        ov.x = (unsigned int)o[0] | ((unsigned int)o[1] << 16);
        ov.y = (unsigned int)o[2] | ((unsigned int)o[3] << 16);
        ov.z = (unsigned int)o[4] | ((unsigned int)o[5] << 16);
        ov.w = (unsigned int)o[6] | ((unsigned int)o[7] << 16);
        *(uint4*)(yn + (size_t)s * INTER + j) = ov;
    }
}

// ---------------------------------------------------------------------------
extern "C" void kernel_launch(void* const* d_in, const int* in_sizes, int n_in,
                              void* d_out, int out_size, void* d_ws, size_t ws_size,
                              hipStream_t stream)
{
    const float* X       = (const float*)d_in[0];
    const float* W_in    = (const float*)d_in[2];
    const float* conv_w  = (const float*)d_in[3];
    const float* conv_b  = (const float*)d_in[4];
    const float* dt_bias = (const float*)d_in[5];
    const float* A_log   = (const float*)d_in[6];
    const float* Dp      = (const float*)d_in[7];
    const float* norm_w  = (const float*)d_in[8];
    const float* W_out   = (const float*)d_in[9];
    float* out = (float*)d_out;
    float* ws  = (float*)d_ws;

    unsigned short* projbf = (unsigned short*)(ws + OFF_PROJBF);
    unsigned short* hbc16  = (unsigned short*)(ws + OFF_HBC);
    float* dtg     = ws + OFF_DTG;
    float* dtpart  = ws + OFF_DTPART;
    float* gm      = ws + OFF_GM;
    float* yv      = ws + OFF_YV;
    unsigned short* Xbf    = (unsigned short*)(ws + OFF_R);
    unsigned short* Winbf  = (unsigned short*)(ws + OFF_R + 2097152);
    unsigned short* ynbf   = (unsigned short*)(ws + OFF_R);   // aliases Xbf (post-GEMM1)
    unsigned short* Woutbf = (unsigned short*)(ws + OFF_WOUT);
    float* part = ws;   // GEMM2 split-K=4 partials: ws[0 .. 16,777,216)

    // all three casts in one launch
    cast3_kernel<<<14592, 256, 0, stream>>>(X, W_in, W_out, Xbf, Winbf, Woutbf);

    // GEMM1: proj[:, 0:8448] bf16 MFMA -> bf16; m-fastest block order
    gemm_bt_mfma<<<dim3(S_LEN / 128, GEMM1N / 128, 1), 256, 0, stream>>>(
        Xbf, E_DIM, 0LL, Winbf, E_DIM, 0LL, nullptr, projbf, GEMM1N, 0LL,
        E_DIM, 1);

    // dt columns fp32, split-K=32 (512 blocks)
    gemm_nt<<<dim3(1, 16, 32), 256, 0, stream>>>(
        X, E_DIM, 64LL, W_in + (size_t)GEMM1N * E_DIM, E_DIM, 64LL,
        dtpart, NH, 131072LL, 64);
    dt_reduce_kernel<<<512, 256, 0, stream>>>(dtpart, dt_bias, dtg);

    // conv + silu -> bf16 hBC
    conv_silu8_kernel<<<dim3(CONVD / 256, S_LEN / 8), 256, 0, stream>>>(
        projbf, conv_w, conv_b, hbc16);

    // Gm[c] = Cm_c @ Bm_c^T via bf16 MFMA (fp32 out)
    gemm_bt_mfma<<<dim3(CS / 128, CS / 128, NCHUNK), 256, 0, stream>>>(
        hbc16 + INTER + N_DIM, CONVD, (long long)CS * CONVD,
        hbc16 + INTER,         CONVD, (long long)CS * CONVD,
        gm, nullptr, CS, (long long)CS * CS, N_DIM, 0);

    ssm_mfma_kernel<<<dim3(NH, NCHUNK), 256, 0, stream>>>(
        hbc16, dtg, gm, A_log, Dp, yv);

    norm_kernel<<<dim3(S_LEN), 256, 0, stream>>>(yv, projbf, norm_w, ynbf);

    // GEMM2 split-K=4 (1024 blocks): partials into ws[0..16.8M), then reduce
    gemm_bt_mfma<<<dim3(E_DIM / 128, S_LEN / 128, 4), 256, 0, stream>>>(
        ynbf, INTER, 1024LL, Woutbf, INTER, 1024LL,
        part, nullptr, E_DIM, 4194304LL, 1024, 0);
    addf4_kernel<<<4096, 256, 0, stream>>>(part, out);
}